// Round 4
// baseline (32568.219 us; speedup 1.0000x reference)
//
#include <hip/hip_runtime.h>
#include <hip/hip_bf16.h>

typedef __hip_bfloat16 bf16;

#define B_   16
#define T_   500
#define D_   768
#define NH_  12
#define DH_  64
#define FFN_ 3072

__device__ __forceinline__ float bfu2f(unsigned short u){ return __uint_as_float(((unsigned)u)<<16); }
__device__ __forceinline__ float geluf(float x){ return 0.5f*x*(1.0f + erff(x*0.70710678118654752f)); }

__device__ __forceinline__ float4 ld4f(const float* p){ return *reinterpret_cast<const float4*>(p); }
__device__ __forceinline__ float4 ld4f(const bf16* p){
  ushort4 u = *reinterpret_cast<const ushort4*>(p);
  return make_float4(bfu2f(u.x), bfu2f(u.y), bfu2f(u.z), bfu2f(u.w));
}
__device__ __forceinline__ float ld1f(const float* p){ return *p; }
__device__ __forceinline__ float ld1f(const bf16* p){ return __bfloat162float(*p); }

// ---------------- conv 5x5 (pad 2) + exact GELU + maxpool(2,1) over H ----------------
// in: [B, Cin, Hin, T] (fp32 for layer 1, bf16 ws after)   out: [B, Cout, Hin/2, T] bf16
// weights/bias fp32 (harness inputs)
template<typename Tin>
__global__ __launch_bounds__(256) void conv_gelu_pool(const Tin* __restrict__ in,
    const float* __restrict__ w, const float* __restrict__ bias, bf16* __restrict__ out,
    int Cin, int Hin, int Cout)
{
  const int T = T_;
  const int Hout = Hin >> 1;
  const int bc = blockIdx.y;
  const int b = bc / Cout, oc = bc % Cout;

  __shared__ float wsm[64*25];
  for (int i = threadIdx.x; i < Cin*25; i += 256)
    wsm[i] = w[(size_t)oc*Cin*25 + i];
  __syncthreads();

  const int pos = blockIdx.x*256 + threadIdx.x;
  if (pos >= Hout*T) return;
  const int x = pos % T, yo = pos / T;
  const float bv = bias[oc];
  float a0 = bv, a1 = bv;
  const int y0 = 2*yo;

  for (int ci = 0; ci < Cin; ci++){
    const Tin* ip = in + ((size_t)(b*Cin + ci)*Hin)*T;
    const float* wf = wsm + ci*25;
    #pragma unroll
    for (int r = 0; r < 6; r++){            // union of the two pooled rows' taps
      const int yy = y0 - 2 + r;
      if (yy < 0 || yy >= Hin) continue;
      const Tin* rp = ip + (size_t)yy*T;
      #pragma unroll
      for (int kx = 0; kx < 5; kx++){
        const int xx = x - 2 + kx;
        const float v = (xx >= 0 && xx < T) ? ld1f(rp + xx) : 0.f;
        if (r < 5)  a0 = fmaf(v, wf[r*5 + kx], a0);
        if (r >= 1) a1 = fmaf(v, wf[(r-1)*5 + kx], a1);
      }
    }
  }
  // pool AFTER gelu (gelu is not monotonic)
  out[((size_t)bc*Hout + yo)*T + x] = __float2bfloat16(fmaxf(geluf(a0), geluf(a1)));
}

// ---------------- transpose [B,768,T] -> [B*T, 768] (bf16 ws -> bf16 ws) ----------------
__global__ __launch_bounds__(256) void transpose_ct(const bf16* __restrict__ p4, bf16* __restrict__ tk)
{
  const int idx = blockIdx.x*256 + threadIdx.x;
  if (idx >= B_*D_*T_) return;
  const int t = idx % T_;
  const int c = (idx / T_) % D_;
  const int b = idx / (T_*D_);
  tk[((size_t)(b*T_ + t))*D_ + c] = p4[idx];
}

// ---------------- GEMM: C = act(A[MxK] @ Bw[KxN] + bias) (+resid) ----------------
// A fp32 or bf16 row-major; Bw/bias fp32 (harness weights). M%64==0, N%64==0, K%16==0.
template<typename TA, int ACT, int RESID, int BF16OUT>
__global__ __launch_bounds__(256) void gemm_k(const TA* __restrict__ A,
    const float* __restrict__ Bw, const float* __restrict__ bias,
    const float* __restrict__ resid, void* __restrict__ Cout, int M, int N, int K)
{
  __shared__ float As[16][65];
  __shared__ float Bs[16][65];
  const int bm = blockIdx.y*64, bn = blockIdx.x*64;
  const int tid = threadIdx.x;
  const int tr = tid >> 4, tc = tid & 15;

  const int am  = tid >> 2;     // A-load row 0..63
  const int ak4 = tid & 3;      // which 4-float group along k
  const int bk  = tid >> 4;     // B-load row 0..15
  const int bn4 = tid & 15;     // which 4-col group

  float acc[4][4] = {{0.f}};

  for (int k0 = 0; k0 < K; k0 += 16){
    const float4 av = ld4f(A + (size_t)(bm + am)*K + k0 + ak4*4);
    As[ak4*4+0][am] = av.x; As[ak4*4+1][am] = av.y;
    As[ak4*4+2][am] = av.z; As[ak4*4+3][am] = av.w;

    const float4 bv = ld4f(Bw + (size_t)(k0 + bk)*N + bn + bn4*4);
    Bs[bk][bn4*4+0] = bv.x; Bs[bk][bn4*4+1] = bv.y;
    Bs[bk][bn4*4+2] = bv.z; Bs[bk][bn4*4+3] = bv.w;
    __syncthreads();

    #pragma unroll
    for (int k = 0; k < 16; k++){
      float a[4], bb_[4];
      #pragma unroll
      for (int i = 0; i < 4; i++) a[i]  = As[k][tr*4 + i];
      #pragma unroll
      for (int j = 0; j < 4; j++) bb_[j] = Bs[k][tc*4 + j];
      #pragma unroll
      for (int i = 0; i < 4; i++)
        #pragma unroll
        for (int j = 0; j < 4; j++)
          acc[i][j] = fmaf(a[i], bb_[j], acc[i][j]);
    }
    __syncthreads();
  }

  #pragma unroll
  for (int i = 0; i < 4; i++){
    const int row = bm + tr*4 + i;
    #pragma unroll
    for (int j = 0; j < 4; j++){
      const int col = bn + tc*4 + j;
      float v = acc[i][j] + bias[col];
      if (ACT == 1) v = geluf(v);
      if (RESID)    v += resid[(size_t)row*N + col];
      if (BF16OUT)  reinterpret_cast<bf16*>(Cout)[(size_t)row*N + col] = __float2bfloat16(v);
      else          reinterpret_cast<float*>(Cout)[(size_t)row*N + col] = v;
    }
  }
}

// ---------------- LayerNorm over D=768: fp32 in -> bf16 out; g/b fp32 ----------------
__global__ __launch_bounds__(256) void layernorm_k(const float* __restrict__ x,
    const float* __restrict__ g, const float* __restrict__ bb, bf16* __restrict__ out)
{
  const int row = blockIdx.x;
  const float* xr = x + (size_t)row*D_;
  const int tid = threadIdx.x;
  const float v0 = xr[tid], v1 = xr[tid+256], v2 = xr[tid+512];

  float s = v0 + v1 + v2;
  #pragma unroll
  for (int o = 32; o > 0; o >>= 1) s += __shfl_xor(s, o);
  __shared__ float sm[4];
  const int wid = tid >> 6, lane = tid & 63;
  if (lane == 0) sm[wid] = s;
  __syncthreads();
  const float mean = (sm[0]+sm[1]+sm[2]+sm[3]) * (1.f/768.f);
  __syncthreads();

  const float d0 = v0-mean, d1 = v1-mean, d2 = v2-mean;
  float ss = d0*d0 + d1*d1 + d2*d2;
  #pragma unroll
  for (int o = 32; o > 0; o >>= 1) ss += __shfl_xor(ss, o);
  if (lane == 0) sm[wid] = ss;
  __syncthreads();
  const float var = (sm[0]+sm[1]+sm[2]+sm[3]) * (1.f/768.f);
  const float inv = rsqrtf(var + 1e-5f);

  bf16* orow = out + (size_t)row*D_;
  orow[tid]     = __float2bfloat16(d0*inv*g[tid]     + bb[tid]);
  orow[tid+256] = __float2bfloat16(d1*inv*g[tid+256] + bb[tid+256]);
  orow[tid+512] = __float2bfloat16(d2*inv*g[tid+512] + bb[tid+512]);
}

// ---------------- simple attention: one wave per (b,h,q) ----------------
// lane d holds head-dim d. Exact skew srel:
//   k<=q -> q[q].er[499-(q-k)] ; k==q+1 -> 0 ; k>q+1 -> q[q+1].er[k-q-2]
__global__ __launch_bounds__(256) void attn_simple_k(const bf16* __restrict__ qb,
    const bf16* __restrict__ kb, const bf16* __restrict__ vb,
    const float* __restrict__ er, bf16* __restrict__ ob)
{
  const int tid = threadIdx.x;
  const int gid = blockIdx.x*4 + (tid >> 6);
  if (gid >= B_*NH_*T_) return;
  const int lane = tid & 63;
  const int q  = gid % T_;
  const int bh = gid / T_;
  const int b = bh / NH_, h = bh % NH_;

  const size_t rowQ = ((size_t)(b*T_ + q))*D_ + h*DH_ + lane;
  const float qd = __bfloat162float(qb[rowQ]);
  const float qn = (q+1 < T_) ? __bfloat162float(qb[rowQ + D_]) : 0.f;

  const bf16* kbase = kb + ((size_t)b*T_)*D_ + h*DH_ + lane;
  const bf16* vbase = vb + ((size_t)b*T_)*D_ + h*DH_ + lane;

  float m = -1.0e30f, l = 0.f, oacc = 0.f;
  for (int k = 0; k < T_; k++){
    float part = qd * __bfloat162float(kbase[(size_t)k*D_]);
    if (k <= q)          part += qd * er[(499 - q + k)*DH_ + lane];
    else if (k > q + 1)  part += qn * er[(k - q - 2)*DH_ + lane];
    #pragma unroll
    for (int o = 32; o > 0; o >>= 1) part += __shfl_xor(part, o);
    const float s = part * 0.125f;
    const float mn = fmaxf(m, s);
    const float p    = __expf(s - mn);
    const float corr = __expf(m - mn);
    l = l*corr + p;
    oacc = oacc*corr + p * __bfloat162float(vbase[(size_t)k*D_]);
    m = mn;
  }
  ob[rowQ] = __float2bfloat16(oacc / l);
}

// =====================================================================
extern "C" void kernel_launch(void* const* d_in, const int* in_sizes, int n_in,
                              void* d_out, int out_size, void* d_ws, size_t ws_size,
                              hipStream_t stream)
{
  // ALL harness tensors are fp32 (reference dtypes).
  const float* spec  = (const float*)d_in[0];
  const float* cw1 = (const float*)d_in[1];  const float* cb1 = (const float*)d_in[2];
  const float* cw2 = (const float*)d_in[3];  const float* cb2 = (const float*)d_in[4];
  const float* cw3 = (const float*)d_in[5];  const float* cb3 = (const float*)d_in[6];
  const float* cw4 = (const float*)d_in[7];  const float* cb4 = (const float*)d_in[8];
  const float* proj_w = (const float*)d_in[9];  const float* proj_b = (const float*)d_in[10];
  const float* ln1_g = (const float*)d_in[11];  const float* ln1_b = (const float*)d_in[12];
  const float* wq = (const float*)d_in[13];  const float* bq = (const float*)d_in[14];
  const float* wk = (const float*)d_in[15];  const float* bk = (const float*)d_in[16];
  const float* wv = (const float*)d_in[17];  const float* bv = (const float*)d_in[18];
  const float* wo = (const float*)d_in[19];  const float* bo = (const float*)d_in[20];
  const float* er = (const float*)d_in[21];
  const float* ln2_g = (const float*)d_in[22];  const float* ln2_b = (const float*)d_in[23];
  const float* w1 = (const float*)d_in[24];  const float* b1 = (const float*)d_in[25];
  const float* w2 = (const float*)d_in[26];  const float* b2 = (const float*)d_in[27];
  const float* dw = (const float*)d_in[28];  const float* db = (const float*)d_in[29];

  // ---- workspace plan (byte offsets; peak 98,304,000 B; ws >= 98.3MB confirmed) ----
  if (ws_size < 98304000ull) return;   // graceful fail (absmax 1.539) instead of OOB fault
  char* W = (char*)d_ws;
  bf16*  p1 = (bf16*) (W + 0);          // [16,32,96,500]  49.152 MB
  bf16*  p2 = (bf16*) (W + 49152000);   // [16,64,48,500]  49.152 MB
  bf16*  p3 = (bf16*) (W + 0);          // [16,64,24,500]  24.576 MB
  bf16*  p4 = (bf16*) (W + 24576000);   // [16,64,12,500]  12.288 MB
  bf16*  tk = (bf16*) (W + 49152000);   // tokens [8000,768] 12.288 MB
  float* xb = (float*)(W + 0);          // residual fp32 [8000,768] 24.576 MB
  bf16*  xn = (bf16*) (W + 24576000);   // LN out
  bf16*  qb = (bf16*) (W + 36864000);
  bf16*  kb = (bf16*) (W + 49152000);
  bf16*  vb = (bf16*) (W + 61440000);
  bf16*  ob = (bf16*) (W + 73728000);
  bf16*  hb = (bf16*) (W + 36864000);   // FFN hidden [8000,3072] (q/k/v/ob dead)

  // ---- CNN stack ----
  conv_gelu_pool<float><<<dim3((96*T_+255)/256, B_*32), 256, 0, stream>>>(spec, cw1, cb1, p1,  1, 192, 32);
  conv_gelu_pool<bf16> <<<dim3((48*T_+255)/256, B_*64), 256, 0, stream>>>(p1,  cw2, cb2, p2, 32,  96, 64);
  conv_gelu_pool<bf16> <<<dim3((24*T_+255)/256, B_*64), 256, 0, stream>>>(p2,  cw3, cb3, p3, 64,  48, 64);
  conv_gelu_pool<bf16> <<<dim3((12*T_+255)/256, B_*64), 256, 0, stream>>>(p3,  cw4, cb4, p4, 64,  24, 64);

  transpose_ct<<<(B_*D_*T_ + 255)/256, 256, 0, stream>>>(p4, tk);
  gemm_k<bf16,0,0,0><<<dim3(D_/64, 125), 256, 0, stream>>>(tk, proj_w, proj_b, nullptr, xb, 8000, D_, D_);

  // ---- transformer layers ----
  for (int l = 0; l < 3; l++){
    const size_t wOff = (size_t)l*D_*D_;
    layernorm_k<<<8000, 256, 0, stream>>>(xb, ln1_g + l*D_, ln1_b + l*D_, xn);
    gemm_k<bf16,0,0,1><<<dim3(12,125), 256, 0, stream>>>(xn, wq + wOff, bq + l*D_, nullptr, qb, 8000, D_, D_);
    gemm_k<bf16,0,0,1><<<dim3(12,125), 256, 0, stream>>>(xn, wk + wOff, bk + l*D_, nullptr, kb, 8000, D_, D_);
    gemm_k<bf16,0,0,1><<<dim3(12,125), 256, 0, stream>>>(xn, wv + wOff, bv + l*D_, nullptr, vb, 8000, D_, D_);

    attn_simple_k<<<(B_*NH_*T_ + 3)/4, 256, 0, stream>>>(qb, kb, vb, er + (size_t)l*T_*DH_, ob);

    gemm_k<bf16,0,1,0><<<dim3(12,125), 256, 0, stream>>>(ob, wo + wOff, bo + l*D_, xb, xb, 8000, D_, D_);

    layernorm_k<<<8000, 256, 0, stream>>>(xb, ln2_g + l*D_, ln2_b + l*D_, xn);
    gemm_k<bf16,1,0,1><<<dim3(FFN_/64,125), 256, 0, stream>>>(xn, w1 + (size_t)l*D_*FFN_, b1 + l*FFN_, nullptr, hb, 8000, FFN_, D_);
    gemm_k<bf16,0,1,0><<<dim3(12,125),      256, 0, stream>>>(hb, w2 + (size_t)l*FFN_*D_, b2 + l*D_,   xb, xb, 8000, D_, FFN_);
  }

  // ---- deproj -> fp32 output [8000, 192] ----
  gemm_k<float,0,0,0><<<dim3(192/64, 125), 256, 0, stream>>>(xb, dw, db, nullptr, d_out, 8000, 192, D_);
}

// Round 5
// 26902.161 us; speedup vs baseline: 1.2106x; 1.2106x over previous
//
#include <hip/hip_runtime.h>
#include <hip/hip_bf16.h>

typedef __hip_bfloat16 bf16;
typedef __attribute__((ext_vector_type(8))) short bf16x8;
typedef __attribute__((ext_vector_type(4))) float f32x4;

#define B_   16
#define T_   500
#define D_   768
#define NH_  12
#define DH_  64
#define FFN_ 3072

__device__ __forceinline__ float bfu2f(unsigned short u){ return __uint_as_float(((unsigned)u)<<16); }
__device__ __forceinline__ float geluf(float x){ return 0.5f*x*(1.0f + erff(x*0.70710678118654752f)); }

__device__ __forceinline__ float4 ld4f(const float* p){ return *reinterpret_cast<const float4*>(p); }
__device__ __forceinline__ float4 ld4f(const bf16* p){
  ushort4 u = *reinterpret_cast<const ushort4*>(p);
  return make_float4(bfu2f(u.x), bfu2f(u.y), bfu2f(u.z), bfu2f(u.w));
}
__device__ __forceinline__ float ld1f(const float* p){ return *p; }
__device__ __forceinline__ float ld1f(const bf16* p){ return __bfloat162float(*p); }

// ---------------- conv 5x5 (pad 2) + exact GELU + maxpool(2,1) over H ----------------
template<typename Tin>
__global__ __launch_bounds__(256) void conv_gelu_pool(const Tin* __restrict__ in,
    const float* __restrict__ w, const float* __restrict__ bias, bf16* __restrict__ out,
    int Cin, int Hin, int Cout)
{
  const int T = T_;
  const int Hout = Hin >> 1;
  const int bc = blockIdx.y;
  const int b = bc / Cout, oc = bc % Cout;

  __shared__ float wsm[64*25];
  for (int i = threadIdx.x; i < Cin*25; i += 256)
    wsm[i] = w[(size_t)oc*Cin*25 + i];
  __syncthreads();

  const int pos = blockIdx.x*256 + threadIdx.x;
  if (pos >= Hout*T) return;
  const int x = pos % T, yo = pos / T;
  const float bv = bias[oc];
  float a0 = bv, a1 = bv;
  const int y0 = 2*yo;

  for (int ci = 0; ci < Cin; ci++){
    const Tin* ip = in + ((size_t)(b*Cin + ci)*Hin)*T;
    const float* wf = wsm + ci*25;
    #pragma unroll
    for (int r = 0; r < 6; r++){
      const int yy = y0 - 2 + r;
      if (yy < 0 || yy >= Hin) continue;
      const Tin* rp = ip + (size_t)yy*T;
      #pragma unroll
      for (int kx = 0; kx < 5; kx++){
        const int xx = x - 2 + kx;
        const float v = (xx >= 0 && xx < T) ? ld1f(rp + xx) : 0.f;
        if (r < 5)  a0 = fmaf(v, wf[r*5 + kx], a0);
        if (r >= 1) a1 = fmaf(v, wf[(r-1)*5 + kx], a1);
      }
    }
  }
  out[((size_t)bc*Hout + yo)*T + x] = __float2bfloat16(fmaxf(geluf(a0), geluf(a1)));
}

// ---------------- transpose [B,768,T] -> [B*T, 768] ----------------
__global__ __launch_bounds__(256) void transpose_ct(const bf16* __restrict__ p4, bf16* __restrict__ tk)
{
  const int idx = blockIdx.x*256 + threadIdx.x;
  if (idx >= B_*D_*T_) return;
  const int t = idx % T_;
  const int c = (idx / T_) % D_;
  const int b = idx / (T_*D_);
  tk[((size_t)(b*T_ + t))*D_ + c] = p4[idx];
}

// ---------------- weight transpose+convert: fp32 [K][N] -> bf16 [N][K] ----------------
__global__ __launch_bounds__(256) void transpose_w(const float* __restrict__ W,
    bf16* __restrict__ out, int K, int N)
{
  __shared__ float tile[32][33];
  const int gk = blockIdx.y*32, gn = blockIdx.x*32;
  const int tr = threadIdx.x >> 5, tc = threadIdx.x & 31;
  #pragma unroll
  for (int i = 0; i < 4; i++)
    tile[tr + i*8][tc] = W[(size_t)(gk + tr + i*8)*N + gn + tc];
  __syncthreads();
  #pragma unroll
  for (int i = 0; i < 4; i++)
    out[(size_t)(gn + tr + i*8)*K + gk + tc] = __float2bfloat16(tile[tc][tr + i*8]);
}

// ---------------- MFMA GEMM: C = act(A[MxK](bf16) @ Bt[NxK]^T(bf16) + bias) (+resid) ----------------
// 128x128 tile, BK=32, 4 waves (2x2), mfma_f32_16x16x32_bf16.
// LDS chunk layout [kgroup g][row]: lane-contiguous ds_write/ds_read (conflict-free).
template<int ACT, int RESID, int BF16OUT>
__global__ __launch_bounds__(256) void mfma_gemm_k(const bf16* __restrict__ A,
    const bf16* __restrict__ Bt, const float* __restrict__ bias,
    const float* __restrict__ resid, void* __restrict__ Cout, int M, int N, int K)
{
  __shared__ uint4 Alds[512];   // [g 0..3][r 0..127] of 8 bf16
  __shared__ uint4 Blds[512];   // [g 0..3][n 0..127] of 8 bf16

  const int tid = threadIdx.x;
  const int wid = tid >> 6, lane = tid & 63;
  const int wr = wid >> 1, wc = wid & 1;
  const int bm = blockIdx.y*128, bn = blockIdx.x*128;

  const int g0 = tid >> 7;          // 0..1 ; second pass uses g0+2
  const int r0 = tid & 127;
  const int arow = min(bm + r0, M-1);
  const int brow = bn + r0;         // N % 128 == 0 at all call sites
  const int lg = lane >> 4, lr = lane & 15;

  f32x4 acc[4][4];
  #pragma unroll
  for (int i = 0; i < 4; i++)
    #pragma unroll
    for (int j = 0; j < 4; j++)
      acc[i][j] = (f32x4){0.f,0.f,0.f,0.f};

  for (int k0 = 0; k0 < K; k0 += 32){
    const uint4 av0 = *reinterpret_cast<const uint4*>(A  + (size_t)arow*K + k0 + g0*8);
    const uint4 av1 = *reinterpret_cast<const uint4*>(A  + (size_t)arow*K + k0 + (g0+2)*8);
    const uint4 bv0 = *reinterpret_cast<const uint4*>(Bt + (size_t)brow*K + k0 + g0*8);
    const uint4 bv1 = *reinterpret_cast<const uint4*>(Bt + (size_t)brow*K + k0 + (g0+2)*8);
    __syncthreads();
    Alds[g0*128 + r0] = av0;  Alds[(g0+2)*128 + r0] = av1;
    Blds[g0*128 + r0] = bv0;  Blds[(g0+2)*128 + r0] = bv1;
    __syncthreads();

    bf16x8 af[4], bfr[4];
    #pragma unroll
    for (int mf = 0; mf < 4; mf++)
      af[mf] = *reinterpret_cast<const bf16x8*>(&Alds[lg*128 + wr*64 + mf*16 + lr]);
    #pragma unroll
    for (int nf = 0; nf < 4; nf++)
      bfr[nf] = *reinterpret_cast<const bf16x8*>(&Blds[lg*128 + wc*64 + nf*16 + lr]);

    #pragma unroll
    for (int mf = 0; mf < 4; mf++)
      #pragma unroll
      for (int nf = 0; nf < 4; nf++)
        acc[mf][nf] = __builtin_amdgcn_mfma_f32_16x16x32_bf16(af[mf], bfr[nf], acc[mf][nf], 0, 0, 0);
  }

  // C/D layout: col = lane&15, row = (lane>>4)*4 + reg   [m89-verified]
  #pragma unroll
  for (int mf = 0; mf < 4; mf++){
    #pragma unroll
    for (int rg = 0; rg < 4; rg++){
      const int row = bm + wr*64 + mf*16 + (lane>>4)*4 + rg;
      if (row >= M) continue;
      #pragma unroll
      for (int nf = 0; nf < 4; nf++){
        const int col = bn + wc*64 + nf*16 + (lane&15);
        float v = acc[mf][nf][rg] + bias[col];
        if (ACT == 1) v = geluf(v);
        if (RESID)    v += resid[(size_t)row*N + col];
        if (BF16OUT)  reinterpret_cast<bf16*>(Cout)[(size_t)row*N + col] = __float2bfloat16(v);
        else          reinterpret_cast<float*>(Cout)[(size_t)row*N + col] = v;
      }
    }
  }
}

// ---------------- fp32 fallback GEMM (deproj: N=192) ----------------
template<typename TA, int ACT, int RESID, int BF16OUT>
__global__ __launch_bounds__(256) void gemm_k(const TA* __restrict__ A,
    const float* __restrict__ Bw, const float* __restrict__ bias,
    const float* __restrict__ resid, void* __restrict__ Cout, int M, int N, int K)
{
  __shared__ float As[16][65];
  __shared__ float Bs[16][65];
  const int bm = blockIdx.y*64, bn = blockIdx.x*64;
  const int tid = threadIdx.x;
  const int tr = tid >> 4, tc = tid & 15;

  const int am  = tid >> 2;
  const int ak4 = tid & 3;
  const int bk  = tid >> 4;
  const int bn4 = tid & 15;

  float acc[4][4] = {{0.f}};

  for (int k0 = 0; k0 < K; k0 += 16){
    const float4 av = ld4f(A + (size_t)(bm + am)*K + k0 + ak4*4);
    As[ak4*4+0][am] = av.x; As[ak4*4+1][am] = av.y;
    As[ak4*4+2][am] = av.z; As[ak4*4+3][am] = av.w;

    const float4 bv = ld4f(Bw + (size_t)(k0 + bk)*N + bn + bn4*4);
    Bs[bk][bn4*4+0] = bv.x; Bs[bk][bn4*4+1] = bv.y;
    Bs[bk][bn4*4+2] = bv.z; Bs[bk][bn4*4+3] = bv.w;
    __syncthreads();

    #pragma unroll
    for (int k = 0; k < 16; k++){
      float a[4], bb_[4];
      #pragma unroll
      for (int i = 0; i < 4; i++) a[i]  = As[k][tr*4 + i];
      #pragma unroll
      for (int j = 0; j < 4; j++) bb_[j] = Bs[k][tc*4 + j];
      #pragma unroll
      for (int i = 0; i < 4; i++)
        #pragma unroll
        for (int j = 0; j < 4; j++)
          acc[i][j] = fmaf(a[i], bb_[j], acc[i][j]);
    }
    __syncthreads();
  }

  #pragma unroll
  for (int i = 0; i < 4; i++){
    const int row = bm + tr*4 + i;
    #pragma unroll
    for (int j = 0; j < 4; j++){
      const int col = bn + tc*4 + j;
      float v = acc[i][j] + bias[col];
      if (ACT == 1) v = geluf(v);
      if (RESID)    v += resid[(size_t)row*N + col];
      if (BF16OUT)  reinterpret_cast<bf16*>(Cout)[(size_t)row*N + col] = __float2bfloat16(v);
      else          reinterpret_cast<float*>(Cout)[(size_t)row*N + col] = v;
    }
  }
}

// ---------------- LayerNorm over D=768: fp32 in -> bf16 out ----------------
__global__ __launch_bounds__(256) void layernorm_k(const float* __restrict__ x,
    const float* __restrict__ g, const float* __restrict__ bb, bf16* __restrict__ out)
{
  const int row = blockIdx.x;
  const float* xr = x + (size_t)row*D_;
  const int tid = threadIdx.x;
  const float v0 = xr[tid], v1 = xr[tid+256], v2 = xr[tid+512];

  float s = v0 + v1 + v2;
  #pragma unroll
  for (int o = 32; o > 0; o >>= 1) s += __shfl_xor(s, o);
  __shared__ float sm[4];
  const int wid = tid >> 6, lane = tid & 63;
  if (lane == 0) sm[wid] = s;
  __syncthreads();
  const float mean = (sm[0]+sm[1]+sm[2]+sm[3]) * (1.f/768.f);
  __syncthreads();

  const float d0 = v0-mean, d1 = v1-mean, d2 = v2-mean;
  float ss = d0*d0 + d1*d1 + d2*d2;
  #pragma unroll
  for (int o = 32; o > 0; o >>= 1) ss += __shfl_xor(ss, o);
  if (lane == 0) sm[wid] = ss;
  __syncthreads();
  const float var = (sm[0]+sm[1]+sm[2]+sm[3]) * (1.f/768.f);
  const float inv = rsqrtf(var + 1e-5f);

  bf16* orow = out + (size_t)row*D_;
  orow[tid]     = __float2bfloat16(d0*inv*g[tid]     + bb[tid]);
  orow[tid+256] = __float2bfloat16(d1*inv*g[tid+256] + bb[tid+256]);
  orow[tid+512] = __float2bfloat16(d2*inv*g[tid+512] + bb[tid+512]);
}

// ---------------- simple attention: one wave per (b,h,q) ----------------
__global__ __launch_bounds__(256) void attn_simple_k(const bf16* __restrict__ qb,
    const bf16* __restrict__ kb, const bf16* __restrict__ vb,
    const float* __restrict__ er, bf16* __restrict__ ob)
{
  const int tid = threadIdx.x;
  const int gid = blockIdx.x*4 + (tid >> 6);
  if (gid >= B_*NH_*T_) return;
  const int lane = tid & 63;
  const int q  = gid % T_;
  const int bh = gid / T_;
  const int b = bh / NH_, h = bh % NH_;

  const size_t rowQ = ((size_t)(b*T_ + q))*D_ + h*DH_ + lane;
  const float qd = __bfloat162float(qb[rowQ]);
  const float qn = (q+1 < T_) ? __bfloat162float(qb[rowQ + D_]) : 0.f;

  const bf16* kbase = kb + ((size_t)b*T_)*D_ + h*DH_ + lane;
  const bf16* vbase = vb + ((size_t)b*T_)*D_ + h*DH_ + lane;

  float m = -1.0e30f, l = 0.f, oacc = 0.f;
  for (int k = 0; k < T_; k++){
    float part = qd * __bfloat162float(kbase[(size_t)k*D_]);
    if (k <= q)          part += qd * er[(499 - q + k)*DH_ + lane];
    else if (k > q + 1)  part += qn * er[(k - q - 2)*DH_ + lane];
    #pragma unroll
    for (int o = 32; o > 0; o >>= 1) part += __shfl_xor(part, o);
    const float s = part * 0.125f;
    const float mn = fmaxf(m, s);
    const float p    = __expf(s - mn);
    const float corr = __expf(m - mn);
    l = l*corr + p;
    oacc = oacc*corr + p * __bfloat162float(vbase[(size_t)k*D_]);
    m = mn;
  }
  ob[rowQ] = __float2bfloat16(oacc / l);
}

// =====================================================================
extern "C" void kernel_launch(void* const* d_in, const int* in_sizes, int n_in,
                              void* d_out, int out_size, void* d_ws, size_t ws_size,
                              hipStream_t stream)
{
  const float* spec  = (const float*)d_in[0];
  const float* cw1 = (const float*)d_in[1];  const float* cb1 = (const float*)d_in[2];
  const float* cw2 = (const float*)d_in[3];  const float* cb2 = (const float*)d_in[4];
  const float* cw3 = (const float*)d_in[5];  const float* cb3 = (const float*)d_in[6];
  const float* cw4 = (const float*)d_in[7];  const float* cb4 = (const float*)d_in[8];
  const float* proj_w = (const float*)d_in[9];  const float* proj_b = (const float*)d_in[10];
  const float* ln1_g = (const float*)d_in[11];  const float* ln1_b = (const float*)d_in[12];
  const float* wq = (const float*)d_in[13];  const float* bq = (const float*)d_in[14];
  const float* wk = (const float*)d_in[15];  const float* bk = (const float*)d_in[16];
  const float* wv = (const float*)d_in[17];  const float* bv = (const float*)d_in[18];
  const float* wo = (const float*)d_in[19];  const float* bo = (const float*)d_in[20];
  const float* er = (const float*)d_in[21];
  const float* ln2_g = (const float*)d_in[22];  const float* ln2_b = (const float*)d_in[23];
  const float* w1 = (const float*)d_in[24];  const float* b1 = (const float*)d_in[25];
  const float* w2 = (const float*)d_in[26];  const float* b2 = (const float*)d_in[27];
  const float* dw = (const float*)d_in[28];  const float* db = (const float*)d_in[29];

  // ---- workspace plan (byte offsets; peak 90.73 MB; ws >= 98.3MB confirmed) ----
  if (ws_size < 98304000ull) return;
  char* W = (char*)d_ws;
  bf16*  p1 = (bf16*) (W + 0);
  bf16*  p2 = (bf16*) (W + 49152000);
  bf16*  p3 = (bf16*) (W + 0);
  bf16*  p4 = (bf16*) (W + 24576000);
  bf16*  tk = (bf16*) (W + 49152000);
  float* xb = (float*)(W + 0);
  bf16*  xn = (bf16*) (W + 24576000);
  bf16*  qb = (bf16*) (W + 36864000);
  bf16*  kb = (bf16*) (W + 49152000);
  bf16*  vb = (bf16*) (W + 61440000);
  bf16*  ob = (bf16*) (W + 73728000);
  bf16*  hb = (bf16*) (W + 36864000);
  bf16*  wt = (bf16*) (W + 86016000);   // 4.72 MB weight scratch (bf16 [N][K])

  // ---- CNN stack ----
  conv_gelu_pool<float><<<dim3((96*T_+255)/256, B_*32), 256, 0, stream>>>(spec, cw1, cb1, p1,  1, 192, 32);
  conv_gelu_pool<bf16> <<<dim3((48*T_+255)/256, B_*64), 256, 0, stream>>>(p1,  cw2, cb2, p2, 32,  96, 64);
  conv_gelu_pool<bf16> <<<dim3((24*T_+255)/256, B_*64), 256, 0, stream>>>(p2,  cw3, cb3, p3, 64,  48, 64);
  conv_gelu_pool<bf16> <<<dim3((12*T_+255)/256, B_*64), 256, 0, stream>>>(p3,  cw4, cb4, p4, 64,  24, 64);

  transpose_ct<<<(B_*D_*T_ + 255)/256, 256, 0, stream>>>(p4, tk);

  transpose_w<<<dim3(D_/32, D_/32), 256, 0, stream>>>(proj_w, wt, D_, D_);
  mfma_gemm_k<0,0,0><<<dim3(6,63), 256, 0, stream>>>(tk, wt, proj_b, nullptr, xb, 8000, D_, D_);

  // ---- transformer layers ----
  for (int l = 0; l < 3; l++){
    const size_t wOff = (size_t)l*D_*D_;
    layernorm_k<<<8000, 256, 0, stream>>>(xb, ln1_g + l*D_, ln1_b + l*D_, xn);

    transpose_w<<<dim3(D_/32, D_/32), 256, 0, stream>>>(wq + wOff, wt, D_, D_);
    mfma_gemm_k<0,0,1><<<dim3(6,63), 256, 0, stream>>>(xn, wt, bq + l*D_, nullptr, qb, 8000, D_, D_);
    transpose_w<<<dim3(D_/32, D_/32), 256, 0, stream>>>(wk + wOff, wt, D_, D_);
    mfma_gemm_k<0,0,1><<<dim3(6,63), 256, 0, stream>>>(xn, wt, bk + l*D_, nullptr, kb, 8000, D_, D_);
    transpose_w<<<dim3(D_/32, D_/32), 256, 0, stream>>>(wv + wOff, wt, D_, D_);
    mfma_gemm_k<0,0,1><<<dim3(6,63), 256, 0, stream>>>(xn, wt, bv + l*D_, nullptr, vb, 8000, D_, D_);

    attn_simple_k<<<(B_*NH_*T_ + 3)/4, 256, 0, stream>>>(qb, kb, vb, er + (size_t)l*T_*DH_, ob);

    transpose_w<<<dim3(D_/32, D_/32), 256, 0, stream>>>(wo + wOff, wt, D_, D_);
    mfma_gemm_k<0,1,0><<<dim3(6,63), 256, 0, stream>>>(ob, wt, bo + l*D_, xb, xb, 8000, D_, D_);

    layernorm_k<<<8000, 256, 0, stream>>>(xb, ln2_g + l*D_, ln2_b + l*D_, xn);

    transpose_w<<<dim3(FFN_/32, D_/32), 256, 0, stream>>>(w1 + (size_t)l*D_*FFN_, wt, D_, FFN_);
    mfma_gemm_k<1,0,1><<<dim3(24,63), 256, 0, stream>>>(xn, wt, b1 + l*FFN_, nullptr, hb, 8000, FFN_, D_);
    transpose_w<<<dim3(D_/32, FFN_/32), 256, 0, stream>>>(w2 + (size_t)l*FFN_*D_, wt, FFN_, D_);
    mfma_gemm_k<0,1,0><<<dim3(6,63), 256, 0, stream>>>(hb, wt, b2 + l*D_, xb, xb, 8000, D_, FFN_);
  }

  // ---- deproj -> fp32 output [8000, 192] ----
  gemm_k<float,0,0,0><<<dim3(192/64, 125), 256, 0, stream>>>(xb, dw, db, nullptr, d_out, 8000, 192, D_);
}

// Round 6
// 13307.498 us; speedup vs baseline: 2.4474x; 2.0216x over previous
//
#include <hip/hip_runtime.h>
#include <hip/hip_bf16.h>

typedef __hip_bfloat16 bf16;
typedef __attribute__((ext_vector_type(8))) short bf16x8;
typedef __attribute__((ext_vector_type(4))) float f32x4;

#define B_   16
#define T_   500
#define D_   768
#define NH_  12
#define DH_  64
#define FFN_ 3072

__device__ __forceinline__ float bfu2f(unsigned short u){ return __uint_as_float(((unsigned)u)<<16); }
__device__ __forceinline__ float geluf(float x){ return 0.5f*x*(1.0f + erff(x*0.70710678118654752f)); }

__device__ __forceinline__ float4 ld4f(const float* p){ return *reinterpret_cast<const float4*>(p); }
__device__ __forceinline__ float4 ld4f(const bf16* p){
  ushort4 u = *reinterpret_cast<const ushort4*>(p);
  return make_float4(bfu2f(u.x), bfu2f(u.y), bfu2f(u.z), bfu2f(u.w));
}
__device__ __forceinline__ float ld1f(const float* p){ return *p; }
__device__ __forceinline__ float ld1f(const bf16* p){ return __bfloat162float(*p); }
__device__ __forceinline__ float2 ld2f(const float* p){ return *reinterpret_cast<const float2*>(p); }
__device__ __forceinline__ float2 ld2f(const bf16* p){
  ushort2 u = *reinterpret_cast<const ushort2*>(p);
  return make_float2(bfu2f(u.x), bfu2f(u.y));
}

// ---------------- conv 5x5 (pad 2) + exact GELU + maxpool(2,1) over H ----------------
// 4 x-positions per thread, 8-value register sliding window, vectorized loads.
template<typename Tin>
__global__ __launch_bounds__(256) void conv_gelu_pool(const Tin* __restrict__ in,
    const float* __restrict__ w, const float* __restrict__ bias, bf16* __restrict__ out,
    int Cin, int Hin, int Cout)
{
  const int Hout = Hin >> 1;
  const int bc = blockIdx.y;
  const int b = bc / Cout, oc = bc % Cout;

  __shared__ float wsm[64*25];
  for (int i = threadIdx.x; i < Cin*25; i += 256)
    wsm[i] = w[(size_t)oc*Cin*25 + i];
  __syncthreads();

  const int pos = blockIdx.x*256 + threadIdx.x;     // over Hout*125 x-groups
  if (pos >= Hout*125) return;
  const int xg = pos % 125, yo = pos / 125;
  const int x0 = xg * 4;
  const bool interior = (xg >= 1) && (xg <= 123);   // x0-2 >= 0 && x0+5 <= 499
  const float bv = bias[oc];
  float a0[4] = {bv,bv,bv,bv}, a1[4] = {bv,bv,bv,bv};
  const int y0 = 2*yo;

  for (int ci = 0; ci < Cin; ci++){
    const Tin* ip = in + ((size_t)(b*Cin + ci)*Hin)*T_;
    const float* wf = wsm + ci*25;
    #pragma unroll
    for (int r = 0; r < 6; r++){                    // union of the two pooled rows' taps
      const int yy = y0 - 2 + r;
      if (yy < 0 || yy >= Hin) continue;
      const Tin* rp = ip + (size_t)yy*T_;
      float v[8];
      if (interior){
        const float2 v01 = ld2f(rp + x0 - 2);
        const float2 v23 = ld2f(rp + x0);
        const float2 v45 = ld2f(rp + x0 + 2);
        const float2 v67 = ld2f(rp + x0 + 4);
        v[0]=v01.x; v[1]=v01.y; v[2]=v23.x; v[3]=v23.y;
        v[4]=v45.x; v[5]=v45.y; v[6]=v67.x; v[7]=v67.y;
      } else {
        #pragma unroll
        for (int j = 0; j < 8; j++){
          const int xx = x0 - 2 + j;
          v[j] = (xx >= 0 && xx < T_) ? ld1f(rp + xx) : 0.f;
        }
      }
      #pragma unroll
      for (int kx = 0; kx < 5; kx++){
        if (r < 5){
          const float w0 = wf[r*5 + kx];
          #pragma unroll
          for (int j = 0; j < 4; j++) a0[j] = fmaf(v[j+kx], w0, a0[j]);
        }
        if (r >= 1){
          const float w1 = wf[(r-1)*5 + kx];
          #pragma unroll
          for (int j = 0; j < 4; j++) a1[j] = fmaf(v[j+kx], w1, a1[j]);
        }
      }
    }
  }
  // pool AFTER gelu (gelu is not monotonic)
  bf16* op = out + ((size_t)bc*Hout + yo)*T_ + x0;
  ushort4 u;
  u.x = __bfloat16_as_ushort(__float2bfloat16(fmaxf(geluf(a0[0]), geluf(a1[0]))));
  u.y = __bfloat16_as_ushort(__float2bfloat16(fmaxf(geluf(a0[1]), geluf(a1[1]))));
  u.z = __bfloat16_as_ushort(__float2bfloat16(fmaxf(geluf(a0[2]), geluf(a1[2]))));
  u.w = __bfloat16_as_ushort(__float2bfloat16(fmaxf(geluf(a0[3]), geluf(a1[3]))));
  *reinterpret_cast<ushort4*>(op) = u;
}

// ---------------- transpose [B,768,T] -> [B*T, 768] ----------------
__global__ __launch_bounds__(256) void transpose_ct(const bf16* __restrict__ p4, bf16* __restrict__ tk)
{
  const int idx = blockIdx.x*256 + threadIdx.x;
  if (idx >= B_*D_*T_) return;
  const int t = idx % T_;
  const int c = (idx / T_) % D_;
  const int b = idx / (T_*D_);
  tk[((size_t)(b*T_ + t))*D_ + c] = p4[idx];
}

// ---------------- weight transpose+convert: fp32 [K][N] -> bf16 [N][K] ----------------
__global__ __launch_bounds__(256) void transpose_w(const float* __restrict__ W,
    bf16* __restrict__ out, int K, int N)
{
  __shared__ float tile[32][33];
  const int gk = blockIdx.y*32, gn = blockIdx.x*32;
  const int tr = threadIdx.x >> 5, tc = threadIdx.x & 31;
  #pragma unroll
  for (int i = 0; i < 4; i++)
    tile[tr + i*8][tc] = W[(size_t)(gk + tr + i*8)*N + gn + tc];
  __syncthreads();
  #pragma unroll
  for (int i = 0; i < 4; i++)
    out[(size_t)(gn + tr + i*8)*K + gk + tc] = __float2bfloat16(tile[tc][tr + i*8]);
}

// ---------------- MFMA GEMM: C = act(A[MxK](bf16) @ Bt[NxK]^T(bf16) + bias) (+resid) ----------------
template<int ACT, int RESID, int BF16OUT>
__global__ __launch_bounds__(256) void mfma_gemm_k(const bf16* __restrict__ A,
    const bf16* __restrict__ Bt, const float* __restrict__ bias,
    const float* __restrict__ resid, void* __restrict__ Cout, int M, int N, int K)
{
  __shared__ uint4 Alds[512];
  __shared__ uint4 Blds[512];

  const int tid = threadIdx.x;
  const int wid = tid >> 6, lane = tid & 63;
  const int wr = wid >> 1, wc = wid & 1;
  const int bm = blockIdx.y*128, bn = blockIdx.x*128;

  const int g0 = tid >> 7;
  const int r0 = tid & 127;
  const int arow = min(bm + r0, M-1);
  const int brow = bn + r0;
  const int lg = lane >> 4, lr = lane & 15;

  f32x4 acc[4][4];
  #pragma unroll
  for (int i = 0; i < 4; i++)
    #pragma unroll
    for (int j = 0; j < 4; j++)
      acc[i][j] = (f32x4){0.f,0.f,0.f,0.f};

  for (int k0 = 0; k0 < K; k0 += 32){
    const uint4 av0 = *reinterpret_cast<const uint4*>(A  + (size_t)arow*K + k0 + g0*8);
    const uint4 av1 = *reinterpret_cast<const uint4*>(A  + (size_t)arow*K + k0 + (g0+2)*8);
    const uint4 bv0 = *reinterpret_cast<const uint4*>(Bt + (size_t)brow*K + k0 + g0*8);
    const uint4 bv1 = *reinterpret_cast<const uint4*>(Bt + (size_t)brow*K + k0 + (g0+2)*8);
    __syncthreads();
    Alds[g0*128 + r0] = av0;  Alds[(g0+2)*128 + r0] = av1;
    Blds[g0*128 + r0] = bv0;  Blds[(g0+2)*128 + r0] = bv1;
    __syncthreads();

    bf16x8 af[4], bfr[4];
    #pragma unroll
    for (int mf = 0; mf < 4; mf++)
      af[mf] = *reinterpret_cast<const bf16x8*>(&Alds[lg*128 + wr*64 + mf*16 + lr]);
    #pragma unroll
    for (int nf = 0; nf < 4; nf++)
      bfr[nf] = *reinterpret_cast<const bf16x8*>(&Blds[lg*128 + wc*64 + nf*16 + lr]);

    #pragma unroll
    for (int mf = 0; mf < 4; mf++)
      #pragma unroll
      for (int nf = 0; nf < 4; nf++)
        acc[mf][nf] = __builtin_amdgcn_mfma_f32_16x16x32_bf16(af[mf], bfr[nf], acc[mf][nf], 0, 0, 0);
  }

  #pragma unroll
  for (int mf = 0; mf < 4; mf++){
    #pragma unroll
    for (int rg = 0; rg < 4; rg++){
      const int row = bm + wr*64 + mf*16 + (lane>>4)*4 + rg;
      if (row >= M) continue;
      #pragma unroll
      for (int nf = 0; nf < 4; nf++){
        const int col = bn + wc*64 + nf*16 + (lane&15);
        float v = acc[mf][nf][rg] + bias[col];
        if (ACT == 1) v = geluf(v);
        if (RESID)    v += resid[(size_t)row*N + col];
        if (BF16OUT)  reinterpret_cast<bf16*>(Cout)[(size_t)row*N + col] = __float2bfloat16(v);
        else          reinterpret_cast<float*>(Cout)[(size_t)row*N + col] = v;
      }
    }
  }
}

// ---------------- fp32 fallback GEMM (deproj: N=192) ----------------
template<typename TA, int ACT, int RESID, int BF16OUT>
__global__ __launch_bounds__(256) void gemm_k(const TA* __restrict__ A,
    const float* __restrict__ Bw, const float* __restrict__ bias,
    const float* __restrict__ resid, void* __restrict__ Cout, int M, int N, int K)
{
  __shared__ float As[16][65];
  __shared__ float Bs[16][65];
  const int bm = blockIdx.y*64, bn = blockIdx.x*64;
  const int tid = threadIdx.x;
  const int tr = tid >> 4, tc = tid & 15;

  const int am  = tid >> 2;
  const int ak4 = tid & 3;
  const int bk  = tid >> 4;
  const int bn4 = tid & 15;

  float acc[4][4] = {{0.f}};

  for (int k0 = 0; k0 < K; k0 += 16){
    const float4 av = ld4f(A + (size_t)(bm + am)*K + k0 + ak4*4);
    As[ak4*4+0][am] = av.x; As[ak4*4+1][am] = av.y;
    As[ak4*4+2][am] = av.z; As[ak4*4+3][am] = av.w;

    const float4 bv = ld4f(Bw + (size_t)(k0 + bk)*N + bn + bn4*4);
    Bs[bk][bn4*4+0] = bv.x; Bs[bk][bn4*4+1] = bv.y;
    Bs[bk][bn4*4+2] = bv.z; Bs[bk][bn4*4+3] = bv.w;
    __syncthreads();

    #pragma unroll
    for (int k = 0; k < 16; k++){
      float a[4], bb_[4];
      #pragma unroll
      for (int i = 0; i < 4; i++) a[i]  = As[k][tr*4 + i];
      #pragma unroll
      for (int j = 0; j < 4; j++) bb_[j] = Bs[k][tc*4 + j];
      #pragma unroll
      for (int i = 0; i < 4; i++)
        #pragma unroll
        for (int j = 0; j < 4; j++)
          acc[i][j] = fmaf(a[i], bb_[j], acc[i][j]);
    }
    __syncthreads();
  }

  #pragma unroll
  for (int i = 0; i < 4; i++){
    const int row = bm + tr*4 + i;
    #pragma unroll
    for (int j = 0; j < 4; j++){
      const int col = bn + tc*4 + j;
      float v = acc[i][j] + bias[col];
      if (ACT == 1) v = geluf(v);
      if (RESID)    v += resid[(size_t)row*N + col];
      if (BF16OUT)  reinterpret_cast<bf16*>(Cout)[(size_t)row*N + col] = __float2bfloat16(v);
      else          reinterpret_cast<float*>(Cout)[(size_t)row*N + col] = v;
    }
  }
}

// ---------------- LayerNorm over D=768: fp32 in -> bf16 out ----------------
__global__ __launch_bounds__(256) void layernorm_k(const float* __restrict__ x,
    const float* __restrict__ g, const float* __restrict__ bb, bf16* __restrict__ out)
{
  const int row = blockIdx.x;
  const float* xr = x + (size_t)row*D_;
  const int tid = threadIdx.x;
  const float v0 = xr[tid], v1 = xr[tid+256], v2 = xr[tid+512];

  float s = v0 + v1 + v2;
  #pragma unroll
  for (int o = 32; o > 0; o >>= 1) s += __shfl_xor(s, o);
  __shared__ float sm[4];
  const int wid = tid >> 6, lane = tid & 63;
  if (lane == 0) sm[wid] = s;
  __syncthreads();
  const float mean = (sm[0]+sm[1]+sm[2]+sm[3]) * (1.f/768.f);
  __syncthreads();

  const float d0 = v0-mean, d1 = v1-mean, d2 = v2-mean;
  float ss = d0*d0 + d1*d1 + d2*d2;
  #pragma unroll
  for (int o = 32; o > 0; o >>= 1) ss += __shfl_xor(ss, o);
  if (lane == 0) sm[wid] = ss;
  __syncthreads();
  const float var = (sm[0]+sm[1]+sm[2]+sm[3]) * (1.f/768.f);
  const float inv = rsqrtf(var + 1e-5f);

  bf16* orow = out + (size_t)row*D_;
  orow[tid]     = __float2bfloat16(d0*inv*g[tid]     + bb[tid]);
  orow[tid+256] = __float2bfloat16(d1*inv*g[tid+256] + bb[tid+256]);
  orow[tid+512] = __float2bfloat16(d2*inv*g[tid+512] + bb[tid+512]);
}

// ---------------- fused flash attention with exact skew-srel ----------------
// srel[q,k]: k<=q -> q[q].er[499-(q-k)] ; k==q+1 -> 0 ; k>q+1 -> q[q+1].er[k-q-2]
// grid: (32 q-tiles of 16, B*NH). block 256 = 16 q-rows x 16 k-cols.
#define LDW 68
__global__ __launch_bounds__(256) void flash_attn_k(const bf16* __restrict__ qb,
    const bf16* __restrict__ kb, const bf16* __restrict__ vb,
    const float* __restrict__ er, bf16* __restrict__ ob)
{
  const int b = blockIdx.y / NH_, h = blockIdx.y % NH_;
  const int q0 = blockIdx.x * 16;
  const int tid = threadIdx.x;
  const int qr = tid >> 4, kc = tid & 15;
  const int q  = q0 + qr;
  const bool qvalid = (q < T_);

  __shared__ float qs[17][LDW];
  __shared__ float ks[16][LDW];
  __shared__ float vs[16][LDW];

  // load q rows q0..q0+16 (one extra for the k>q+1 branch)
  for (int i = tid; i < 17*16; i += 256){
    const int r = i >> 4, d4 = (i & 15) * 4;
    const int qq = q0 + r;
    float4 v = (qq < T_) ? ld4f(qb + ((size_t)(b*T_ + qq))*D_ + h*DH_ + d4)
                         : make_float4(0.f,0.f,0.f,0.f);
    qs[r][d4+0]=v.x; qs[r][d4+1]=v.y; qs[r][d4+2]=v.z; qs[r][d4+3]=v.w;
  }

  float m = -3.0e38f, l = 0.f;
  float oacc[4] = {0.f,0.f,0.f,0.f};

  for (int k0 = 0; k0 < T_; k0 += 16){
    __syncthreads();
    {   // cooperative K/V chunk load
      const int r = tid >> 4, d4 = (tid & 15) * 4;
      const int kk = k0 + r;
      float4 kv = (kk < T_) ? ld4f(kb + ((size_t)(b*T_ + kk))*D_ + h*DH_ + d4)
                            : make_float4(0.f,0.f,0.f,0.f);
      float4 vv = (kk < T_) ? ld4f(vb + ((size_t)(b*T_ + kk))*D_ + h*DH_ + d4)
                            : make_float4(0.f,0.f,0.f,0.f);
      ks[r][d4+0]=kv.x; ks[r][d4+1]=kv.y; ks[r][d4+2]=kv.z; ks[r][d4+3]=kv.w;
      vs[r][d4+0]=vv.x; vs[r][d4+1]=vv.y; vs[r][d4+2]=vv.z; vs[r][d4+3]=vv.w;
    }
    __syncthreads();

    const int k = k0 + kc;
    const bool kvalid = (k < T_);
    float s = -3.0e38f;
    if (qvalid && kvalid){
      const float4* q4 = reinterpret_cast<const float4*>(&qs[qr][0]);
      const float4* k4 = reinterpret_cast<const float4*>(&ks[kc][0]);
      float d1 = 0.f;
      #pragma unroll
      for (int i = 0; i < 16; i++){
        const float4 a = q4[i], c = k4[i];
        d1 = fmaf(a.x,c.x, fmaf(a.y,c.y, fmaf(a.z,c.z, fmaf(a.w,c.w, d1))));
      }
      float d2 = 0.f;
      if (k != q + 1){
        const int eidx = (k <= q) ? (499 - q + k) : (k - q - 2);
        const float4* t4 = reinterpret_cast<const float4*>(&qs[qr + ((k <= q) ? 0 : 1)][0]);
        const float* e = er + (size_t)eidx * DH_;
        #pragma unroll
        for (int i = 0; i < 16; i++){
          const float4 a = t4[i];
          const float4 ev = ld4f(e + i*4);
          d2 = fmaf(a.x,ev.x, fmaf(a.y,ev.y, fmaf(a.z,ev.z, fmaf(a.w,ev.w, d2))));
        }
      }
      s = (d1 + d2) * 0.125f;
    }

    // online softmax across this row's 16 lanes
    float mx = s;
    #pragma unroll
    for (int o = 8; o > 0; o >>= 1) mx = fmaxf(mx, __shfl_xor(mx, o, 16));
    const float mn = fmaxf(m, mx);
    const float p = kvalid ? __expf(s - mn) : 0.f;
    const float corr = __expf(m - mn);
    float ps = p;
    #pragma unroll
    for (int o = 8; o > 0; o >>= 1) ps += __shfl_xor(ps, o, 16);
    l = l*corr + ps;
    m = mn;
    #pragma unroll
    for (int j = 0; j < 4; j++) oacc[j] *= corr;

    #pragma unroll
    for (int kc2 = 0; kc2 < 16; kc2++){
      const float pk = __shfl(p, kc2, 16);
      const float4 vv = *reinterpret_cast<const float4*>(&vs[kc2][kc*4]);
      oacc[0] = fmaf(pk, vv.x, oacc[0]);
      oacc[1] = fmaf(pk, vv.y, oacc[1]);
      oacc[2] = fmaf(pk, vv.z, oacc[2]);
      oacc[3] = fmaf(pk, vv.w, oacc[3]);
    }
  }

  if (qvalid){
    const float inv = 1.f / l;
    bf16* op = ob + ((size_t)(b*T_ + q))*D_ + h*DH_ + kc*4;
    ushort4 u;
    u.x = __bfloat16_as_ushort(__float2bfloat16(oacc[0]*inv));
    u.y = __bfloat16_as_ushort(__float2bfloat16(oacc[1]*inv));
    u.z = __bfloat16_as_ushort(__float2bfloat16(oacc[2]*inv));
    u.w = __bfloat16_as_ushort(__float2bfloat16(oacc[3]*inv));
    *reinterpret_cast<ushort4*>(op) = u;
  }
}

// =====================================================================
extern "C" void kernel_launch(void* const* d_in, const int* in_sizes, int n_in,
                              void* d_out, int out_size, void* d_ws, size_t ws_size,
                              hipStream_t stream)
{
  const float* spec  = (const float*)d_in[0];
  const float* cw1 = (const float*)d_in[1];  const float* cb1 = (const float*)d_in[2];
  const float* cw2 = (const float*)d_in[3];  const float* cb2 = (const float*)d_in[4];
  const float* cw3 = (const float*)d_in[5];  const float* cb3 = (const float*)d_in[6];
  const float* cw4 = (const float*)d_in[7];  const float* cb4 = (const float*)d_in[8];
  const float* proj_w = (const float*)d_in[9];  const float* proj_b = (const float*)d_in[10];
  const float* ln1_g = (const float*)d_in[11];  const float* ln1_b = (const float*)d_in[12];
  const float* wq = (const float*)d_in[13];  const float* bq = (const float*)d_in[14];
  const float* wk = (const float*)d_in[15];  const float* bk = (const float*)d_in[16];
  const float* wv = (const float*)d_in[17];  const float* bv = (const float*)d_in[18];
  const float* wo = (const float*)d_in[19];  const float* bo = (const float*)d_in[20];
  const float* er = (const float*)d_in[21];
  const float* ln2_g = (const float*)d_in[22];  const float* ln2_b = (const float*)d_in[23];
  const float* w1 = (const float*)d_in[24];  const float* b1 = (const float*)d_in[25];
  const float* w2 = (const float*)d_in[26];  const float* b2 = (const float*)d_in[27];
  const float* dw = (const float*)d_in[28];  const float* db = (const float*)d_in[29];

  if (ws_size < 98304000ull) return;
  char* W = (char*)d_ws;
  bf16*  p1 = (bf16*) (W + 0);
  bf16*  p2 = (bf16*) (W + 49152000);
  bf16*  p3 = (bf16*) (W + 0);
  bf16*  p4 = (bf16*) (W + 24576000);
  bf16*  tk = (bf16*) (W + 49152000);
  float* xb = (float*)(W + 0);
  bf16*  xn = (bf16*) (W + 24576000);
  bf16*  qb = (bf16*) (W + 36864000);
  bf16*  kb = (bf16*) (W + 49152000);
  bf16*  vb = (bf16*) (W + 61440000);
  bf16*  ob = (bf16*) (W + 73728000);
  bf16*  hb = (bf16*) (W + 36864000);
  bf16*  wt = (bf16*) (W + 86016000);

  // ---- CNN stack ----
  conv_gelu_pool<float><<<dim3((96*125+255)/256, B_*32), 256, 0, stream>>>(spec, cw1, cb1, p1,  1, 192, 32);
  conv_gelu_pool<bf16> <<<dim3((48*125+255)/256, B_*64), 256, 0, stream>>>(p1,  cw2, cb2, p2, 32,  96, 64);
  conv_gelu_pool<bf16> <<<dim3((24*125+255)/256, B_*64), 256, 0, stream>>>(p2,  cw3, cb3, p3, 64,  48, 64);
  conv_gelu_pool<bf16> <<<dim3((12*125+255)/256, B_*64), 256, 0, stream>>>(p3,  cw4, cb4, p4, 64,  24, 64);

  transpose_ct<<<(B_*D_*T_ + 255)/256, 256, 0, stream>>>(p4, tk);

  transpose_w<<<dim3(D_/32, D_/32), 256, 0, stream>>>(proj_w, wt, D_, D_);
  mfma_gemm_k<0,0,0><<<dim3(6,63), 256, 0, stream>>>(tk, wt, proj_b, nullptr, xb, 8000, D_, D_);

  // ---- transformer layers ----
  for (int l = 0; l < 3; l++){
    const size_t wOff = (size_t)l*D_*D_;
    layernorm_k<<<8000, 256, 0, stream>>>(xb, ln1_g + l*D_, ln1_b + l*D_, xn);

    transpose_w<<<dim3(D_/32, D_/32), 256, 0, stream>>>(wq + wOff, wt, D_, D_);
    mfma_gemm_k<0,0,1><<<dim3(6,63), 256, 0, stream>>>(xn, wt, bq + l*D_, nullptr, qb, 8000, D_, D_);
    transpose_w<<<dim3(D_/32, D_/32), 256, 0, stream>>>(wk + wOff, wt, D_, D_);
    mfma_gemm_k<0,0,1><<<dim3(6,63), 256, 0, stream>>>(xn, wt, bk + l*D_, nullptr, kb, 8000, D_, D_);
    transpose_w<<<dim3(D_/32, D_/32), 256, 0, stream>>>(wv + wOff, wt, D_, D_);
    mfma_gemm_k<0,0,1><<<dim3(6,63), 256, 0, stream>>>(xn, wt, bv + l*D_, nullptr, vb, 8000, D_, D_);

    flash_attn_k<<<dim3(32, B_*NH_), 256, 0, stream>>>(qb, kb, vb, er + (size_t)l*T_*DH_, ob);

    transpose_w<<<dim3(D_/32, D_/32), 256, 0, stream>>>(wo + wOff, wt, D_, D_);
    mfma_gemm_k<0,1,0><<<dim3(6,63), 256, 0, stream>>>(ob, wt, bo + l*D_, xb, xb, 8000, D_, D_);

    layernorm_k<<<8000, 256, 0, stream>>>(xb, ln2_g + l*D_, ln2_b + l*D_, xn);

    transpose_w<<<dim3(FFN_/32, D_/32), 256, 0, stream>>>(w1 + (size_t)l*D_*FFN_, wt, D_, FFN_);
    mfma_gemm_k<1,0,1><<<dim3(24,63), 256, 0, stream>>>(xn, wt, b1 + l*FFN_, nullptr, hb, 8000, FFN_, D_);
    transpose_w<<<dim3(D_/32, FFN_/32), 256, 0, stream>>>(w2 + (size_t)l*FFN_*D_, wt, FFN_, D_);
    mfma_gemm_k<0,1,0><<<dim3(6,63), 256, 0, stream>>>(hb, wt, b2 + l*D_, xb, xb, 8000, D_, FFN_);
  }

  // ---- deproj -> fp32 output [8000, 192] ----
  gemm_k<float,0,0,0><<<dim3(192/64, 125), 256, 0, stream>>>(xb, dw, db, nullptr, d_out, 8000, 192, D_);
}

// Round 7
// 7393.265 us; speedup vs baseline: 4.4051x; 1.7999x over previous
//
#include <hip/hip_runtime.h>
#include <hip/hip_bf16.h>

typedef __hip_bfloat16 bf16;
typedef __attribute__((ext_vector_type(8))) short bf16x8;
typedef __attribute__((ext_vector_type(4))) float f32x4;

#define B_   16
#define T_   500
#define D_   768
#define NH_  12
#define DH_  64
#define FFN_ 3072

__device__ __forceinline__ float bfu2f(unsigned short u){ return __uint_as_float(((unsigned)u)<<16); }
__device__ __forceinline__ float geluf(float x){ return 0.5f*x*(1.0f + erff(x*0.70710678118654752f)); }

__device__ __forceinline__ float4 ld4f(const float* p){ return *reinterpret_cast<const float4*>(p); }
__device__ __forceinline__ float4 ld4f(const bf16* p){
  ushort4 u = *reinterpret_cast<const ushort4*>(p);
  return make_float4(bfu2f(u.x), bfu2f(u.y), bfu2f(u.z), bfu2f(u.w));
}

// ---------------- conv1: Cin=1, 32 oc per thread, writes NHWC [b][96][500][32] ----------------
__global__ __launch_bounds__(256) void conv1_k(const float* __restrict__ spec,
    const float* __restrict__ w, const float* __restrict__ bias, bf16* __restrict__ out)
{
  const int pos = blockIdx.x*256 + threadIdx.x;
  if (pos >= B_*96*500) return;
  const int x  = pos % 500;
  const int yo = (pos/500) % 96;
  const int b  = pos/(500*96);
  const float* ip = spec + (size_t)b*192*500;

  float v[6][5];
  #pragma unroll
  for (int r = 0; r < 6; r++){
    const int yy = 2*yo - 2 + r;
    const bool vy = (yy >= 0) && (yy < 192);
    const float* rp = ip + (size_t)(vy ? yy : 0)*500;
    #pragma unroll
    for (int c = 0; c < 5; c++){
      const int xx = x - 2 + c;
      v[r][c] = (vy && xx >= 0 && xx < 500) ? rp[xx] : 0.f;
    }
  }

  const size_t obase = (((size_t)(b*96 + yo))*500 + x)*32;
  #pragma unroll
  for (int oc = 0; oc < 32; oc++){
    float a0 = bias[oc], a1 = bias[oc];
    #pragma unroll
    for (int r = 0; r < 5; r++)
      #pragma unroll
      for (int c = 0; c < 5; c++){
        const float wv = w[oc*25 + r*5 + c];
        a0 = fmaf(v[r][c],   wv, a0);
        a1 = fmaf(v[r+1][c], wv, a1);
      }
    out[obase + oc] = __float2bfloat16(fmaxf(geluf(a0), geluf(a1)));
  }
}

// ---------------- conv weight transpose: fp32 OIHW [64][Cin][5][5] -> bf16 [tap][oc][ci] ----------------
__global__ __launch_bounds__(256) void conv_wt_k(const float* __restrict__ w,
    bf16* __restrict__ wt, int Cin)
{
  const int idx = blockIdx.x*256 + threadIdx.x;
  if (idx >= 25*64*Cin) return;
  const int ci  = idx % Cin;
  const int oc  = (idx/Cin) % 64;
  const int tap = idx/(Cin*64);
  wt[idx] = __float2bfloat16(w[(size_t)(oc*Cin + ci)*25 + tap]);
}

// ---------------- MFMA conv (Cin=32/64, Cout=64) + GELU + pool, NHWC in/out ----------------
// Block: one pooled output row (conv rows 2yo,2yo+1) x 64-x chunk x 64 oc. No LDS.
// A-frag: lane row = x-position, 8 consecutive ci (contiguous NHWC). B: wt[tap][oc][ci].
template<int CIN>
__global__ __launch_bounds__(256) void conv_mfma_k(const bf16* __restrict__ in,
    const bf16* __restrict__ wt, const float* __restrict__ bias,
    bf16* __restrict__ out, int Hin)
{
  const int Hout = Hin >> 1;
  const int x0 = blockIdx.x * 64;
  const int yo = blockIdx.y % Hout;
  const int b  = blockIdx.y / Hout;
  const int tid = threadIdx.x, w = tid >> 6, lane = tid & 63;
  const int lr = lane & 15, kb = lane >> 4;
  const int xl = w*16 + lr;          // this wave's x within chunk (A-frag rows)
  const int xg = x0 + xl;

  f32x4 acc0[4], acc1[4];
  #pragma unroll
  for (int nf = 0; nf < 4; nf++){ acc0[nf] = (f32x4){0,0,0,0}; acc1[nf] = (f32x4){0,0,0,0}; }

  for (int ky = 0; ky < 5; ky++){
    const int yy0 = 2*yo + ky - 2;
    const int yy1 = yy0 + 1;
    const bool v0 = (yy0 >= 0) && (yy0 < Hin);
    const bool v1 = (yy1 >= 0) && (yy1 < Hin);
    #pragma unroll
    for (int kx = 0; kx < 5; kx++){
      const int xx = xg + kx - 2;
      const bool vx = (xx >= 0) && (xx < 500);
      const int tap = ky*5 + kx;
      #pragma unroll
      for (int c0 = 0; c0 < CIN; c0 += 32){
        bf16x8 bfr[4];
        #pragma unroll
        for (int nf = 0; nf < 4; nf++)
          bfr[nf] = *reinterpret_cast<const bf16x8*>(wt + ((size_t)(tap*64 + nf*16 + lr))*CIN + c0 + kb*8);

        bf16x8 a0 = {0,0,0,0,0,0,0,0}, a1 = {0,0,0,0,0,0,0,0};
        if (vx){
          if (v0) a0 = *reinterpret_cast<const bf16x8*>(in + (((size_t)(b*Hin + yy0))*500 + xx)*CIN + c0 + kb*8);
          if (v1) a1 = *reinterpret_cast<const bf16x8*>(in + (((size_t)(b*Hin + yy1))*500 + xx)*CIN + c0 + kb*8);
        }
        #pragma unroll
        for (int nf = 0; nf < 4; nf++){
          acc0[nf] = __builtin_amdgcn_mfma_f32_16x16x32_bf16(a0, bfr[nf], acc0[nf], 0, 0, 0);
          acc1[nf] = __builtin_amdgcn_mfma_f32_16x16x32_bf16(a1, bfr[nf], acc1[nf], 0, 0, 0);
        }
      }
    }
  }

  // epilogue: C/D row = kb*4+rg (x), col = lr (oc). pool(gelu) the two conv rows.
  #pragma unroll
  for (int rg = 0; rg < 4; rg++){
    const int xs = x0 + w*16 + kb*4 + rg;
    if (xs < 500){
      const size_t obase = (((size_t)(b*Hout + yo))*500 + xs)*64;
      #pragma unroll
      for (int nf = 0; nf < 4; nf++){
        const int oc = nf*16 + lr;
        const float bv = bias[oc];
        const float p0 = geluf(acc0[nf][rg] + bv);
        const float p1 = geluf(acc1[nf][rg] + bv);
        out[obase + oc] = __float2bfloat16(fmaxf(p0, p1));
      }
    }
  }
}

// ---------------- tokens: NHWC conv4 out [b][12][500][64] -> tk[b*T+t][ci*12+yo] ----------------
__global__ __launch_bounds__(256) void tokens_k(const bf16* __restrict__ n4, bf16* __restrict__ tk)
{
  const int idx = blockIdx.x*256 + threadIdx.x;
  if (idx >= B_*12*500*64) return;
  const int ci = idx & 63;
  const int t  = (idx >> 6) % 500;
  const int yo = (idx >> 6) / 500 % 12;
  const int b  = idx / (64*500*12);
  tk[((size_t)(b*500 + t))*768 + ci*12 + yo] = n4[idx];
}

// ---------------- weight transpose+convert: fp32 [K][N] -> bf16 [N][K] ----------------
__global__ __launch_bounds__(256) void transpose_w(const float* __restrict__ W,
    bf16* __restrict__ out, int K, int N)
{
  __shared__ float tile[32][33];
  const int gk = blockIdx.y*32, gn = blockIdx.x*32;
  const int tr = threadIdx.x >> 5, tc = threadIdx.x & 31;
  #pragma unroll
  for (int i = 0; i < 4; i++)
    tile[tr + i*8][tc] = W[(size_t)(gk + tr + i*8)*N + gn + tc];
  __syncthreads();
  #pragma unroll
  for (int i = 0; i < 4; i++)
    out[(size_t)(gn + tr + i*8)*K + gk + tc] = __float2bfloat16(tile[tc][tr + i*8]);
}

// ---------------- MFMA GEMM: C = act(A[MxK](bf16) @ Bt[NxK]^T(bf16) + bias) (+resid) ----------------
template<int ACT, int RESID, int BF16OUT>
__global__ __launch_bounds__(256) void mfma_gemm_k(const bf16* __restrict__ A,
    const bf16* __restrict__ Bt, const float* __restrict__ bias,
    const float* __restrict__ resid, void* __restrict__ Cout, int M, int N, int K)
{
  __shared__ uint4 Alds[512];
  __shared__ uint4 Blds[512];

  const int tid = threadIdx.x;
  const int wid = tid >> 6, lane = tid & 63;
  const int wr = wid >> 1, wc = wid & 1;
  const int bm = blockIdx.y*128, bn = blockIdx.x*128;

  const int g0 = tid >> 7;
  const int r0 = tid & 127;
  const int arow = min(bm + r0, M-1);
  const int brow = bn + r0;
  const int lg = lane >> 4, lr = lane & 15;

  f32x4 acc[4][4];
  #pragma unroll
  for (int i = 0; i < 4; i++)
    #pragma unroll
    for (int j = 0; j < 4; j++)
      acc[i][j] = (f32x4){0.f,0.f,0.f,0.f};

  for (int k0 = 0; k0 < K; k0 += 32){
    const uint4 av0 = *reinterpret_cast<const uint4*>(A  + (size_t)arow*K + k0 + g0*8);
    const uint4 av1 = *reinterpret_cast<const uint4*>(A  + (size_t)arow*K + k0 + (g0+2)*8);
    const uint4 bv0 = *reinterpret_cast<const uint4*>(Bt + (size_t)brow*K + k0 + g0*8);
    const uint4 bv1 = *reinterpret_cast<const uint4*>(Bt + (size_t)brow*K + k0 + (g0+2)*8);
    __syncthreads();
    Alds[g0*128 + r0] = av0;  Alds[(g0+2)*128 + r0] = av1;
    Blds[g0*128 + r0] = bv0;  Blds[(g0+2)*128 + r0] = bv1;
    __syncthreads();

    bf16x8 af[4], bfr[4];
    #pragma unroll
    for (int mf = 0; mf < 4; mf++)
      af[mf] = *reinterpret_cast<const bf16x8*>(&Alds[lg*128 + wr*64 + mf*16 + lr]);
    #pragma unroll
    for (int nf = 0; nf < 4; nf++)
      bfr[nf] = *reinterpret_cast<const bf16x8*>(&Blds[lg*128 + wc*64 + nf*16 + lr]);

    #pragma unroll
    for (int mf = 0; mf < 4; mf++)
      #pragma unroll
      for (int nf = 0; nf < 4; nf++)
        acc[mf][nf] = __builtin_amdgcn_mfma_f32_16x16x32_bf16(af[mf], bfr[nf], acc[mf][nf], 0, 0, 0);
  }

  #pragma unroll
  for (int mf = 0; mf < 4; mf++){
    #pragma unroll
    for (int rg = 0; rg < 4; rg++){
      const int row = bm + wr*64 + mf*16 + (lane>>4)*4 + rg;
      if (row >= M) continue;
      #pragma unroll
      for (int nf = 0; nf < 4; nf++){
        const int col = bn + wc*64 + nf*16 + (lane&15);
        float v = acc[mf][nf][rg] + bias[col];
        if (ACT == 1) v = geluf(v);
        if (RESID)    v += resid[(size_t)row*N + col];
        if (BF16OUT)  reinterpret_cast<bf16*>(Cout)[(size_t)row*N + col] = __float2bfloat16(v);
        else          reinterpret_cast<float*>(Cout)[(size_t)row*N + col] = v;
      }
    }
  }
}

// ---------------- fp32 fallback GEMM (deproj: N=192) ----------------
template<typename TA, int ACT, int RESID, int BF16OUT>
__global__ __launch_bounds__(256) void gemm_k(const TA* __restrict__ A,
    const float* __restrict__ Bw, const float* __restrict__ bias,
    const float* __restrict__ resid, void* __restrict__ Cout, int M, int N, int K)
{
  __shared__ float As[16][65];
  __shared__ float Bs[16][65];
  const int bm = blockIdx.y*64, bn = blockIdx.x*64;
  const int tid = threadIdx.x;
  const int tr = tid >> 4, tc = tid & 15;

  const int am  = tid >> 2;
  const int ak4 = tid & 3;
  const int bk  = tid >> 4;
  const int bn4 = tid & 15;

  float acc[4][4] = {{0.f}};

  for (int k0 = 0; k0 < K; k0 += 16){
    const float4 av = ld4f(A + (size_t)(bm + am)*K + k0 + ak4*4);
    As[ak4*4+0][am] = av.x; As[ak4*4+1][am] = av.y;
    As[ak4*4+2][am] = av.z; As[ak4*4+3][am] = av.w;

    const float4 bv = ld4f(Bw + (size_t)(k0 + bk)*N + bn + bn4*4);
    Bs[bk][bn4*4+0] = bv.x; Bs[bk][bn4*4+1] = bv.y;
    Bs[bk][bn4*4+2] = bv.z; Bs[bk][bn4*4+3] = bv.w;
    __syncthreads();

    #pragma unroll
    for (int k = 0; k < 16; k++){
      float a[4], bb_[4];
      #pragma unroll
      for (int i = 0; i < 4; i++) a[i]  = As[k][tr*4 + i];
      #pragma unroll
      for (int j = 0; j < 4; j++) bb_[j] = Bs[k][tc*4 + j];
      #pragma unroll
      for (int i = 0; i < 4; i++)
        #pragma unroll
        for (int j = 0; j < 4; j++)
          acc[i][j] = fmaf(a[i], bb_[j], acc[i][j]);
    }
    __syncthreads();
  }

  #pragma unroll
  for (int i = 0; i < 4; i++){
    const int row = bm + tr*4 + i;
    #pragma unroll
    for (int j = 0; j < 4; j++){
      const int col = bn + tc*4 + j;
      float v = acc[i][j] + bias[col];
      if (ACT == 1) v = geluf(v);
      if (RESID)    v += resid[(size_t)row*N + col];
      if (BF16OUT)  reinterpret_cast<bf16*>(Cout)[(size_t)row*N + col] = __float2bfloat16(v);
      else          reinterpret_cast<float*>(Cout)[(size_t)row*N + col] = v;
    }
  }
}

// ---------------- LayerNorm over D=768: fp32 in -> bf16 out ----------------
__global__ __launch_bounds__(256) void layernorm_k(const float* __restrict__ x,
    const float* __restrict__ g, const float* __restrict__ bb, bf16* __restrict__ out)
{
  const int row = blockIdx.x;
  const float* xr = x + (size_t)row*D_;
  const int tid = threadIdx.x;
  const float v0 = xr[tid], v1 = xr[tid+256], v2 = xr[tid+512];

  float s = v0 + v1 + v2;
  #pragma unroll
  for (int o = 32; o > 0; o >>= 1) s += __shfl_xor(s, o);
  __shared__ float sm[4];
  const int wid = tid >> 6, lane = tid & 63;
  if (lane == 0) sm[wid] = s;
  __syncthreads();
  const float mean = (sm[0]+sm[1]+sm[2]+sm[3]) * (1.f/768.f);
  __syncthreads();

  const float d0 = v0-mean, d1 = v1-mean, d2 = v2-mean;
  float ss = d0*d0 + d1*d1 + d2*d2;
  #pragma unroll
  for (int o = 32; o > 0; o >>= 1) ss += __shfl_xor(ss, o);
  if (lane == 0) sm[wid] = ss;
  __syncthreads();
  const float var = (sm[0]+sm[1]+sm[2]+sm[3]) * (1.f/768.f);
  const float inv = rsqrtf(var + 1e-5f);

  bf16* orow = out + (size_t)row*D_;
  orow[tid]     = __float2bfloat16(d0*inv*g[tid]     + bb[tid]);
  orow[tid+256] = __float2bfloat16(d1*inv*g[tid+256] + bb[tid+256]);
  orow[tid+512] = __float2bfloat16(d2*inv*g[tid+512] + bb[tid+512]);
}

// ---------------- fused flash attention with exact skew-srel ----------------
#define LDW 68
__global__ __launch_bounds__(256) void flash_attn_k(const bf16* __restrict__ qb,
    const bf16* __restrict__ kb, const bf16* __restrict__ vb,
    const float* __restrict__ er, bf16* __restrict__ ob)
{
  const int b = blockIdx.y / NH_, h = blockIdx.y % NH_;
  const int q0 = blockIdx.x * 16;
  const int tid = threadIdx.x;
  const int qr = tid >> 4, kc = tid & 15;
  const int q  = q0 + qr;
  const bool qvalid = (q < T_);

  __shared__ float qs[17][LDW];
  __shared__ float ks[16][LDW];
  __shared__ float vs[16][LDW];

  for (int i = tid; i < 17*16; i += 256){
    const int r = i >> 4, d4 = (i & 15) * 4;
    const int qq = q0 + r;
    float4 v = (qq < T_) ? ld4f(qb + ((size_t)(b*T_ + qq))*D_ + h*DH_ + d4)
                         : make_float4(0.f,0.f,0.f,0.f);
    qs[r][d4+0]=v.x; qs[r][d4+1]=v.y; qs[r][d4+2]=v.z; qs[r][d4+3]=v.w;
  }

  float m = -3.0e38f, l = 0.f;
  float oacc[4] = {0.f,0.f,0.f,0.f};

  for (int k0 = 0; k0 < T_; k0 += 16){
    __syncthreads();
    {
      const int r = tid >> 4, d4 = (tid & 15) * 4;
      const int kk = k0 + r;
      float4 kv = (kk < T_) ? ld4f(kb + ((size_t)(b*T_ + kk))*D_ + h*DH_ + d4)
                            : make_float4(0.f,0.f,0.f,0.f);
      float4 vv = (kk < T_) ? ld4f(vb + ((size_t)(b*T_ + kk))*D_ + h*DH_ + d4)
                            : make_float4(0.f,0.f,0.f,0.f);
      ks[r][d4+0]=kv.x; ks[r][d4+1]=kv.y; ks[r][d4+2]=kv.z; ks[r][d4+3]=kv.w;
      vs[r][d4+0]=vv.x; vs[r][d4+1]=vv.y; vs[r][d4+2]=vv.z; vs[r][d4+3]=vv.w;
    }
    __syncthreads();

    const int k = k0 + kc;
    const bool kvalid = (k < T_);
    float s = -3.0e38f;
    if (qvalid && kvalid){
      const float4* q4 = reinterpret_cast<const float4*>(&qs[qr][0]);
      const float4* k4 = reinterpret_cast<const float4*>(&ks[kc][0]);
      float d1 = 0.f;
      #pragma unroll
      for (int i = 0; i < 16; i++){
        const float4 a = q4[i], c = k4[i];
        d1 = fmaf(a.x,c.x, fmaf(a.y,c.y, fmaf(a.z,c.z, fmaf(a.w,c.w, d1))));
      }
      float d2 = 0.f;
      if (k != q + 1){
        const int eidx = (k <= q) ? (499 - q + k) : (k - q - 2);
        const float4* t4 = reinterpret_cast<const float4*>(&qs[qr + ((k <= q) ? 0 : 1)][0]);
        const float* e = er + (size_t)eidx * DH_;
        #pragma unroll
        for (int i = 0; i < 16; i++){
          const float4 a = t4[i];
          const float4 ev = ld4f(e + i*4);
          d2 = fmaf(a.x,ev.x, fmaf(a.y,ev.y, fmaf(a.z,ev.z, fmaf(a.w,ev.w, d2))));
        }
      }
      s = (d1 + d2) * 0.125f;
    }

    float mx = s;
    #pragma unroll
    for (int o = 8; o > 0; o >>= 1) mx = fmaxf(mx, __shfl_xor(mx, o, 16));
    const float mn = fmaxf(m, mx);
    const float p = kvalid ? __expf(s - mn) : 0.f;
    const float corr = __expf(m - mn);
    float ps = p;
    #pragma unroll
    for (int o = 8; o > 0; o >>= 1) ps += __shfl_xor(ps, o, 16);
    l = l*corr + ps;
    m = mn;
    #pragma unroll
    for (int j = 0; j < 4; j++) oacc[j] *= corr;

    #pragma unroll
    for (int kc2 = 0; kc2 < 16; kc2++){
      const float pk = __shfl(p, kc2, 16);
      const float4 vv = *reinterpret_cast<const float4*>(&vs[kc2][kc*4]);
      oacc[0] = fmaf(pk, vv.x, oacc[0]);
      oacc[1] = fmaf(pk, vv.y, oacc[1]);
      oacc[2] = fmaf(pk, vv.z, oacc[2]);
      oacc[3] = fmaf(pk, vv.w, oacc[3]);
    }
  }

  if (qvalid){
    const float inv = 1.f / l;
    bf16* op = ob + ((size_t)(b*T_ + q))*D_ + h*DH_ + kc*4;
    ushort4 u;
    u.x = __bfloat16_as_ushort(__float2bfloat16(oacc[0]*inv));
    u.y = __bfloat16_as_ushort(__float2bfloat16(oacc[1]*inv));
    u.z = __bfloat16_as_ushort(__float2bfloat16(oacc[2]*inv));
    u.w = __bfloat16_as_ushort(__float2bfloat16(oacc[3]*inv));
    *reinterpret_cast<ushort4*>(op) = u;
  }
}

// =====================================================================
extern "C" void kernel_launch(void* const* d_in, const int* in_sizes, int n_in,
                              void* d_out, int out_size, void* d_ws, size_t ws_size,
                              hipStream_t stream)
{
  const float* spec  = (const float*)d_in[0];
  const float* cw1 = (const float*)d_in[1];  const float* cb1 = (const float*)d_in[2];
  const float* cw2 = (const float*)d_in[3];  const float* cb2 = (const float*)d_in[4];
  const float* cw3 = (const float*)d_in[5];  const float* cb3 = (const float*)d_in[6];
  const float* cw4 = (const float*)d_in[7];  const float* cb4 = (const float*)d_in[8];
  const float* proj_w = (const float*)d_in[9];  const float* proj_b = (const float*)d_in[10];
  const float* ln1_g = (const float*)d_in[11];  const float* ln1_b = (const float*)d_in[12];
  const float* wq = (const float*)d_in[13];  const float* bq = (const float*)d_in[14];
  const float* wk = (const float*)d_in[15];  const float* bk = (const float*)d_in[16];
  const float* wv = (const float*)d_in[17];  const float* bv = (const float*)d_in[18];
  const float* wo = (const float*)d_in[19];  const float* bo = (const float*)d_in[20];
  const float* er = (const float*)d_in[21];
  const float* ln2_g = (const float*)d_in[22];  const float* ln2_b = (const float*)d_in[23];
  const float* w1 = (const float*)d_in[24];  const float* b1 = (const float*)d_in[25];
  const float* w2 = (const float*)d_in[26];  const float* b2 = (const float*)d_in[27];
  const float* dw = (const float*)d_in[28];  const float* db = (const float*)d_in[29];

  if (ws_size < 98304000ull) return;
  char* W = (char*)d_ws;
  // conv phase (NHWC):
  bf16*  n1 = (bf16*) (W + 0);          // [16][96][500][32]  49.152 MB
  bf16*  n2 = (bf16*) (W + 49152000);   // [16][48][500][64]  49.152 MB
  bf16*  n3 = (bf16*) (W + 0);          // [16][24][500][64]  24.576 MB (n1 dead)
  bf16*  n4 = (bf16*) (W + 24576000);   // [16][12][500][64]  12.288 MB
  bf16*  tk = (bf16*) (W + 49152000);   // tokens [8000][768] (n2 dead)
  // transformer phase:
  float* xb = (float*)(W + 0);
  bf16*  xn = (bf16*) (W + 24576000);
  bf16*  qb = (bf16*) (W + 36864000);
  bf16*  kb = (bf16*) (W + 49152000);
  bf16*  vb = (bf16*) (W + 61440000);
  bf16*  ob = (bf16*) (W + 73728000);
  bf16*  hb = (bf16*) (W + 36864000);
  bf16*  wt = (bf16*) (W + 86016000);
  // conv weight scratch lives in d_out (fully overwritten by deproj at the end)
  bf16* cwt2 = (bf16*)d_out;                          // 25*64*32*2 = 102.4 KB
  bf16* cwt3 = (bf16*)((char*)d_out + 262144);        // 204.8 KB
  bf16* cwt4 = (bf16*)((char*)d_out + 786432);        // 204.8 KB

  // ---- CNN stack (NHWC, MFMA for conv2-4) ----
  conv_wt_k<<<(25*64*32 + 255)/256, 256, 0, stream>>>(cw2, cwt2, 32);
  conv_wt_k<<<(25*64*64 + 255)/256, 256, 0, stream>>>(cw3, cwt3, 64);
  conv_wt_k<<<(25*64*64 + 255)/256, 256, 0, stream>>>(cw4, cwt4, 64);

  conv1_k<<<(B_*96*500 + 255)/256, 256, 0, stream>>>(spec, cw1, cb1, n1);
  conv_mfma_k<32><<<dim3(8, B_*48), 256, 0, stream>>>(n1, cwt2, cb2, n2, 96);
  conv_mfma_k<64><<<dim3(8, B_*24), 256, 0, stream>>>(n2, cwt3, cb3, n3, 48);
  conv_mfma_k<64><<<dim3(8, B_*12), 256, 0, stream>>>(n3, cwt4, cb4, n4, 24);

  tokens_k<<<(B_*12*500*64 + 255)/256, 256, 0, stream>>>(n4, tk);

  transpose_w<<<dim3(D_/32, D_/32), 256, 0, stream>>>(proj_w, wt, D_, D_);
  mfma_gemm_k<0,0,0><<<dim3(6,63), 256, 0, stream>>>(tk, wt, proj_b, nullptr, xb, 8000, D_, D_);

  // ---- transformer layers ----
  for (int l = 0; l < 3; l++){
    const size_t wOff = (size_t)l*D_*D_;
    layernorm_k<<<8000, 256, 0, stream>>>(xb, ln1_g + l*D_, ln1_b + l*D_, xn);

    transpose_w<<<dim3(D_/32, D_/32), 256, 0, stream>>>(wq + wOff, wt, D_, D_);
    mfma_gemm_k<0,0,1><<<dim3(6,63), 256, 0, stream>>>(xn, wt, bq + l*D_, nullptr, qb, 8000, D_, D_);
    transpose_w<<<dim3(D_/32, D_/32), 256, 0, stream>>>(wk + wOff, wt, D_, D_);
    mfma_gemm_k<0,0,1><<<dim3(6,63), 256, 0, stream>>>(xn, wt, bk + l*D_, nullptr, kb, 8000, D_, D_);
    transpose_w<<<dim3(D_/32, D_/32), 256, 0, stream>>>(wv + wOff, wt, D_, D_);
    mfma_gemm_k<0,0,1><<<dim3(6,63), 256, 0, stream>>>(xn, wt, bv + l*D_, nullptr, vb, 8000, D_, D_);

    flash_attn_k<<<dim3(32, B_*NH_), 256, 0, stream>>>(qb, kb, vb, er + (size_t)l*T_*DH_, ob);

    transpose_w<<<dim3(D_/32, D_/32), 256, 0, stream>>>(wo + wOff, wt, D_, D_);
    mfma_gemm_k<0,1,0><<<dim3(6,63), 256, 0, stream>>>(ob, wt, bo + l*D_, xb, xb, 8000, D_, D_);

    layernorm_k<<<8000, 256, 0, stream>>>(xb, ln2_g + l*D_, ln2_b + l*D_, xn);

    transpose_w<<<dim3(FFN_/32, D_/32), 256, 0, stream>>>(w1 + (size_t)l*D_*FFN_, wt, D_, FFN_);
    mfma_gemm_k<1,0,1><<<dim3(24,63), 256, 0, stream>>>(xn, wt, b1 + l*FFN_, nullptr, hb, 8000, FFN_, D_);
    transpose_w<<<dim3(D_/32, FFN_/32), 256, 0, stream>>>(w2 + (size_t)l*FFN_*D_, wt, FFN_, D_);
    mfma_gemm_k<0,1,0><<<dim3(6,63), 256, 0, stream>>>(hb, wt, b2 + l*D_, xb, xb, 8000, D_, FFN_);
  }

  // ---- deproj -> fp32 output [8000, 192] ----
  gemm_k<float,0,0,0><<<dim3(192/64, 125), 256, 0, stream>>>(xb, dw, db, nullptr, d_out, 8000, 192, D_);
}

// Round 8
// 7385.204 us; speedup vs baseline: 4.4099x; 1.0011x over previous
//
#include <hip/hip_runtime.h>
#include <hip/hip_bf16.h>

typedef __hip_bfloat16 bf16;
typedef __attribute__((ext_vector_type(8))) short bf16x8;
typedef __attribute__((ext_vector_type(4))) float f32x4;

#define B_   16
#define T_   500
#define D_   768
#define NH_  12
#define DH_  64
#define FFN_ 3072

__device__ __forceinline__ float bfu2f(unsigned short u){ return __uint_as_float(((unsigned)u)<<16); }
__device__ __forceinline__ float geluf(float x){ return 0.5f*x*(1.0f + erff(x*0.70710678118654752f)); }

__device__ __forceinline__ float4 ld4f(const float* p){ return *reinterpret_cast<const float4*>(p); }
__device__ __forceinline__ float4 ld4f(const bf16* p){
  ushort4 u = *reinterpret_cast<const ushort4*>(p);
  return make_float4(bfu2f(u.x), bfu2f(u.y), bfu2f(u.z), bfu2f(u.w));
}

// ---------------- conv1: Cin=1, 32 oc per thread, writes NHWC [b][96][500][32] ----------------
__global__ __launch_bounds__(256) void conv1_k(const float* __restrict__ spec,
    const float* __restrict__ w, const float* __restrict__ bias, bf16* __restrict__ out)
{
  const int pos = blockIdx.x*256 + threadIdx.x;
  if (pos >= B_*96*500) return;
  const int x  = pos % 500;
  const int yo = (pos/500) % 96;
  const int b  = pos/(500*96);
  const float* ip = spec + (size_t)b*192*500;

  float v[6][5];
  #pragma unroll
  for (int r = 0; r < 6; r++){
    const int yy = 2*yo - 2 + r;
    const bool vy = (yy >= 0) && (yy < 192);
    const float* rp = ip + (size_t)(vy ? yy : 0)*500;
    #pragma unroll
    for (int c = 0; c < 5; c++){
      const int xx = x - 2 + c;
      v[r][c] = (vy && xx >= 0 && xx < 500) ? rp[xx] : 0.f;
    }
  }

  const size_t obase = (((size_t)(b*96 + yo))*500 + x)*32;
  #pragma unroll
  for (int oc = 0; oc < 32; oc++){
    float a0 = bias[oc], a1 = bias[oc];
    #pragma unroll
    for (int r = 0; r < 5; r++)
      #pragma unroll
      for (int c = 0; c < 5; c++){
        const float wv = w[oc*25 + r*5 + c];
        a0 = fmaf(v[r][c],   wv, a0);
        a1 = fmaf(v[r+1][c], wv, a1);
      }
    out[obase + oc] = __float2bfloat16(fmaxf(geluf(a0), geluf(a1)));
  }
}

// ---------------- conv weight transpose: fp32 OIHW [64][Cin][5][5] -> bf16 [tap][oc][ci] ----------------
__global__ __launch_bounds__(256) void conv_wt_k(const float* __restrict__ w,
    bf16* __restrict__ wt, int Cin)
{
  const int idx = blockIdx.x*256 + threadIdx.x;
  if (idx >= 25*64*Cin) return;
  const int ci  = idx % Cin;
  const int oc  = (idx/Cin) % 64;
  const int tap = idx/(Cin*64);
  wt[idx] = __float2bfloat16(w[(size_t)(oc*Cin + ci)*25 + tap]);
}

// ---------------- MFMA conv (Cin=32/64, Cout=64) + GELU + pool, NHWC in/out ----------------
// Block: one pooled output row (conv rows 2yo,2yo+1) x 64-x chunk x 64 oc. No LDS.
// A-frag: lane row = x-position, 8 consecutive ci (contiguous NHWC). B: wt[tap][oc][ci].
template<int CIN>
__global__ __launch_bounds__(256) void conv_mfma_k(const bf16* __restrict__ in,
    const bf16* __restrict__ wt, const float* __restrict__ bias,
    bf16* __restrict__ out, int Hin)
{
  const int Hout = Hin >> 1;
  const int x0 = blockIdx.x * 64;
  const int yo = blockIdx.y % Hout;
  const int b  = blockIdx.y / Hout;
  const int tid = threadIdx.x, w = tid >> 6, lane = tid & 63;
  const int lr = lane & 15, kb = lane >> 4;
  const int xl = w*16 + lr;          // this wave's x within chunk (A-frag rows)
  const int xg = x0 + xl;

  f32x4 acc0[4], acc1[4];
  #pragma unroll
  for (int nf = 0; nf < 4; nf++){ acc0[nf] = (f32x4){0,0,0,0}; acc1[nf] = (f32x4){0,0,0,0}; }

  for (int ky = 0; ky < 5; ky++){
    const int yy0 = 2*yo + ky - 2;
    const int yy1 = yy0 + 1;
    const bool v0 = (yy0 >= 0) && (yy0 < Hin);
    const bool v1 = (yy1 >= 0) && (yy1 < Hin);
    #pragma unroll
    for (int kx = 0; kx < 5; kx++){
      const int xx = xg + kx - 2;
      const bool vx = (xx >= 0) && (xx < 500);
      const int tap = ky*5 + kx;
      #pragma unroll
      for (int c0 = 0; c0 < CIN; c0 += 32){
        bf16x8 bfr[4];
        #pragma unroll
        for (int nf = 0; nf < 4; nf++)
          bfr[nf] = *reinterpret_cast<const bf16x8*>(wt + ((size_t)(tap*64 + nf*16 + lr))*CIN + c0 + kb*8);

        bf16x8 a0 = {0,0,0,0,0,0,0,0}, a1 = {0,0,0,0,0,0,0,0};
        if (vx){
          if (v0) a0 = *reinterpret_cast<const bf16x8*>(in + (((size_t)(b*Hin + yy0))*500 + xx)*CIN + c0 + kb*8);
          if (v1) a1 = *reinterpret_cast<const bf16x8*>(in + (((size_t)(b*Hin + yy1))*500 + xx)*CIN + c0 + kb*8);
        }
        #pragma unroll
        for (int nf = 0; nf < 4; nf++){
          acc0[nf] = __builtin_amdgcn_mfma_f32_16x16x32_bf16(a0, bfr[nf], acc0[nf], 0, 0, 0);
          acc1[nf] = __builtin_amdgcn_mfma_f32_16x16x32_bf16(a1, bfr[nf], acc1[nf], 0, 0, 0);
        }
      }
    }
  }

  // epilogue: C/D row = kb*4+rg (x), col = lr (oc). pool(gelu) the two conv rows.
  #pragma unroll
  for (int rg = 0; rg < 4; rg++){
    const int xs = x0 + w*16 + kb*4 + rg;
    if (xs < 500){
      const size_t obase = (((size_t)(b*Hout + yo))*500 + xs)*64;
      #pragma unroll
      for (int nf = 0; nf < 4; nf++){
        const int oc = nf*16 + lr;
        const float bv = bias[oc];
        const float p0 = geluf(acc0[nf][rg] + bv);
        const float p1 = geluf(acc1[nf][rg] + bv);
        out[obase + oc] = __float2bfloat16(fmaxf(p0, p1));
      }
    }
  }
}

// ---------------- tokens: NHWC conv4 out [b][12][500][64] -> tk[b*T+t][ci*12+yo] ----------------
__global__ __launch_bounds__(256) void tokens_k(const bf16* __restrict__ n4, bf16* __restrict__ tk)
{
  const int idx = blockIdx.x*256 + threadIdx.x;
  if (idx >= B_*12*500*64) return;
  const int ci = idx & 63;
  const int t  = (idx >> 6) % 500;
  const int yo = (idx >> 6) / 500 % 12;
  const int b  = idx / (64*500*12);
  tk[((size_t)(b*500 + t))*768 + ci*12 + yo] = n4[idx];
}

// ---------------- weight transpose+convert: fp32 [K][N] -> bf16 [N][K] ----------------
__global__ __launch_bounds__(256) void transpose_w(const float* __restrict__ W,
    bf16* __restrict__ out, int K, int N)
{
  __shared__ float tile[32][33];
  const int gk = blockIdx.y*32, gn = blockIdx.x*32;
  const int tr = threadIdx.x >> 5, tc = threadIdx.x & 31;
  #pragma unroll
  for (int i = 0; i < 4; i++)
    tile[tr + i*8][tc] = W[(size_t)(gk + tr + i*8)*N + gn + tc];
  __syncthreads();
  #pragma unroll
  for (int i = 0; i < 4; i++)
    out[(size_t)(gn + tr + i*8)*K + gk + tc] = __float2bfloat16(tile[tc][tr + i*8]);
}

// ---------------- MFMA GEMM: C = act(A[MxK](bf16) @ Bt[NxK]^T(bf16) + bias) (+resid) ----------------
template<int ACT, int RESID, int BF16OUT>
__global__ __launch_bounds__(256) void mfma_gemm_k(const bf16* __restrict__ A,
    const bf16* __restrict__ Bt, const float* __restrict__ bias,
    const float* __restrict__ resid, void* __restrict__ Cout, int M, int N, int K)
{
  __shared__ uint4 Alds[512];
  __shared__ uint4 Blds[512];

  const int tid = threadIdx.x;
  const int wid = tid >> 6, lane = tid & 63;
  const int wr = wid >> 1, wc = wid & 1;
  const int bm = blockIdx.y*128, bn = blockIdx.x*128;

  const int g0 = tid >> 7;
  const int r0 = tid & 127;
  const int arow = min(bm + r0, M-1);
  const int brow = bn + r0;
  const int lg = lane >> 4, lr = lane & 15;

  f32x4 acc[4][4];
  #pragma unroll
  for (int i = 0; i < 4; i++)
    #pragma unroll
    for (int j = 0; j < 4; j++)
      acc[i][j] = (f32x4){0.f,0.f,0.f,0.f};

  for (int k0 = 0; k0 < K; k0 += 32){
    const uint4 av0 = *reinterpret_cast<const uint4*>(A  + (size_t)arow*K + k0 + g0*8);
    const uint4 av1 = *reinterpret_cast<const uint4*>(A  + (size_t)arow*K + k0 + (g0+2)*8);
    const uint4 bv0 = *reinterpret_cast<const uint4*>(Bt + (size_t)brow*K + k0 + g0*8);
    const uint4 bv1 = *reinterpret_cast<const uint4*>(Bt + (size_t)brow*K + k0 + (g0+2)*8);
    __syncthreads();
    Alds[g0*128 + r0] = av0;  Alds[(g0+2)*128 + r0] = av1;
    Blds[g0*128 + r0] = bv0;  Blds[(g0+2)*128 + r0] = bv1;
    __syncthreads();

    bf16x8 af[4], bfr[4];
    #pragma unroll
    for (int mf = 0; mf < 4; mf++)
      af[mf] = *reinterpret_cast<const bf16x8*>(&Alds[lg*128 + wr*64 + mf*16 + lr]);
    #pragma unroll
    for (int nf = 0; nf < 4; nf++)
      bfr[nf] = *reinterpret_cast<const bf16x8*>(&Blds[lg*128 + wc*64 + nf*16 + lr]);

    #pragma unroll
    for (int mf = 0; mf < 4; mf++)
      #pragma unroll
      for (int nf = 0; nf < 4; nf++)
        acc[mf][nf] = __builtin_amdgcn_mfma_f32_16x16x32_bf16(af[mf], bfr[nf], acc[mf][nf], 0, 0, 0);
  }

  #pragma unroll
  for (int mf = 0; mf < 4; mf++){
    #pragma unroll
    for (int rg = 0; rg < 4; rg++){
      const int row = bm + wr*64 + mf*16 + (lane>>4)*4 + rg;
      if (row >= M) continue;
      #pragma unroll
      for (int nf = 0; nf < 4; nf++){
        const int col = bn + wc*64 + nf*16 + (lane&15);
        float v = acc[mf][nf][rg] + bias[col];
        if (ACT == 1) v = geluf(v);
        if (RESID)    v += resid[(size_t)row*N + col];
        if (BF16OUT)  reinterpret_cast<bf16*>(Cout)[(size_t)row*N + col] = __float2bfloat16(v);
        else          reinterpret_cast<float*>(Cout)[(size_t)row*N + col] = v;
      }
    }
  }
}

// ---------------- fp32 fallback GEMM (deproj: N=192) ----------------
template<typename TA, int ACT, int RESID, int BF16OUT>
__global__ __launch_bounds__(256) void gemm_k(const TA* __restrict__ A,
    const float* __restrict__ Bw, const float* __restrict__ bias,
    const float* __restrict__ resid, void* __restrict__ Cout, int M, int N, int K)
{
  __shared__ float As[16][65];
  __shared__ float Bs[16][65];
  const int bm = blockIdx.y*64, bn = blockIdx.x*64;
  const int tid = threadIdx.x;
  const int tr = tid >> 4, tc = tid & 15;

  const int am  = tid >> 2;
  const int ak4 = tid & 3;
  const int bk  = tid >> 4;
  const int bn4 = tid & 15;

  float acc[4][4] = {{0.f}};

  for (int k0 = 0; k0 < K; k0 += 16){
    const float4 av = ld4f(A + (size_t)(bm + am)*K + k0 + ak4*4);
    As[ak4*4+0][am] = av.x; As[ak4*4+1][am] = av.y;
    As[ak4*4+2][am] = av.z; As[ak4*4+3][am] = av.w;

    const float4 bv = ld4f(Bw + (size_t)(k0 + bk)*N + bn + bn4*4);
    Bs[bk][bn4*4+0] = bv.x; Bs[bk][bn4*4+1] = bv.y;
    Bs[bk][bn4*4+2] = bv.z; Bs[bk][bn4*4+3] = bv.w;
    __syncthreads();

    #pragma unroll
    for (int k = 0; k < 16; k++){
      float a[4], bb_[4];
      #pragma unroll
      for (int i = 0; i < 4; i++) a[i]  = As[k][tr*4 + i];
      #pragma unroll
      for (int j = 0; j < 4; j++) bb_[j] = Bs[k][tc*4 + j];
      #pragma unroll
      for (int i = 0; i < 4; i++)
        #pragma unroll
        for (int j = 0; j < 4; j++)
          acc[i][j] = fmaf(a[i], bb_[j], acc[i][j]);
    }
    __syncthreads();
  }

  #pragma unroll
  for (int i = 0; i < 4; i++){
    const int row = bm + tr*4 + i;
    #pragma unroll
    for (int j = 0; j < 4; j++){
      const int col = bn + tc*4 + j;
      float v = acc[i][j] + bias[col];
      if (ACT == 1) v = geluf(v);
      if (RESID)    v += resid[(size_t)row*N + col];
      if (BF16OUT)  reinterpret_cast<bf16*>(Cout)[(size_t)row*N + col] = __float2bfloat16(v);
      else          reinterpret_cast<float*>(Cout)[(size_t)row*N + col] = v;
    }
  }
}

// ---------------- LayerNorm over D=768: fp32 in -> bf16 out ----------------
__global__ __launch_bounds__(256) void layernorm_k(const float* __restrict__ x,
    const float* __restrict__ g, const float* __restrict__ bb, bf16* __restrict__ out)
{
  const int row = blockIdx.x;
  const float* xr = x + (size_t)row*D_;
  const int tid = threadIdx.x;
  const float v0 = xr[tid], v1 = xr[tid+256], v2 = xr[tid+512];

  float s = v0 + v1 + v2;
  #pragma unroll
  for (int o = 32; o > 0; o >>= 1) s += __shfl_xor(s, o);
  __shared__ float sm[4];
  const int wid = tid >> 6, lane = tid & 63;
  if (lane == 0) sm[wid] = s;
  __syncthreads();
  const float mean = (sm[0]+sm[1]+sm[2]+sm[3]) * (1.f/768.f);
  __syncthreads();

  const float d0 = v0-mean, d1 = v1-mean, d2 = v2-mean;
  float ss = d0*d0 + d1*d1 + d2*d2;
  #pragma unroll
  for (int o = 32; o > 0; o >>= 1) ss += __shfl_xor(ss, o);
  if (lane == 0) sm[wid] = ss;
  __syncthreads();
  const float var = (sm[0]+sm[1]+sm[2]+sm[3]) * (1.f/768.f);
  const float inv = rsqrtf(var + 1e-5f);

  bf16* orow = out + (size_t)row*D_;
  orow[tid]     = __float2bfloat16(d0*inv*g[tid]     + bb[tid]);
  orow[tid+256] = __float2bfloat16(d1*inv*g[tid+256] + bb[tid+256]);
  orow[tid+512] = __float2bfloat16(d2*inv*g[tid+512] + bb[tid+512]);
}

// ---------------- fused flash attention with exact skew-srel ----------------
#define LDW 68
__global__ __launch_bounds__(256) void flash_attn_k(const bf16* __restrict__ qb,
    const bf16* __restrict__ kb, const bf16* __restrict__ vb,
    const float* __restrict__ er, bf16* __restrict__ ob)
{
  const int b = blockIdx.y / NH_, h = blockIdx.y % NH_;
  const int q0 = blockIdx.x * 16;
  const int tid = threadIdx.x;
  const int qr = tid >> 4, kc = tid & 15;
  const int q  = q0 + qr;
  const bool qvalid = (q < T_);

  __shared__ float qs[17][LDW];
  __shared__ float ks[16][LDW];
  __shared__ float vs[16][LDW];

  for (int i = tid; i < 17*16; i += 256){
    const int r = i >> 4, d4 = (i & 15) * 4;
    const int qq = q0 + r;
    float4 v = (qq < T_) ? ld4f(qb + ((size_t)(b*T_ + qq))*D_ + h*DH_ + d4)
                         : make_float4(0.f,0.f,0.f,0.f);
    qs[r][d4+0]=v.x; qs[r][d4+1]=v.y; qs[r][d4+2]=v.z; qs[r][d4+3]=v.w;
  }

  float m = -3.0e38f, l = 0.f;
  float oacc[4] = {0.f,0.f,0.f,0.f};

  for (int k0 = 0; k0 < T_; k0 += 16){
    __syncthreads();
    {
      const int r = tid >> 4, d4 = (tid & 15) * 4;
      const int kk = k0 + r;
      float4 kv = (kk < T_) ? ld4f(kb + ((size_t)(b*T_ + kk))*D_ + h*DH_ + d4)
                            : make_float4(0.f,0.f,0.f,0.f);
      float4 vv = (kk < T_) ? ld4f(vb + ((size_t)(b*T_ + kk))*D_ + h*DH_ + d4)
                            : make_float4(0.f,0.f,0.f,0.f);
      ks[r][d4+0]=kv.x; ks[r][d4+1]=kv.y; ks[r][d4+2]=kv.z; ks[r][d4+3]=kv.w;
      vs[r][d4+0]=vv.x; vs[r][d4+1]=vv.y; vs[r][d4+2]=vv.z; vs[r][d4+3]=vv.w;
    }
    __syncthreads();

    const int k = k0 + kc;
    const bool kvalid = (k < T_);
    float s = -3.0e38f;
    if (qvalid && kvalid){
      const float4* q4 = reinterpret_cast<const float4*>(&qs[qr][0]);
      const float4* k4 = reinterpret_cast<const float4*>(&ks[kc][0]);
      float d1 = 0.f;
      #pragma unroll
      for (int i = 0; i < 16; i++){
        const float4 a = q4[i], c = k4[i];
        d1 = fmaf(a.x,c.x, fmaf(a.y,c.y, fmaf(a.z,c.z, fmaf(a.w,c.w, d1))));
      }
      float d2 = 0.f;
      if (k != q + 1){
        const int eidx = (k <= q) ? (499 - q + k) : (k - q - 2);
        const float4* t4 = reinterpret_cast<const float4*>(&qs[qr + ((k <= q) ? 0 : 1)][0]);
        const float* e = er + (size_t)eidx * DH_;
        #pragma unroll
        for (int i = 0; i < 16; i++){
          const float4 a = t4[i];
          const float4 ev = ld4f(e + i*4);
          d2 = fmaf(a.x,ev.x, fmaf(a.y,ev.y, fmaf(a.z,ev.z, fmaf(a.w,ev.w, d2))));
        }
      }
      s = (d1 + d2) * 0.125f;
    }

    float mx = s;
    #pragma unroll
    for (int o = 8; o > 0; o >>= 1) mx = fmaxf(mx, __shfl_xor(mx, o, 16));
    const float mn = fmaxf(m, mx);
    const float p = kvalid ? __expf(s - mn) : 0.f;
    const float corr = __expf(m - mn);
    float ps = p;
    #pragma unroll
    for (int o = 8; o > 0; o >>= 1) ps += __shfl_xor(ps, o, 16);
    l = l*corr + ps;
    m = mn;
    #pragma unroll
    for (int j = 0; j < 4; j++) oacc[j] *= corr;

    #pragma unroll
    for (int kc2 = 0; kc2 < 16; kc2++){
      const float pk = __shfl(p, kc2, 16);
      const float4 vv = *reinterpret_cast<const float4*>(&vs[kc2][kc*4]);
      oacc[0] = fmaf(pk, vv.x, oacc[0]);
      oacc[1] = fmaf(pk, vv.y, oacc[1]);
      oacc[2] = fmaf(pk, vv.z, oacc[2]);
      oacc[3] = fmaf(pk, vv.w, oacc[3]);
    }
  }

  if (qvalid){
    const float inv = 1.f / l;
    bf16* op = ob + ((size_t)(b*T_ + q))*D_ + h*DH_ + kc*4;
    ushort4 u;
    u.x = __bfloat16_as_ushort(__float2bfloat16(oacc[0]*inv));
    u.y = __bfloat16_as_ushort(__float2bfloat16(oacc[1]*inv));
    u.z = __bfloat16_as_ushort(__float2bfloat16(oacc[2]*inv));
    u.w = __bfloat16_as_ushort(__float2bfloat16(oacc[3]*inv));
    *reinterpret_cast<ushort4*>(op) = u;
  }
}

// =====================================================================
extern "C" void kernel_launch(void* const* d_in, const int* in_sizes, int n_in,
                              void* d_out, int out_size, void* d_ws, size_t ws_size,
                              hipStream_t stream)
{
  const float* spec  = (const float*)d_in[0];
  const float* cw1 = (const float*)d_in[1];  const float* cb1 = (const float*)d_in[2];
  const float* cw2 = (const float*)d_in[3];  const float* cb2 = (const float*)d_in[4];
  const float* cw3 = (const float*)d_in[5];  const float* cb3 = (const float*)d_in[6];
  const float* cw4 = (const float*)d_in[7];  const float* cb4 = (const float*)d_in[8];
  const float* proj_w = (const float*)d_in[9];  const float* proj_b = (const float*)d_in[10];
  const float* ln1_g = (const float*)d_in[11];  const float* ln1_b = (const float*)d_in[12];
  const float* wq = (const float*)d_in[13];  const float* bq = (const float*)d_in[14];
  const float* wk = (const float*)d_in[15];  const float* bk = (const float*)d_in[16];
  const float* wv = (const float*)d_in[17];  const float* bv = (const float*)d_in[18];
  const float* wo = (const float*)d_in[19];  const float* bo = (const float*)d_in[20];
  const float* er = (const float*)d_in[21];
  const float* ln2_g = (const float*)d_in[22];  const float* ln2_b = (const float*)d_in[23];
  const float* w1 = (const float*)d_in[24];  const float* b1 = (const float*)d_in[25];
  const float* w2 = (const float*)d_in[26];  const float* b2 = (const float*)d_in[27];
  const float* dw = (const float*)d_in[28];  const float* db = (const float*)d_in[29];

  if (ws_size < 98304000ull) return;
  char* W = (char*)d_ws;
  // conv phase (NHWC):
  bf16*  n1 = (bf16*) (W + 0);          // [16][96][500][32]  49.152 MB
  bf16*  n2 = (bf16*) (W + 49152000);   // [16][48][500][64]  49.152 MB
  bf16*  n3 = (bf16*) (W + 0);          // [16][24][500][64]  24.576 MB (n1 dead)
  bf16*  n4 = (bf16*) (W + 24576000);   // [16][12][500][64]  12.288 MB
  bf16*  tk = (bf16*) (W + 49152000);   // tokens [8000][768] (n2 dead)
  // transformer phase:
  float* xb = (float*)(W + 0);
  bf16*  xn = (bf16*) (W + 24576000);
  bf16*  qb = (bf16*) (W + 36864000);
  bf16*  kb = (bf16*) (W + 49152000);
  bf16*  vb = (bf16*) (W + 61440000);
  bf16*  ob = (bf16*) (W + 73728000);
  bf16*  hb = (bf16*) (W + 36864000);
  bf16*  wt = (bf16*) (W + 86016000);
  // conv weight scratch lives in d_out (fully overwritten by deproj at the end)
  bf16* cwt2 = (bf16*)d_out;                          // 25*64*32*2 = 102.4 KB
  bf16* cwt3 = (bf16*)((char*)d_out + 262144);        // 204.8 KB
  bf16* cwt4 = (bf16*)((char*)d_out + 786432);        // 204.8 KB

  // ---- CNN stack (NHWC, MFMA for conv2-4) ----
  conv_wt_k<<<(25*64*32 + 255)/256, 256, 0, stream>>>(cw2, cwt2, 32);
  conv_wt_k<<<(25*64*64 + 255)/256, 256, 0, stream>>>(cw3, cwt3, 64);
  conv_wt_k<<<(25*64*64 + 255)/256, 256, 0, stream>>>(cw4, cwt4, 64);

  conv1_k<<<(B_*96*500 + 255)/256, 256, 0, stream>>>(spec, cw1, cb1, n1);
  conv_mfma_k<32><<<dim3(8, B_*48), 256, 0, stream>>>(n1, cwt2, cb2, n2, 96);
  conv_mfma_k<64><<<dim3(8, B_*24), 256, 0, stream>>>(n2, cwt3, cb3, n3, 48);
  conv_mfma_k<64><<<dim3(8, B_*12), 256, 0, stream>>>(n3, cwt4, cb4, n4, 24);

  tokens_k<<<(B_*12*500*64 + 255)/256, 256, 0, stream>>>(n4, tk);

  transpose_w<<<dim3(D_/32, D_/32), 256, 0, stream>>>(proj_w, wt, D_, D_);
  mfma_gemm_k<0,0,0><<<dim3(6,63), 256, 0, stream>>>(tk, wt, proj_b, nullptr, xb, 8000, D_, D_);

  // ---- transformer layers ----
  for (int l = 0; l < 3; l++){
    const size_t wOff = (size_t)l*D_*D_;
    layernorm_k<<<8000, 256, 0, stream>>>(xb, ln1_g + l*D_, ln1_b + l*D_, xn);

    transpose_w<<<dim3(D_/32, D_/32), 256, 0, stream>>>(wq + wOff, wt, D_, D_);
    mfma_gemm_k<0,0,1><<<dim3(6,63), 256, 0, stream>>>(xn, wt, bq + l*D_, nullptr, qb, 8000, D_, D_);
    transpose_w<<<dim3(D_/32, D_/32), 256, 0, stream>>>(wk + wOff, wt, D_, D_);
    mfma_gemm_k<0,0,1><<<dim3(6,63), 256, 0, stream>>>(xn, wt, bk + l*D_, nullptr, kb, 8000, D_, D_);
    transpose_w<<<dim3(D_/32, D_/32), 256, 0, stream>>>(wv + wOff, wt, D_, D_);
    mfma_gemm_k<0,0,1><<<dim3(6,63), 256, 0, stream>>>(xn, wt, bv + l*D_, nullptr, vb, 8000, D_, D_);

    flash_attn_k<<<dim3(32, B_*NH_), 256, 0, stream>>>(qb, kb, vb, er + (size_t)l*T_*DH_, ob);

    transpose_w<<<dim3(D_/32, D_/32), 256, 0, stream>>>(wo + wOff, wt, D_, D_);
    mfma_gemm_k<0,1,0><<<dim3(6,63), 256, 0, stream>>>(ob, wt, bo + l*D_, xb, xb, 8000, D_, D_);

    layernorm_k<<<8000, 256, 0, stream>>>(xb, ln2_g + l*D_, ln2_b + l*D_, xn);

    transpose_w<<<dim3(FFN_/32, D_/32), 256, 0, stream>>>(w1 + (size_t)l*D_*FFN_, wt, D_, FFN_);
    mfma_gemm_k<1,0,1><<<dim3(24,63), 256, 0, stream>>>(xn, wt, b1 + l*FFN_, nullptr, hb, 8000, FFN_, D_);
    transpose_w<<<dim3(D_/32, FFN_/32), 256, 0, stream>>>(w2 + (size_t)l*FFN_*D_, wt, FFN_, D_);
    mfma_gemm_k<0,1,0><<<dim3(6,63), 256, 0, stream>>>(hb, wt, b2 + l*D_, xb, xb, 8000, D_, FFN_);
  }

  // ---- deproj -> fp32 output [8000, 192] ----
  gemm_k<float,0,0,0><<<dim3(192/64, 125), 256, 0, stream>>>(xb, dw, db, nullptr, d_out, 8000, 192, D_);
}

// Round 9
// 6365.599 us; speedup vs baseline: 5.1163x; 1.1602x over previous
//
#include <hip/hip_runtime.h>
#include <hip/hip_bf16.h>

typedef __hip_bfloat16 bf16;
typedef __attribute__((ext_vector_type(8))) short bf16x8;
typedef __attribute__((ext_vector_type(4))) float f32x4;

#define B_   16
#define T_   500
#define D_   768
#define NH_  12
#define DH_  64
#define FFN_ 3072

__device__ __forceinline__ float bfu2f(unsigned short u){ return __uint_as_float(((unsigned)u)<<16); }
__device__ __forceinline__ float geluf(float x){ return 0.5f*x*(1.0f + erff(x*0.70710678118654752f)); }

__device__ __forceinline__ float4 ld4f(const float* p){ return *reinterpret_cast<const float4*>(p); }
__device__ __forceinline__ float4 ld4f(const bf16* p){
  ushort4 u = *reinterpret_cast<const ushort4*>(p);
  return make_float4(bfu2f(u.x), bfu2f(u.y), bfu2f(u.z), bfu2f(u.w));
}

// ---------------- conv1: Cin=1, 32 oc per thread, writes NHWC [b][96][500][32] ----------------
__global__ __launch_bounds__(256) void conv1_k(const float* __restrict__ spec,
    const float* __restrict__ w, const float* __restrict__ bias, bf16* __restrict__ out)
{
  const int pos = blockIdx.x*256 + threadIdx.x;
  if (pos >= B_*96*500) return;
  const int x  = pos % 500;
  const int yo = (pos/500) % 96;
  const int b  = pos/(500*96);
  const float* ip = spec + (size_t)b*192*500;

  float v[6][5];
  #pragma unroll
  for (int r = 0; r < 6; r++){
    const int yy = 2*yo - 2 + r;
    const bool vy = (yy >= 0) && (yy < 192);
    const float* rp = ip + (size_t)(vy ? yy : 0)*500;
    #pragma unroll
    for (int c = 0; c < 5; c++){
      const int xx = x - 2 + c;
      v[r][c] = (vy && xx >= 0 && xx < 500) ? rp[xx] : 0.f;
    }
  }

  const size_t obase = (((size_t)(b*96 + yo))*500 + x)*32;
  #pragma unroll
  for (int oc = 0; oc < 32; oc++){
    float a0 = bias[oc], a1 = bias[oc];
    #pragma unroll
    for (int r = 0; r < 5; r++)
      #pragma unroll
      for (int c = 0; c < 5; c++){
        const float wv = w[oc*25 + r*5 + c];
        a0 = fmaf(v[r][c],   wv, a0);
        a1 = fmaf(v[r+1][c], wv, a1);
      }
    out[obase + oc] = __float2bfloat16(fmaxf(geluf(a0), geluf(a1)));
  }
}

// ---------------- conv weight repack: OIHW fp32 -> bf16 [tap][cg][nf][lane][8] ----------------
// element e = (((tap*(CIN/32)+cg)*4+nf)*64 + lane)*8 + j  holds  w[oc=nf*16+(lane&15)][ci=cg*32+(lane>>4)*8+j][tap]
template<int CIN>
__global__ __launch_bounds__(256) void conv_wt_k(const float* __restrict__ w, bf16* __restrict__ wt)
{
  const int e = blockIdx.x*256 + threadIdx.x;
  if (e >= 25*CIN*64) return;
  const int j    = e & 7;
  const int lane = (e >> 3) & 63;
  const int nf   = (e >> 9) & 3;
  const int t3   = e >> 11;
  const int cg   = t3 % (CIN/32);
  const int tap  = t3 / (CIN/32);
  const int oc = nf*16 + (lane & 15);
  const int ci = cg*32 + (lane >> 4)*8 + j;
  wt[e] = __float2bfloat16(w[(size_t)(oc*CIN + ci)*25 + tap]);
}

// ---------------- MFMA conv + GELU + pool, NHWC, LDS-staged branch-free inner loop ----------------
// Block: (b, yo, 64-x chunk) x 64 oc. LDS: 6 rows x 68 x x CIN bf16, XOR-swizzled (^(xx&7)<<4).
template<int CIN>
__global__ __launch_bounds__(256) void conv_mfma_k(const bf16* __restrict__ in,
    const bf16* __restrict__ wt, const float* __restrict__ bias,
    bf16* __restrict__ out, int Hin)
{
  constexpr int KB   = CIN/8;          // uint4 chunks per x
  constexpr int ROWB = 68*CIN*2;       // bytes per LDS row (low 7 bits zero)
  __shared__ uint4 ldsu[6*68*CIN/8];
  char* lds = (char*)ldsu;

  const int Hout = Hin >> 1;
  const int x0 = blockIdx.x * 64;
  const int yo = blockIdx.y % Hout;
  const int b  = blockIdx.y / Hout;
  const int tid = threadIdx.x, w = tid >> 6, lane = tid & 63;
  const int lr = lane & 15, kb = lane >> 4;

  // ---- stage input halo (zero-padded) ----
  for (int idx = tid; idx < 6*68*KB; idx += 256){
    const int kbb = idx % KB;
    const int xx  = (idx/KB) % 68;
    const int r   = idx/(KB*68);
    const int yy = 2*yo + r - 2;
    const int xg = x0 + xx - 2;
    uint4 v = make_uint4(0,0,0,0);
    if (yy >= 0 && yy < Hin && xg >= 0 && xg < 500)
      v = *reinterpret_cast<const uint4*>(in + (((size_t)(b*Hin + yy))*500 + xg)*CIN + kbb*8);
    int off = r*ROWB + xx*(CIN*2) + kbb*16;
    off ^= (xx & 7) << 4;
    *reinterpret_cast<uint4*>(lds + off) = v;
  }
  __syncthreads();

  f32x4 acc0[4], acc1[4];
  #pragma unroll
  for (int nf = 0; nf < 4; nf++){ acc0[nf] = (f32x4){0,0,0,0}; acc1[nf] = (f32x4){0,0,0,0}; }

  const int xl = w*16 + lr;
  #pragma unroll
  for (int ky = 0; ky < 5; ky++){
    #pragma unroll
    for (int kx = 0; kx < 5; kx++){
      const int xx = xl + kx;
      const int tap = ky*5 + kx;
      #pragma unroll
      for (int cg = 0; cg < CIN/32; cg++){
        int aoff = ky*ROWB + xx*(CIN*2) + (cg*32 + kb*8)*2;
        aoff ^= (xx & 7) << 4;
        const bf16x8 a0 = *reinterpret_cast<const bf16x8*>(lds + aoff);
        const bf16x8 a1 = *reinterpret_cast<const bf16x8*>(lds + aoff + ROWB);
        const bf16* bp = wt + ((size_t)((tap*(CIN/32) + cg)*4)*64 + lane)*8;
        #pragma unroll
        for (int nf = 0; nf < 4; nf++){
          const bf16x8 bf_ = *reinterpret_cast<const bf16x8*>(bp + nf*512);
          acc0[nf] = __builtin_amdgcn_mfma_f32_16x16x32_bf16(a0, bf_, acc0[nf], 0, 0, 0);
          acc1[nf] = __builtin_amdgcn_mfma_f32_16x16x32_bf16(a1, bf_, acc1[nf], 0, 0, 0);
        }
      }
    }
  }

  // epilogue: C/D row = kb*4+rg (x), col = lr (oc). pool(gelu) the two conv rows.
  #pragma unroll
  for (int rg = 0; rg < 4; rg++){
    const int xs = x0 + w*16 + kb*4 + rg;
    if (xs < 500){
      const size_t obase = (((size_t)(b*Hout + yo))*500 + xs)*64;
      #pragma unroll
      for (int nf = 0; nf < 4; nf++){
        const int oc = nf*16 + lr;
        const float bv = bias[oc];
        const float p0 = geluf(acc0[nf][rg] + bv);
        const float p1 = geluf(acc1[nf][rg] + bv);
        out[obase + oc] = __float2bfloat16(fmaxf(p0, p1));
      }
    }
  }
}

// ---------------- tokens: NHWC conv4 out [b][12][500][64] -> tk[b*T+t][ci*12+yo] ----------------
__global__ __launch_bounds__(256) void tokens_k(const bf16* __restrict__ n4, bf16* __restrict__ tk)
{
  const int idx = blockIdx.x*256 + threadIdx.x;
  if (idx >= B_*12*500*64) return;
  const int ci = idx & 63;
  const int t  = (idx >> 6) % 500;
  const int yo = (idx >> 6) / 500 % 12;
  const int b  = idx / (64*500*12);
  tk[((size_t)(b*500 + t))*768 + ci*12 + yo] = n4[idx];
}

// ---------------- weight transpose+convert: fp32 [K][N] -> bf16 [N][K] ----------------
__global__ __launch_bounds__(256) void transpose_w(const float* __restrict__ W,
    bf16* __restrict__ out, int K, int N)
{
  __shared__ float tile[32][33];
  const int gk = blockIdx.y*32, gn = blockIdx.x*32;
  const int tr = threadIdx.x >> 5, tc = threadIdx.x & 31;
  #pragma unroll
  for (int i = 0; i < 4; i++)
    tile[tr + i*8][tc] = W[(size_t)(gk + tr + i*8)*N + gn + tc];
  __syncthreads();
  #pragma unroll
  for (int i = 0; i < 4; i++)
    out[(size_t)(gn + tr + i*8)*K + gk + tc] = __float2bfloat16(tile[tc][tr + i*8]);
}

// ---------------- MFMA GEMM: C = act(A[MxK](bf16) @ Bt[NxK]^T(bf16) + bias) (+resid) ----------------
template<int ACT, int RESID, int BF16OUT>
__global__ __launch_bounds__(256) void mfma_gemm_k(const bf16* __restrict__ A,
    const bf16* __restrict__ Bt, const float* __restrict__ bias,
    const float* __restrict__ resid, void* __restrict__ Cout, int M, int N, int K)
{
  __shared__ uint4 Alds[512];
  __shared__ uint4 Blds[512];

  const int tid = threadIdx.x;
  const int wid = tid >> 6, lane = tid & 63;
  const int wr = wid >> 1, wc = wid & 1;
  const int bm = blockIdx.y*128, bn = blockIdx.x*128;

  const int g0 = tid >> 7;
  const int r0 = tid & 127;
  const int arow = min(bm + r0, M-1);
  const int brow = bn + r0;
  const int lg = lane >> 4, lr = lane & 15;

  f32x4 acc[4][4];
  #pragma unroll
  for (int i = 0; i < 4; i++)
    #pragma unroll
    for (int j = 0; j < 4; j++)
      acc[i][j] = (f32x4){0.f,0.f,0.f,0.f};

  for (int k0 = 0; k0 < K; k0 += 32){
    const uint4 av0 = *reinterpret_cast<const uint4*>(A  + (size_t)arow*K + k0 + g0*8);
    const uint4 av1 = *reinterpret_cast<const uint4*>(A  + (size_t)arow*K + k0 + (g0+2)*8);
    const uint4 bv0 = *reinterpret_cast<const uint4*>(Bt + (size_t)brow*K + k0 + g0*8);
    const uint4 bv1 = *reinterpret_cast<const uint4*>(Bt + (size_t)brow*K + k0 + (g0+2)*8);
    __syncthreads();
    Alds[g0*128 + r0] = av0;  Alds[(g0+2)*128 + r0] = av1;
    Blds[g0*128 + r0] = bv0;  Blds[(g0+2)*128 + r0] = bv1;
    __syncthreads();

    bf16x8 af[4], bfr[4];
    #pragma unroll
    for (int mf = 0; mf < 4; mf++)
      af[mf] = *reinterpret_cast<const bf16x8*>(&Alds[lg*128 + wr*64 + mf*16 + lr]);
    #pragma unroll
    for (int nf = 0; nf < 4; nf++)
      bfr[nf] = *reinterpret_cast<const bf16x8*>(&Blds[lg*128 + wc*64 + nf*16 + lr]);

    #pragma unroll
    for (int mf = 0; mf < 4; mf++)
      #pragma unroll
      for (int nf = 0; nf < 4; nf++)
        acc[mf][nf] = __builtin_amdgcn_mfma_f32_16x16x32_bf16(af[mf], bfr[nf], acc[mf][nf], 0, 0, 0);
  }

  #pragma unroll
  for (int mf = 0; mf < 4; mf++){
    #pragma unroll
    for (int rg = 0; rg < 4; rg++){
      const int row = bm + wr*64 + mf*16 + (lane>>4)*4 + rg;
      if (row >= M) continue;
      #pragma unroll
      for (int nf = 0; nf < 4; nf++){
        const int col = bn + wc*64 + nf*16 + (lane&15);
        float v = acc[mf][nf][rg] + bias[col];
        if (ACT == 1) v = geluf(v);
        if (RESID)    v += resid[(size_t)row*N + col];
        if (BF16OUT)  reinterpret_cast<bf16*>(Cout)[(size_t)row*N + col] = __float2bfloat16(v);
        else          reinterpret_cast<float*>(Cout)[(size_t)row*N + col] = v;
      }
    }
  }
}

// ---------------- fp32 fallback GEMM (deproj: N=192) ----------------
template<typename TA, int ACT, int RESID, int BF16OUT>
__global__ __launch_bounds__(256) void gemm_k(const TA* __restrict__ A,
    const float* __restrict__ Bw, const float* __restrict__ bias,
    const float* __restrict__ resid, void* __restrict__ Cout, int M, int N, int K)
{
  __shared__ float As[16][65];
  __shared__ float Bs[16][65];
  const int bm = blockIdx.y*64, bn = blockIdx.x*64;
  const int tid = threadIdx.x;
  const int tr = tid >> 4, tc = tid & 15;

  const int am  = tid >> 2;
  const int ak4 = tid & 3;
  const int bk  = tid >> 4;
  const int bn4 = tid & 15;

  float acc[4][4] = {{0.f}};

  for (int k0 = 0; k0 < K; k0 += 16){
    const float4 av = ld4f(A + (size_t)(bm + am)*K + k0 + ak4*4);
    As[ak4*4+0][am] = av.x; As[ak4*4+1][am] = av.y;
    As[ak4*4+2][am] = av.z; As[ak4*4+3][am] = av.w;

    const float4 bv = ld4f(Bw + (size_t)(k0 + bk)*N + bn + bn4*4);
    Bs[bk][bn4*4+0] = bv.x; Bs[bk][bn4*4+1] = bv.y;
    Bs[bk][bn4*4+2] = bv.z; Bs[bk][bn4*4+3] = bv.w;
    __syncthreads();

    #pragma unroll
    for (int k = 0; k < 16; k++){
      float a[4], bb_[4];
      #pragma unroll
      for (int i = 0; i < 4; i++) a[i]  = As[k][tr*4 + i];
      #pragma unroll
      for (int j = 0; j < 4; j++) bb_[j] = Bs[k][tc*4 + j];
      #pragma unroll
      for (int i = 0; i < 4; i++)
        #pragma unroll
        for (int j = 0; j < 4; j++)
          acc[i][j] = fmaf(a[i], bb_[j], acc[i][j]);
    }
    __syncthreads();
  }

  #pragma unroll
  for (int i = 0; i < 4; i++){
    const int row = bm + tr*4 + i;
    #pragma unroll
    for (int j = 0; j < 4; j++){
      const int col = bn + tc*4 + j;
      float v = acc[i][j] + bias[col];
      if (ACT == 1) v = geluf(v);
      if (RESID)    v += resid[(size_t)row*N + col];
      if (BF16OUT)  reinterpret_cast<bf16*>(Cout)[(size_t)row*N + col] = __float2bfloat16(v);
      else          reinterpret_cast<float*>(Cout)[(size_t)row*N + col] = v;
    }
  }
}

// ---------------- LayerNorm over D=768: fp32 in -> bf16 out ----------------
__global__ __launch_bounds__(256) void layernorm_k(const float* __restrict__ x,
    const float* __restrict__ g, const float* __restrict__ bb, bf16* __restrict__ out)
{
  const int row = blockIdx.x;
  const float* xr = x + (size_t)row*D_;
  const int tid = threadIdx.x;
  const float v0 = xr[tid], v1 = xr[tid+256], v2 = xr[tid+512];

  float s = v0 + v1 + v2;
  #pragma unroll
  for (int o = 32; o > 0; o >>= 1) s += __shfl_xor(s, o);
  __shared__ float sm[4];
  const int wid = tid >> 6, lane = tid & 63;
  if (lane == 0) sm[wid] = s;
  __syncthreads();
  const float mean = (sm[0]+sm[1]+sm[2]+sm[3]) * (1.f/768.f);
  __syncthreads();

  const float d0 = v0-mean, d1 = v1-mean, d2 = v2-mean;
  float ss = d0*d0 + d1*d1 + d2*d2;
  #pragma unroll
  for (int o = 32; o > 0; o >>= 1) ss += __shfl_xor(ss, o);
  if (lane == 0) sm[wid] = ss;
  __syncthreads();
  const float var = (sm[0]+sm[1]+sm[2]+sm[3]) * (1.f/768.f);
  const float inv = rsqrtf(var + 1e-5f);

  bf16* orow = out + (size_t)row*D_;
  orow[tid]     = __float2bfloat16(d0*inv*g[tid]     + bb[tid]);
  orow[tid+256] = __float2bfloat16(d1*inv*g[tid+256] + bb[tid+256]);
  orow[tid+512] = __float2bfloat16(d2*inv*g[tid+512] + bb[tid+512]);
}

// ---------------- fused flash attention, K/V double-buffered (1 barrier/tile) ----------------
// srel[q,k]: k<=q -> q[q].er[499-(q-k)] ; k==q+1 -> 0 ; k>q+1 -> q[q+1].er[k-q-2]
#define LDW 68
__global__ __launch_bounds__(256) void flash_attn_k(const bf16* __restrict__ qb,
    const bf16* __restrict__ kb, const bf16* __restrict__ vb,
    const float* __restrict__ er, bf16* __restrict__ ob)
{
  const int b = blockIdx.y / NH_, h = blockIdx.y % NH_;
  const int q0 = blockIdx.x * 16;
  const int tid = threadIdx.x;
  const int qr = tid >> 4, kc = tid & 15;
  const int q  = q0 + qr;
  const bool qvalid = (q < T_);

  __shared__ float qs[17][LDW];
  __shared__ float ks[2][16][LDW];
  __shared__ float vs[2][16][LDW];

  // stage q rows q0..q0+16 (one extra for the k>q+1 branch)
  for (int i = tid; i < 17*16; i += 256){
    const int r = i >> 4, d4 = (i & 15) * 4;
    const int qq = q0 + r;
    float4 v = (qq < T_) ? ld4f(qb + ((size_t)(b*T_ + qq))*D_ + h*DH_ + d4)
                         : make_float4(0.f,0.f,0.f,0.f);
    qs[r][d4+0]=v.x; qs[r][d4+1]=v.y; qs[r][d4+2]=v.z; qs[r][d4+3]=v.w;
  }

  const int sr = tid >> 4, sd = (tid & 15) * 4;   // staging coords
  {  // tile 0 (rows 0..15 all valid)
    const float4 kv = ld4f(kb + ((size_t)(b*T_ + sr))*D_ + h*DH_ + sd);
    const float4 vv = ld4f(vb + ((size_t)(b*T_ + sr))*D_ + h*DH_ + sd);
    ks[0][sr][sd+0]=kv.x; ks[0][sr][sd+1]=kv.y; ks[0][sr][sd+2]=kv.z; ks[0][sr][sd+3]=kv.w;
    vs[0][sr][sd+0]=vv.x; vs[0][sr][sd+1]=vv.y; vs[0][sr][sd+2]=vv.z; vs[0][sr][sd+3]=vv.w;
  }
  __syncthreads();

  float m = -3.0e38f, l = 0.f;
  float oacc[4] = {0.f,0.f,0.f,0.f};
  int cur = 0;

  for (int k0 = 0; k0 < T_; k0 += 16){
    // issue next tile's loads early (T14: latency hides under compute)
    const bool pf = (k0 + 16 < T_);
    float4 nk = make_float4(0.f,0.f,0.f,0.f), nv = make_float4(0.f,0.f,0.f,0.f);
    if (pf){
      const int kk = k0 + 16 + sr;
      if (kk < T_){
        nk = ld4f(kb + ((size_t)(b*T_ + kk))*D_ + h*DH_ + sd);
        nv = ld4f(vb + ((size_t)(b*T_ + kk))*D_ + h*DH_ + sd);
      }
    }

    const int k = k0 + kc;
    const bool kvalid = (k < T_);
    float s = -3.0e38f;
    if (qvalid && kvalid){
      const float4* q4 = reinterpret_cast<const float4*>(&qs[qr][0]);
      const float4* k4 = reinterpret_cast<const float4*>(&ks[cur][kc][0]);
      float d1 = 0.f;
      #pragma unroll
      for (int i = 0; i < 16; i++){
        const float4 a = q4[i], c = k4[i];
        d1 = fmaf(a.x,c.x, fmaf(a.y,c.y, fmaf(a.z,c.z, fmaf(a.w,c.w, d1))));
      }
      float d2 = 0.f;
      if (k != q + 1){
        const int eidx = (k <= q) ? (499 - q + k) : (k - q - 2);
        const float4* t4 = reinterpret_cast<const float4*>(&qs[qr + ((k <= q) ? 0 : 1)][0]);
        const float* e = er + (size_t)eidx * DH_;
        #pragma unroll
        for (int i = 0; i < 16; i++){
          const float4 a = t4[i];
          const float4 ev = ld4f(e + i*4);
          d2 = fmaf(a.x,ev.x, fmaf(a.y,ev.y, fmaf(a.z,ev.z, fmaf(a.w,ev.w, d2))));
        }
      }
      s = (d1 + d2) * 0.125f;
    }

    // online softmax across this row's 16 lanes
    float mx = s;
    #pragma unroll
    for (int o = 8; o > 0; o >>= 1) mx = fmaxf(mx, __shfl_xor(mx, o, 16));
    const float mn = fmaxf(m, mx);
    const float p = kvalid ? __expf(s - mn) : 0.f;
    const float corr = __expf(m - mn);
    float ps = p;
    #pragma unroll
    for (int o = 8; o > 0; o >>= 1) ps += __shfl_xor(ps, o, 16);
    l = l*corr + ps;
    m = mn;
    #pragma unroll
    for (int j = 0; j < 4; j++) oacc[j] *= corr;

    #pragma unroll
    for (int kc2 = 0; kc2 < 16; kc2++){
      const float pk = __shfl(p, kc2, 16);
      const float4 vv = *reinterpret_cast<const float4*>(&vs[cur][kc2][kc*4]);
      oacc[0] = fmaf(pk, vv.x, oacc[0]);
      oacc[1] = fmaf(pk, vv.y, oacc[1]);
      oacc[2] = fmaf(pk, vv.z, oacc[2]);
      oacc[3] = fmaf(pk, vv.w, oacc[3]);
    }

    // write next tile into the other buffer; single barrier per tile
    if (pf){
      ks[cur^1][sr][sd+0]=nk.x; ks[cur^1][sr][sd+1]=nk.y; ks[cur^1][sr][sd+2]=nk.z; ks[cur^1][sr][sd+3]=nk.w;
      vs[cur^1][sr][sd+0]=nv.x; vs[cur^1][sr][sd+1]=nv.y; vs[cur^1][sr][sd+2]=nv.z; vs[cur^1][sr][sd+3]=nv.w;
    }
    __syncthreads();
    cur ^= 1;
  }

  if (qvalid){
    const float inv = 1.f / l;
    bf16* op = ob + ((size_t)(b*T_ + q))*D_ + h*DH_ + kc*4;
    ushort4 u;
    u.x = __bfloat16_as_ushort(__float2bfloat16(oacc[0]*inv));
    u.y = __bfloat16_as_ushort(__float2bfloat16(oacc[1]*inv));
    u.z = __bfloat16_as_ushort(__float2bfloat16(oacc[2]*inv));
    u.w = __bfloat16_as_ushort(__float2bfloat16(oacc[3]*inv));
    *reinterpret_cast<ushort4*>(op) = u;
  }
}

// =====================================================================
extern "C" void kernel_launch(void* const* d_in, const int* in_sizes, int n_in,
                              void* d_out, int out_size, void* d_ws, size_t ws_size,
                              hipStream_t stream)
{
  const float* spec  = (const float*)d_in[0];
  const float* cw1 = (const float*)d_in[1];  const float* cb1 = (const float*)d_in[2];
  const float* cw2 = (const float*)d_in[3];  const float* cb2 = (const float*)d_in[4];
  const float* cw3 = (const float*)d_in[5];  const float* cb3 = (const float*)d_in[6];
  const float* cw4 = (const float*)d_in[7];  const float* cb4 = (const float*)d_in[8];
  const float* proj_w = (const float*)d_in[9];  const float* proj_b = (const float*)d_in[10];
  const float* ln1_g = (const float*)d_in[11];  const float* ln1_b = (const float*)d_in[12];
  const float* wq = (const float*)d_in[13];  const float* bq = (const float*)d_in[14];
  const float* wk = (const float*)d_in[15];  const float* bk = (const float*)d_in[16];
  const float* wv = (const float*)d_in[17];  const float* bv = (const float*)d_in[18];
  const float* wo = (const float*)d_in[19];  const float* bo = (const float*)d_in[20];
  const float* er = (const float*)d_in[21];
  const float* ln2_g = (const float*)d_in[22];  const float* ln2_b = (const float*)d_in[23];
  const float* w1 = (const float*)d_in[24];  const float* b1 = (const float*)d_in[25];
  const float* w2 = (const float*)d_in[26];  const float* b2 = (const float*)d_in[27];
  const float* dw = (const float*)d_in[28];  const float* db = (const float*)d_in[29];

  if (ws_size < 98304000ull) return;
  char* W = (char*)d_ws;
  bf16*  n1 = (bf16*) (W + 0);          // [16][96][500][32]
  bf16*  n2 = (bf16*) (W + 49152000);   // [16][48][500][64]
  bf16*  n3 = (bf16*) (W + 0);          // [16][24][500][64]
  bf16*  n4 = (bf16*) (W + 24576000);   // [16][12][500][64]
  bf16*  tk = (bf16*) (W + 49152000);
  float* xb = (float*)(W + 0);
  bf16*  xn = (bf16*) (W + 24576000);
  bf16*  qb = (bf16*) (W + 36864000);
  bf16*  kb = (bf16*) (W + 49152000);
  bf16*  vb = (bf16*) (W + 61440000);
  bf16*  ob = (bf16*) (W + 73728000);
  bf16*  hb = (bf16*) (W + 36864000);
  bf16*  wt = (bf16*) (W + 86016000);
  // conv weight scratch in d_out (overwritten by deproj at the end)
  bf16* cwt2 = (bf16*)d_out;                          // 102.4 KB
  bf16* cwt3 = (bf16*)((char*)d_out + 262144);        // 204.8 KB
  bf16* cwt4 = (bf16*)((char*)d_out + 786432);        // 204.8 KB

  // ---- CNN stack (NHWC, MFMA for conv2-4) ----
  conv_wt_k<32><<<(25*32*64 + 255)/256, 256, 0, stream>>>(cw2, cwt2);
  conv_wt_k<64><<<(25*64*64 + 255)/256, 256, 0, stream>>>(cw3, cwt3);
  conv_wt_k<64><<<(25*64*64 + 255)/256, 256, 0, stream>>>(cw4, cwt4);

  conv1_k<<<(B_*96*500 + 255)/256, 256, 0, stream>>>(spec, cw1, cb1, n1);
  conv_mfma_k<32><<<dim3(8, B_*48), 256, 0, stream>>>(n1, cwt2, cb2, n2, 96);
  conv_mfma_k<64><<<dim3(8, B_*24), 256, 0, stream>>>(n2, cwt3, cb3, n3, 48);
  conv_mfma_k<64><<<dim3(8, B_*12), 256, 0, stream>>>(n3, cwt4, cb4, n4, 24);

  tokens_k<<<(B_*12*500*64 + 255)/256, 256, 0, stream>>>(n4, tk);

  transpose_w<<<dim3(D_/32, D_/32), 256, 0, stream>>>(proj_w, wt, D_, D_);
  mfma_gemm_k<0,0,0><<<dim3(6,63), 256, 0, stream>>>(tk, wt, proj_b, nullptr, xb, 8000, D_, D_);

  // ---- transformer layers ----
  for (int l = 0; l < 3; l++){
    const size_t wOff = (size_t)l*D_*D_;
    layernorm_k<<<8000, 256, 0, stream>>>(xb, ln1_g + l*D_, ln1_b + l*D_, xn);

    transpose_w<<<dim3(D_/32, D_/32), 256, 0, stream>>>(wq + wOff, wt, D_, D_);
    mfma_gemm_k<0,0,1><<<dim3(6,63), 256, 0, stream>>>(xn, wt, bq + l*D_, nullptr, qb, 8000, D_, D_);
    transpose_w<<<dim3(D_/32, D_/32), 256, 0, stream>>>(wk + wOff, wt, D_, D_);
    mfma_gemm_k<0,0,1><<<dim3(6,63), 256, 0, stream>>>(xn, wt, bk + l*D_, nullptr, kb, 8000, D_, D_);
    transpose_w<<<dim3(D_/32, D_/32), 256, 0, stream>>>(wv + wOff, wt, D_, D_);
    mfma_gemm_k<0,0,1><<<dim3(6,63), 256, 0, stream>>>(xn, wt, bv + l*D_, nullptr, vb, 8000, D_, D_);

    flash_attn_k<<<dim3(32, B_*NH_), 256, 0, stream>>>(qb, kb, vb, er + (size_t)l*T_*DH_, ob);

    transpose_w<<<dim3(D_/32, D_/32), 256, 0, stream>>>(wo + wOff, wt, D_, D_);
    mfma_gemm_k<0,1,0><<<dim3(6,63), 256, 0, stream>>>(ob, wt, bo + l*D_, xb, xb, 8000, D_, D_);

    layernorm_k<<<8000, 256, 0, stream>>>(xb, ln2_g + l*D_, ln2_b + l*D_, xn);

    transpose_w<<<dim3(FFN_/32, D_/32), 256, 0, stream>>>(w1 + (size_t)l*D_*FFN_, wt, D_, FFN_);
    mfma_gemm_k<1,0,1><<<dim3(24,63), 256, 0, stream>>>(xn, wt, b1 + l*FFN_, nullptr, hb, 8000, FFN_, D_);
    transpose_w<<<dim3(D_/32, FFN_/32), 256, 0, stream>>>(w2 + (size_t)l*FFN_*D_, wt, FFN_, D_);
    mfma_gemm_k<0,1,0><<<dim3(6,63), 256, 0, stream>>>(hb, wt, b2 + l*D_, xb, xb, 8000, D_, FFN_);
  }

  // ---- deproj -> fp32 output [8000, 192] ----
  gemm_k<float,0,0,0><<<dim3(192/64, 125), 256, 0, stream>>>(xb, dw, db, nullptr, d_out, 8000, 192, D_);
}

// Round 10
// 6351.777 us; speedup vs baseline: 5.1274x; 1.0022x over previous
//
#include <hip/hip_runtime.h>
#include <hip/hip_bf16.h>

typedef __hip_bfloat16 bf16;
typedef __attribute__((ext_vector_type(8))) short bf16x8;
typedef __attribute__((ext_vector_type(4))) float f32x4;

#define B_   16
#define T_   500
#define D_   768
#define NH_  12
#define DH_  64
#define FFN_ 3072

__device__ __forceinline__ float bfu2f(unsigned short u){ return __uint_as_float(((unsigned)u)<<16); }
__device__ __forceinline__ float geluf(float x){ return 0.5f*x*(1.0f + erff(x*0.70710678118654752f)); }

__device__ __forceinline__ float4 ld4f(const float* p){ return *reinterpret_cast<const float4*>(p); }
__device__ __forceinline__ float4 ld4f(const bf16* p){
  ushort4 u = *reinterpret_cast<const ushort4*>(p);
  return make_float4(bfu2f(u.x), bfu2f(u.y), bfu2f(u.z), bfu2f(u.w));
}

// ---------------- conv1: Cin=1, 32 oc per thread, writes NHWC [b][96][500][32] ----------------
__global__ __launch_bounds__(256) void conv1_k(const float* __restrict__ spec,
    const float* __restrict__ w, const float* __restrict__ bias, bf16* __restrict__ out)
{
  const int pos = blockIdx.x*256 + threadIdx.x;
  if (pos >= B_*96*500) return;
  const int x  = pos % 500;
  const int yo = (pos/500) % 96;
  const int b  = pos/(500*96);
  const float* ip = spec + (size_t)b*192*500;

  float v[6][5];
  #pragma unroll
  for (int r = 0; r < 6; r++){
    const int yy = 2*yo - 2 + r;
    const bool vy = (yy >= 0) && (yy < 192);
    const float* rp = ip + (size_t)(vy ? yy : 0)*500;
    #pragma unroll
    for (int c = 0; c < 5; c++){
      const int xx = x - 2 + c;
      v[r][c] = (vy && xx >= 0 && xx < 500) ? rp[xx] : 0.f;
    }
  }

  const size_t obase = (((size_t)(b*96 + yo))*500 + x)*32;
  #pragma unroll
  for (int oc = 0; oc < 32; oc++){
    float a0 = bias[oc], a1 = bias[oc];
    #pragma unroll
    for (int r = 0; r < 5; r++)
      #pragma unroll
      for (int c = 0; c < 5; c++){
        const float wv = w[oc*25 + r*5 + c];
        a0 = fmaf(v[r][c],   wv, a0);
        a1 = fmaf(v[r+1][c], wv, a1);
      }
    out[obase + oc] = __float2bfloat16(fmaxf(geluf(a0), geluf(a1)));
  }
}

// ---------------- conv weight repack: OIHW fp32 -> bf16 [tap][cg][nf][lane][8] ----------------
// element e = (((tap*(CIN/32)+cg)*4+nf)*64 + lane)*8 + j  holds  w[oc=nf*16+(lane&15)][ci=cg*32+(lane>>4)*8+j][tap]
template<int CIN>
__global__ __launch_bounds__(256) void conv_wt_k(const float* __restrict__ w, bf16* __restrict__ wt)
{
  const int e = blockIdx.x*256 + threadIdx.x;
  if (e >= 25*CIN*64) return;
  const int j    = e & 7;
  const int lane = (e >> 3) & 63;
  const int nf   = (e >> 9) & 3;
  const int t3   = e >> 11;
  const int cg   = t3 % (CIN/32);
  const int tap  = t3 / (CIN/32);
  const int oc = nf*16 + (lane & 15);
  const int ci = cg*32 + (lane >> 4)*8 + j;
  wt[e] = __float2bfloat16(w[(size_t)(oc*CIN + ci)*25 + tap]);
}

// ---------------- MFMA conv + GELU + pool, NHWC, LDS-staged branch-free inner loop ----------------
// Block: (b, yo, 64-x chunk) x 64 oc. LDS: 6 rows x 68 x x CIN bf16, XOR-swizzled (^(xx&7)<<4).
template<int CIN>
__global__ __launch_bounds__(256) void conv_mfma_k(const bf16* __restrict__ in,
    const bf16* __restrict__ wt, const float* __restrict__ bias,
    bf16* __restrict__ out, int Hin)
{
  constexpr int KB   = CIN/8;          // uint4 chunks per x
  constexpr int ROWB = 68*CIN*2;       // bytes per LDS row (low 7 bits zero)
  __shared__ uint4 ldsu[6*68*CIN/8];
  char* lds = (char*)ldsu;

  const int Hout = Hin >> 1;
  const int x0 = blockIdx.x * 64;
  const int yo = blockIdx.y % Hout;
  const int b  = blockIdx.y / Hout;
  const int tid = threadIdx.x, w = tid >> 6, lane = tid & 63;
  const int lr = lane & 15, kb = lane >> 4;

  // ---- stage input halo (zero-padded) ----
  for (int idx = tid; idx < 6*68*KB; idx += 256){
    const int kbb = idx % KB;
    const int xx  = (idx/KB) % 68;
    const int r   = idx/(KB*68);
    const int yy = 2*yo + r - 2;
    const int xg = x0 + xx - 2;
    uint4 v = make_uint4(0,0,0,0);
    if (yy >= 0 && yy < Hin && xg >= 0 && xg < 500)
      v = *reinterpret_cast<const uint4*>(in + (((size_t)(b*Hin + yy))*500 + xg)*CIN + kbb*8);
    int off = r*ROWB + xx*(CIN*2) + kbb*16;
    off ^= (xx & 7) << 4;
    *reinterpret_cast<uint4*>(lds + off) = v;
  }
  __syncthreads();

  f32x4 acc0[4], acc1[4];
  #pragma unroll
  for (int nf = 0; nf < 4; nf++){ acc0[nf] = (f32x4){0,0,0,0}; acc1[nf] = (f32x4){0,0,0,0}; }

  const int xl = w*16 + lr;
  #pragma unroll
  for (int ky = 0; ky < 5; ky++){
    #pragma unroll
    for (int kx = 0; kx < 5; kx++){
      const int xx = xl + kx;
      const int tap = ky*5 + kx;
      #pragma unroll
      for (int cg = 0; cg < CIN/32; cg++){
        int aoff = ky*ROWB + xx*(CIN*2) + (cg*32 + kb*8)*2;
        aoff ^= (xx & 7) << 4;
        const bf16x8 a0 = *reinterpret_cast<const bf16x8*>(lds + aoff);
        const bf16x8 a1 = *reinterpret_cast<const bf16x8*>(lds + aoff + ROWB);
        const bf16* bp = wt + ((size_t)((tap*(CIN/32) + cg)*4)*64 + lane)*8;
        #pragma unroll
        for (int nf = 0; nf < 4; nf++){
          const bf16x8 bf_ = *reinterpret_cast<const bf16x8*>(bp + nf*512);
          acc0[nf] = __builtin_amdgcn_mfma_f32_16x16x32_bf16(a0, bf_, acc0[nf], 0, 0, 0);
          acc1[nf] = __builtin_amdgcn_mfma_f32_16x16x32_bf16(a1, bf_, acc1[nf], 0, 0, 0);
        }
      }
    }
  }

  // epilogue: C/D row = kb*4+rg (x), col = lr (oc). pool(gelu) the two conv rows.
  #pragma unroll
  for (int rg = 0; rg < 4; rg++){
    const int xs = x0 + w*16 + kb*4 + rg;
    if (xs < 500){
      const size_t obase = (((size_t)(b*Hout + yo))*500 + xs)*64;
      #pragma unroll
      for (int nf = 0; nf < 4; nf++){
        const int oc = nf*16 + lr;
        const float bv = bias[oc];
        const float p0 = geluf(acc0[nf][rg] + bv);
        const float p1 = geluf(acc1[nf][rg] + bv);
        out[obase + oc] = __float2bfloat16(fmaxf(p0, p1));
      }
    }
  }
}

// ---------------- tokens: NHWC conv4 out [b][12][500][64] -> tk[b*T+t][ci*12+yo] ----------------
__global__ __launch_bounds__(256) void tokens_k(const bf16* __restrict__ n4, bf16* __restrict__ tk)
{
  const int idx = blockIdx.x*256 + threadIdx.x;
  if (idx >= B_*12*500*64) return;
  const int ci = idx & 63;
  const int t  = (idx >> 6) % 500;
  const int yo = (idx >> 6) / 500 % 12;
  const int b  = idx / (64*500*12);
  tk[((size_t)(b*500 + t))*768 + ci*12 + yo] = n4[idx];
}

// ---------------- weight transpose+convert: fp32 [K][N] -> bf16 [N][K] ----------------
__global__ __launch_bounds__(256) void transpose_w(const float* __restrict__ W,
    bf16* __restrict__ out, int K, int N)
{
  __shared__ float tile[32][33];
  const int gk = blockIdx.y*32, gn = blockIdx.x*32;
  const int tr = threadIdx.x >> 5, tc = threadIdx.x & 31;
  #pragma unroll
  for (int i = 0; i < 4; i++)
    tile[tr + i*8][tc] = W[(size_t)(gk + tr + i*8)*N + gn + tc];
  __syncthreads();
  #pragma unroll
  for (int i = 0; i < 4; i++)
    out[(size_t)(gn + tr + i*8)*K + gk + tc] = __float2bfloat16(tile[tc][tr + i*8]);
}

// ---------------- MFMA GEMM: C = act(A[MxK](bf16) @ Bt[NxK]^T(bf16) + bias) (+resid) ----------------
template<int ACT, int RESID, int BF16OUT>
__global__ __launch_bounds__(256) void mfma_gemm_k(const bf16* __restrict__ A,
    const bf16* __restrict__ Bt, const float* __restrict__ bias,
    const float* __restrict__ resid, void* __restrict__ Cout, int M, int N, int K)
{
  __shared__ uint4 Alds[512];
  __shared__ uint4 Blds[512];

  const int tid = threadIdx.x;
  const int wid = tid >> 6, lane = tid & 63;
  const int wr = wid >> 1, wc = wid & 1;
  const int bm = blockIdx.y*128, bn = blockIdx.x*128;

  const int g0 = tid >> 7;
  const int r0 = tid & 127;
  const int arow = min(bm + r0, M-1);
  const int brow = bn + r0;
  const int lg = lane >> 4, lr = lane & 15;

  f32x4 acc[4][4];
  #pragma unroll
  for (int i = 0; i < 4; i++)
    #pragma unroll
    for (int j = 0; j < 4; j++)
      acc[i][j] = (f32x4){0.f,0.f,0.f,0.f};

  for (int k0 = 0; k0 < K; k0 += 32){
    const uint4 av0 = *reinterpret_cast<const uint4*>(A  + (size_t)arow*K + k0 + g0*8);
    const uint4 av1 = *reinterpret_cast<const uint4*>(A  + (size_t)arow*K + k0 + (g0+2)*8);
    const uint4 bv0 = *reinterpret_cast<const uint4*>(Bt + (size_t)brow*K + k0 + g0*8);
    const uint4 bv1 = *reinterpret_cast<const uint4*>(Bt + (size_t)brow*K + k0 + (g0+2)*8);
    __syncthreads();
    Alds[g0*128 + r0] = av0;  Alds[(g0+2)*128 + r0] = av1;
    Blds[g0*128 + r0] = bv0;  Blds[(g0+2)*128 + r0] = bv1;
    __syncthreads();

    bf16x8 af[4], bfr[4];
    #pragma unroll
    for (int mf = 0; mf < 4; mf++)
      af[mf] = *reinterpret_cast<const bf16x8*>(&Alds[lg*128 + wr*64 + mf*16 + lr]);
    #pragma unroll
    for (int nf = 0; nf < 4; nf++)
      bfr[nf] = *reinterpret_cast<const bf16x8*>(&Blds[lg*128 + wc*64 + nf*16 + lr]);

    #pragma unroll
    for (int mf = 0; mf < 4; mf++)
      #pragma unroll
      for (int nf = 0; nf < 4; nf++)
        acc[mf][nf] = __builtin_amdgcn_mfma_f32_16x16x32_bf16(af[mf], bfr[nf], acc[mf][nf], 0, 0, 0);
  }

  #pragma unroll
  for (int mf = 0; mf < 4; mf++){
    #pragma unroll
    for (int rg = 0; rg < 4; rg++){
      const int row = bm + wr*64 + mf*16 + (lane>>4)*4 + rg;
      if (row >= M) continue;
      #pragma unroll
      for (int nf = 0; nf < 4; nf++){
        const int col = bn + wc*64 + nf*16 + (lane&15);
        float v = acc[mf][nf][rg] + bias[col];
        if (ACT == 1) v = geluf(v);
        if (RESID)    v += resid[(size_t)row*N + col];
        if (BF16OUT)  reinterpret_cast<bf16*>(Cout)[(size_t)row*N + col] = __float2bfloat16(v);
        else          reinterpret_cast<float*>(Cout)[(size_t)row*N + col] = v;
      }
    }
  }
}

// ---------------- fp32 fallback GEMM (deproj: N=192) ----------------
template<typename TA, int ACT, int RESID, int BF16OUT>
__global__ __launch_bounds__(256) void gemm_k(const TA* __restrict__ A,
    const float* __restrict__ Bw, const float* __restrict__ bias,
    const float* __restrict__ resid, void* __restrict__ Cout, int M, int N, int K)
{
  __shared__ float As[16][65];
  __shared__ float Bs[16][65];
  const int bm = blockIdx.y*64, bn = blockIdx.x*64;
  const int tid = threadIdx.x;
  const int tr = tid >> 4, tc = tid & 15;

  const int am  = tid >> 2;
  const int ak4 = tid & 3;
  const int bk  = tid >> 4;
  const int bn4 = tid & 15;

  float acc[4][4] = {{0.f}};

  for (int k0 = 0; k0 < K; k0 += 16){
    const float4 av = ld4f(A + (size_t)(bm + am)*K + k0 + ak4*4);
    As[ak4*4+0][am] = av.x; As[ak4*4+1][am] = av.y;
    As[ak4*4+2][am] = av.z; As[ak4*4+3][am] = av.w;

    const float4 bv = ld4f(Bw + (size_t)(k0 + bk)*N + bn + bn4*4);
    Bs[bk][bn4*4+0] = bv.x; Bs[bk][bn4*4+1] = bv.y;
    Bs[bk][bn4*4+2] = bv.z; Bs[bk][bn4*4+3] = bv.w;
    __syncthreads();

    #pragma unroll
    for (int k = 0; k < 16; k++){
      float a[4], bb_[4];
      #pragma unroll
      for (int i = 0; i < 4; i++) a[i]  = As[k][tr*4 + i];
      #pragma unroll
      for (int j = 0; j < 4; j++) bb_[j] = Bs[k][tc*4 + j];
      #pragma unroll
      for (int i = 0; i < 4; i++)
        #pragma unroll
        for (int j = 0; j < 4; j++)
          acc[i][j] = fmaf(a[i], bb_[j], acc[i][j]);
    }
    __syncthreads();
  }

  #pragma unroll
  for (int i = 0; i < 4; i++){
    const int row = bm + tr*4 + i;
    #pragma unroll
    for (int j = 0; j < 4; j++){
      const int col = bn + tc*4 + j;
      float v = acc[i][j] + bias[col];
      if (ACT == 1) v = geluf(v);
      if (RESID)    v += resid[(size_t)row*N + col];
      if (BF16OUT)  reinterpret_cast<bf16*>(Cout)[(size_t)row*N + col] = __float2bfloat16(v);
      else          reinterpret_cast<float*>(Cout)[(size_t)row*N + col] = v;
    }
  }
}

// ---------------- LayerNorm over D=768: fp32 in -> bf16 out ----------------
__global__ __launch_bounds__(256) void layernorm_k(const float* __restrict__ x,
    const float* __restrict__ g, const float* __restrict__ bb, bf16* __restrict__ out)
{
  const int row = blockIdx.x;
  const float* xr = x + (size_t)row*D_;
  const int tid = threadIdx.x;
  const float v0 = xr[tid], v1 = xr[tid+256], v2 = xr[tid+512];

  float s = v0 + v1 + v2;
  #pragma unroll
  for (int o = 32; o > 0; o >>= 1) s += __shfl_xor(s, o);
  __shared__ float sm[4];
  const int wid = tid >> 6, lane = tid & 63;
  if (lane == 0) sm[wid] = s;
  __syncthreads();
  const float mean = (sm[0]+sm[1]+sm[2]+sm[3]) * (1.f/768.f);
  __syncthreads();

  const float d0 = v0-mean, d1 = v1-mean, d2 = v2-mean;
  float ss = d0*d0 + d1*d1 + d2*d2;
  #pragma unroll
  for (int o = 32; o > 0; o >>= 1) ss += __shfl_xor(ss, o);
  if (lane == 0) sm[wid] = ss;
  __syncthreads();
  const float var = (sm[0]+sm[1]+sm[2]+sm[3]) * (1.f/768.f);
  const float inv = rsqrtf(var + 1e-5f);

  bf16* orow = out + (size_t)row*D_;
  orow[tid]     = __float2bfloat16(d0*inv*g[tid]     + bb[tid]);
  orow[tid+256] = __float2bfloat16(d1*inv*g[tid+256] + bb[tid+256]);
  orow[tid+512] = __float2bfloat16(d2*inv*g[tid+512] + bb[tid+512]);
}

// ---------------- fused flash attention, K/V double-buffered (1 barrier/tile) ----------------
// srel[q,k]: k<=q -> q[q].er[499-(q-k)] ; k==q+1 -> 0 ; k>q+1 -> q[q+1].er[k-q-2]
#define LDW 68
__global__ __launch_bounds__(256) void flash_attn_k(const bf16* __restrict__ qb,
    const bf16* __restrict__ kb, const bf16* __restrict__ vb,
    const float* __restrict__ er, bf16* __restrict__ ob)
{
  const int b = blockIdx.y / NH_, h = blockIdx.y % NH_;
  const int q0 = blockIdx.x * 16;
  const int tid = threadIdx.x;
  const int qr = tid >> 4, kc = tid & 15;
  const int q  = q0 + qr;
  const bool qvalid = (q < T_);

  __shared__ float qs[17][LDW];
  __shared__ float ks[2][16][LDW];
  __shared__ float vs[2][16][LDW];

  // stage q rows q0..q0+16 (one extra for the k>q+1 branch)
  for (int i = tid; i < 17*16; i += 256){
    const int r = i >> 4, d4 = (i & 15) * 4;
    const int qq = q0 + r;
    float4 v = (qq < T_) ? ld4f(qb + ((size_t)(b*T_ + qq))*D_ + h*DH_ + d4)
                         : make_float4(0.f,0.f,0.f,0.f);
    qs[r][d4+0]=v.x; qs[r][d4+1]=v.y; qs[r][d4+2]=v.z; qs[r][d4+3]=v.w;
  }

  const int sr = tid >> 4, sd = (tid & 15) * 4;   // staging coords
  {  // tile 0 (rows 0..15 all valid)
    const float4 kv = ld4f(kb + ((size_t)(b*T_ + sr))*D_ + h*DH_ + sd);
    const float4 vv = ld4f(vb + ((size_t)(b*T_ + sr))*D_ + h*DH_ + sd);
    ks[0][sr][sd+0]=kv.x; ks[0][sr][sd+1]=kv.y; ks[0][sr][sd+2]=kv.z; ks[0][sr][sd+3]=kv.w;
    vs[0][sr][sd+0]=vv.x; vs[0][sr][sd+1]=vv.y; vs[0][sr][sd+2]=vv.z; vs[0][sr][sd+3]=vv.w;
  }
  __syncthreads();

  float m = -3.0e38f, l = 0.f;
  float oacc[4] = {0.f,0.f,0.f,0.f};
  int cur = 0;

  for (int k0 = 0; k0 < T_; k0 += 16){
    // issue next tile's loads early (T14: latency hides under compute)
    const bool pf = (k0 + 16 < T_);
    float4 nk = make_float4(0.f,0.f,0.f,0.f), nv = make_float4(0.f,0.f,0.f,0.f);
    if (pf){
      const int kk = k0 + 16 + sr;
      if (kk < T_){
        nk = ld4f(kb + ((size_t)(b*T_ + kk))*D_ + h*DH_ + sd);
        nv = ld4f(vb + ((size_t)(b*T_ + kk))*D_ + h*DH_ + sd);
      }
    }

    const int k = k0 + kc;
    const bool kvalid = (k < T_);
    float s = -3.0e38f;
    if (qvalid && kvalid){
      const float4* q4 = reinterpret_cast<const float4*>(&qs[qr][0]);
      const float4* k4 = reinterpret_cast<const float4*>(&ks[cur][kc][0]);
      float d1 = 0.f;
      #pragma unroll
      for (int i = 0; i < 16; i++){
        const float4 a = q4[i], c = k4[i];
        d1 = fmaf(a.x,c.x, fmaf(a.y,c.y, fmaf(a.z,c.z, fmaf(a.w,c.w, d1))));
      }
      float d2 = 0.f;
      if (k != q + 1){
        const int eidx = (k <= q) ? (499 - q + k) : (k - q - 2);
        const float4* t4 = reinterpret_cast<const float4*>(&qs[qr + ((k <= q) ? 0 : 1)][0]);
        const float* e = er + (size_t)eidx * DH_;
        #pragma unroll
        for (int i = 0; i < 16; i++){
          const float4 a = t4[i];
          const float4 ev = ld4f(e + i*4);
          d2 = fmaf(a.x,ev.x, fmaf(a.y,ev.y, fmaf(a.z,ev.z, fmaf(a.w,ev.w, d2))));
        }
      }
      s = (d1 + d2) * 0.125f;
    }

    // online softmax across this row's 16 lanes
    float mx = s;
    #pragma unroll
    for (int o = 8; o > 0; o >>= 1) mx = fmaxf(mx, __shfl_xor(mx, o, 16));
    const float mn = fmaxf(m, mx);
    const float p = kvalid ? __expf(s - mn) : 0.f;
    const float corr = __expf(m - mn);
    float ps = p;
    #pragma unroll
    for (int o = 8; o > 0; o >>= 1) ps += __shfl_xor(ps, o, 16);
    l = l*corr + ps;
    m = mn;
    #pragma unroll
    for (int j = 0; j < 4; j++) oacc[j] *= corr;

    #pragma unroll
    for (int kc2 = 0; kc2 < 16; kc2++){
      const float pk = __shfl(p, kc2, 16);
      const float4 vv = *reinterpret_cast<const float4*>(&vs[cur][kc2][kc*4]);
      oacc[0] = fmaf(pk, vv.x, oacc[0]);
      oacc[1] = fmaf(pk, vv.y, oacc[1]);
      oacc[2] = fmaf(pk, vv.z, oacc[2]);
      oacc[3] = fmaf(pk, vv.w, oacc[3]);
    }

    // write next tile into the other buffer; single barrier per tile
    if (pf){
      ks[cur^1][sr][sd+0]=nk.x; ks[cur^1][sr][sd+1]=nk.y; ks[cur^1][sr][sd+2]=nk.z; ks[cur^1][sr][sd+3]=nk.w;
      vs[cur^1][sr][sd+0]=nv.x; vs[cur^1][sr][sd+1]=nv.y; vs[cur^1][sr][sd+2]=nv.z; vs[cur^1][sr][sd+3]=nv.w;
    }
    __syncthreads();
    cur ^= 1;
  }

  if (qvalid){
    const float inv = 1.f / l;
    bf16* op = ob + ((size_t)(b*T_ + q))*D_ + h*DH_ + kc*4;
    ushort4 u;
    u.x = __bfloat16_as_ushort(__float2bfloat16(oacc[0]*inv));
    u.y = __bfloat16_as_ushort(__float2bfloat16(oacc[1]*inv));
    u.z = __bfloat16_as_ushort(__float2bfloat16(oacc[2]*inv));
    u.w = __bfloat16_as_ushort(__float2bfloat16(oacc[3]*inv));
    *reinterpret_cast<ushort4*>(op) = u;
  }
}

// =====================================================================
extern "C" void kernel_launch(void* const* d_in, const int* in_sizes, int n_in,
                              void* d_out, int out_size, void* d_ws, size_t ws_size,
                              hipStream_t stream)
{
  const float* spec  = (const float*)d_in[0];
  const float* cw1 = (const float*)d_in[1];  const float* cb1 = (const float*)d_in[2];
  const float* cw2 = (const float*)d_in[3];  const float* cb2 = (const float*)d_in[4];
  const float* cw3 = (const float*)d_in[5];  const float* cb3 = (const float*)d_in[6];
  const float* cw4 = (const float*)d_in[7];  const float* cb4 = (const float*)d_in[8];
  const float* proj_w = (const float*)d_in[9];  const float* proj_b = (const float*)d_in[10];
  const float* ln1_g = (const float*)d_in[11];  const float* ln1_b = (const float*)d_in[12];
  const float* wq = (const float*)d_in[13];  const float* bq = (const float*)d_in[14];
  const float* wk = (const float*)d_in[15];  const float* bk = (const float*)d_in[16];
  const float* wv = (const float*)d_in[17];  const float* bv = (const float*)d_in[18];
  const float* wo = (const float*)d_in[19];  const float* bo = (const float*)d_in[20];
  const float* er = (const float*)d_in[21];
  const float* ln2_g = (const float*)d_in[22];  const float* ln2_b = (const float*)d_in[23];
  const float* w1 = (const float*)d_in[24];  const float* b1 = (const float*)d_in[25];
  const float* w2 = (const float*)d_in[26];  const float* b2 = (const float*)d_in[27];
  const float* dw = (const float*)d_in[28];  const float* db = (const float*)d_in[29];

  if (ws_size < 98304000ull) return;
  char* W = (char*)d_ws;
  bf16*  n1 = (bf16*) (W + 0);          // [16][96][500][32]
  bf16*  n2 = (bf16*) (W + 49152000);   // [16][48][500][64]
  bf16*  n3 = (bf16*) (W + 0);          // [16][24][500][64]
  bf16*  n4 = (bf16*) (W + 24576000);   // [16][12][500][64]
  bf16*  tk = (bf16*) (W + 49152000);
  float* xb = (float*)(W + 0);
  bf16*  xn = (bf16*) (W + 24576000);
  bf16*  qb = (bf16*) (W + 36864000);
  bf16*  kb = (bf16*) (W + 49152000);
  bf16*  vb = (bf16*) (W + 61440000);
  bf16*  ob = (bf16*) (W + 73728000);
  bf16*  hb = (bf16*) (W + 36864000);
  bf16*  wt = (bf16*) (W + 86016000);
  // conv weight scratch in d_out (overwritten by deproj at the end)
  bf16* cwt2 = (bf16*)d_out;                          // 102.4 KB
  bf16* cwt3 = (bf16*)((char*)d_out + 262144);        // 204.8 KB
  bf16* cwt4 = (bf16*)((char*)d_out + 786432);        // 204.8 KB

  // ---- CNN stack (NHWC, MFMA for conv2-4) ----
  conv_wt_k<32><<<(25*32*64 + 255)/256, 256, 0, stream>>>(cw2, cwt2);
  conv_wt_k<64><<<(25*64*64 + 255)/256, 256, 0, stream>>>(cw3, cwt3);
  conv_wt_k<64><<<(25*64*64 + 255)/256, 256, 0, stream>>>(cw4, cwt4);

  conv1_k<<<(B_*96*500 + 255)/256, 256, 0, stream>>>(spec, cw1, cb1, n1);
  conv_mfma_k<32><<<dim3(8, B_*48), 256, 0, stream>>>(n1, cwt2, cb2, n2, 96);
  conv_mfma_k<64><<<dim3(8, B_*24), 256, 0, stream>>>(n2, cwt3, cb3, n3, 48);
  conv_mfma_k<64><<<dim3(8, B_*12), 256, 0, stream>>>(n3, cwt4, cb4, n4, 24);

  tokens_k<<<(B_*12*500*64 + 255)/256, 256, 0, stream>>>(n4, tk);

  transpose_w<<<dim3(D_/32, D_/32), 256, 0, stream>>>(proj_w, wt, D_, D_);
  mfma_gemm_k<0,0,0><<<dim3(6,63), 256, 0, stream>>>(tk, wt, proj_b, nullptr, xb, 8000, D_, D_);

  // ---- transformer layers ----
  for (int l = 0; l < 3; l++){
    const size_t wOff = (size_t)l*D_*D_;
    layernorm_k<<<8000, 256, 0, stream>>>(xb, ln1_g + l*D_, ln1_b + l*D_, xn);

    transpose_w<<<dim3(D_/32, D_/32), 256, 0, stream>>>(wq + wOff, wt, D_, D_);
    mfma_gemm_k<0,0,1><<<dim3(6,63), 256, 0, stream>>>(xn, wt, bq + l*D_, nullptr, qb, 8000, D_, D_);
    transpose_w<<<dim3(D_/32, D_/32), 256, 0, stream>>>(wk + wOff, wt, D_, D_);
    mfma_gemm_k<0,0,1><<<dim3(6,63), 256, 0, stream>>>(xn, wt, bk + l*D_, nullptr, kb, 8000, D_, D_);
    transpose_w<<<dim3(D_/32, D_/32), 256, 0, stream>>>(wv + wOff, wt, D_, D_);
    mfma_gemm_k<0,0,1><<<dim3(6,63), 256, 0, stream>>>(xn, wt, bv + l*D_, nullptr, vb, 8000, D_, D_);

    flash_attn_k<<<dim3(32, B_*NH_), 256, 0, stream>>>(qb, kb, vb, er + (size_t)l*T_*DH_, ob);

    transpose_w<<<dim3(D_/32, D_/32), 256, 0, stream>>>(wo + wOff, wt, D_, D_);
    mfma_gemm_k<0,1,0><<<dim3(6,63), 256, 0, stream>>>(ob, wt, bo + l*D_, xb, xb, 8000, D_, D_);

    layernorm_k<<<8000, 256, 0, stream>>>(xb, ln2_g + l*D_, ln2_b + l*D_, xn);

    transpose_w<<<dim3(FFN_/32, D_/32), 256, 0, stream>>>(w1 + (size_t)l*D_*FFN_, wt, D_, FFN_);
    mfma_gemm_k<1,0,1><<<dim3(24,63), 256, 0, stream>>>(xn, wt, b1 + l*FFN_, nullptr, hb, 8000, FFN_, D_);
    transpose_w<<<dim3(D_/32, FFN_/32), 256, 0, stream>>>(w2 + (size_t)l*FFN_*D_, wt, FFN_, D_);
    mfma_gemm_k<0,1,0><<<dim3(6,63), 256, 0, stream>>>(hb, wt, b2 + l*D_, xb, xb, 8000, D_, FFN_);
  }

  // ---- deproj -> fp32 output [8000, 192] ----
  gemm_k<float,0,0,0><<<dim3(192/64, 125), 256, 0, stream>>>(xb, dw, db, nullptr, d_out, 8000, 192, D_);
}

// Round 12
// 4198.055 us; speedup vs baseline: 7.7579x; 1.5130x over previous
//
#include <hip/hip_runtime.h>
#include <hip/hip_bf16.h>

typedef __hip_bfloat16 bf16;
typedef __attribute__((ext_vector_type(8))) short bf16x8;
typedef __attribute__((ext_vector_type(4))) float f32x4;

#define B_   16
#define T_   500
#define D_   768
#define NH_  12
#define DH_  64
#define FFN_ 3072

__device__ __forceinline__ float bfu2f(unsigned short u){ return __uint_as_float(((unsigned)u)<<16); }
__device__ __forceinline__ float geluf(float x){ return 0.5f*x*(1.0f + erff(x*0.70710678118654752f)); }

__device__ __forceinline__ float4 ld4f(const float* p){ return *reinterpret_cast<const float4*>(p); }
__device__ __forceinline__ float4 ld4f(const bf16* p){
  ushort4 u = *reinterpret_cast<const ushort4*>(p);
  return make_float4(bfu2f(u.x), bfu2f(u.y), bfu2f(u.z), bfu2f(u.w));
}

// ---------------- conv1: Cin=1, 32 oc per thread, writes NHWC [b][96][500][32] ----------------
__global__ __launch_bounds__(256) void conv1_k(const float* __restrict__ spec,
    const float* __restrict__ w, const float* __restrict__ bias, bf16* __restrict__ out)
{
  const int pos = blockIdx.x*256 + threadIdx.x;
  if (pos >= B_*96*500) return;
  const int x  = pos % 500;
  const int yo = (pos/500) % 96;
  const int b  = pos/(500*96);
  const float* ip = spec + (size_t)b*192*500;

  float v[6][5];
  #pragma unroll
  for (int r = 0; r < 6; r++){
    const int yy = 2*yo - 2 + r;
    const bool vy = (yy >= 0) && (yy < 192);
    const float* rp = ip + (size_t)(vy ? yy : 0)*500;
    #pragma unroll
    for (int c = 0; c < 5; c++){
      const int xx = x - 2 + c;
      v[r][c] = (vy && xx >= 0 && xx < 500) ? rp[xx] : 0.f;
    }
  }

  const size_t obase = (((size_t)(b*96 + yo))*500 + x)*32;
  #pragma unroll
  for (int oc = 0; oc < 32; oc++){
    float a0 = bias[oc], a1 = bias[oc];
    #pragma unroll
    for (int r = 0; r < 5; r++)
      #pragma unroll
      for (int c = 0; c < 5; c++){
        const float wv = w[oc*25 + r*5 + c];
        a0 = fmaf(v[r][c],   wv, a0);
        a1 = fmaf(v[r+1][c], wv, a1);
      }
    out[obase + oc] = __float2bfloat16(fmaxf(geluf(a0), geluf(a1)));
  }
}

// ---------------- conv weight repack: OIHW fp32 -> bf16 [tap][cg][nf][lane][8] ----------------
template<int CIN>
__global__ __launch_bounds__(256) void conv_wt_k(const float* __restrict__ w, bf16* __restrict__ wt)
{
  const int e = blockIdx.x*256 + threadIdx.x;
  if (e >= 25*CIN*64) return;
  const int j    = e & 7;
  const int lane = (e >> 3) & 63;
  const int nf   = (e >> 9) & 3;
  const int t3   = e >> 11;
  const int cg   = t3 % (CIN/32);
  const int tap  = t3 / (CIN/32);
  const int oc = nf*16 + (lane & 15);
  const int ci = cg*32 + (lane >> 4)*8 + j;
  wt[e] = __float2bfloat16(w[(size_t)(oc*CIN + ci)*25 + tap]);
}

// ---------------- MFMA conv + GELU + pool, NHWC, LDS-staged branch-free inner loop ----------------
template<int CIN>
__global__ __launch_bounds__(256) void conv_mfma_k(const bf16* __restrict__ in,
    const bf16* __restrict__ wt, const float* __restrict__ bias,
    bf16* __restrict__ out, int Hin)
{
  constexpr int KB   = CIN/8;
  constexpr int ROWB = 68*CIN*2;
  __shared__ uint4 ldsu[6*68*CIN/8];
  char* lds = (char*)ldsu;

  const int Hout = Hin >> 1;
  const int x0 = blockIdx.x * 64;
  const int yo = blockIdx.y % Hout;
  const int b  = blockIdx.y / Hout;
  const int tid = threadIdx.x, w = tid >> 6, lane = tid & 63;
  const int lr = lane & 15, kb = lane >> 4;

  for (int idx = tid; idx < 6*68*KB; idx += 256){
    const int kbb = idx % KB;
    const int xx  = (idx/KB) % 68;
    const int r   = idx/(KB*68);
    const int yy = 2*yo + r - 2;
    const int xg = x0 + xx - 2;
    uint4 v = make_uint4(0,0,0,0);
    if (yy >= 0 && yy < Hin && xg >= 0 && xg < 500)
      v = *reinterpret_cast<const uint4*>(in + (((size_t)(b*Hin + yy))*500 + xg)*CIN + kbb*8);
    int off = r*ROWB + xx*(CIN*2) + kbb*16;
    off ^= (xx & 7) << 4;
    *reinterpret_cast<uint4*>(lds + off) = v;
  }
  __syncthreads();

  f32x4 acc0[4], acc1[4];
  #pragma unroll
  for (int nf = 0; nf < 4; nf++){ acc0[nf] = (f32x4){0,0,0,0}; acc1[nf] = (f32x4){0,0,0,0}; }

  const int xl = w*16 + lr;
  #pragma unroll
  for (int ky = 0; ky < 5; ky++){
    #pragma unroll
    for (int kx = 0; kx < 5; kx++){
      const int xx = xl + kx;
      const int tap = ky*5 + kx;
      #pragma unroll
      for (int cg = 0; cg < CIN/32; cg++){
        int aoff = ky*ROWB + xx*(CIN*2) + (cg*32 + kb*8)*2;
        aoff ^= (xx & 7) << 4;
        const bf16x8 a0 = *reinterpret_cast<const bf16x8*>(lds + aoff);
        const bf16x8 a1 = *reinterpret_cast<const bf16x8*>(lds + aoff + ROWB);
        const bf16* bp = wt + ((size_t)((tap*(CIN/32) + cg)*4)*64 + lane)*8;
        #pragma unroll
        for (int nf = 0; nf < 4; nf++){
          const bf16x8 bf_ = *reinterpret_cast<const bf16x8*>(bp + nf*512);
          acc0[nf] = __builtin_amdgcn_mfma_f32_16x16x32_bf16(a0, bf_, acc0[nf], 0, 0, 0);
          acc1[nf] = __builtin_amdgcn_mfma_f32_16x16x32_bf16(a1, bf_, acc1[nf], 0, 0, 0);
        }
      }
    }
  }

  #pragma unroll
  for (int rg = 0; rg < 4; rg++){
    const int xs = x0 + w*16 + kb*4 + rg;
    if (xs < 500){
      const size_t obase = (((size_t)(b*Hout + yo))*500 + xs)*64;
      #pragma unroll
      for (int nf = 0; nf < 4; nf++){
        const int oc = nf*16 + lr;
        const float bv = bias[oc];
        const float p0 = geluf(acc0[nf][rg] + bv);
        const float p1 = geluf(acc1[nf][rg] + bv);
        out[obase + oc] = __float2bfloat16(fmaxf(p0, p1));
      }
    }
  }
}

// ---------------- tokens: NHWC conv4 out -> tk[b*T+t][ci*12+yo] ----------------
__global__ __launch_bounds__(256) void tokens_k(const bf16* __restrict__ n4, bf16* __restrict__ tk)
{
  const int idx = blockIdx.x*256 + threadIdx.x;
  if (idx >= B_*12*500*64) return;
  const int ci = idx & 63;
  const int t  = (idx >> 6) % 500;
  const int yo = (idx >> 6) / 500 % 12;
  const int b  = idx / (64*500*12);
  tk[((size_t)(b*500 + t))*768 + ci*12 + yo] = n4[idx];
}

// ---------------- er fp32 -> bf16 ----------------
__global__ __launch_bounds__(256) void er2bf_k(const float* __restrict__ er, bf16* __restrict__ out)
{
  const int idx = blockIdx.x*256 + threadIdx.x;
  if (idx < T_*DH_) out[idx] = __float2bfloat16(er[idx]);
}

// ---------------- fp32 -> bf16 bulk cast (vectorized) ----------------
__global__ __launch_bounds__(256) void f2bf_k(const float* __restrict__ x, bf16* __restrict__ out, int n4)
{
  const int idx = blockIdx.x*256 + threadIdx.x;
  if (idx >= n4) return;
  const float4 v = *reinterpret_cast<const float4*>(x + idx*4);
  ushort4 u;
  u.x = __bfloat16_as_ushort(__float2bfloat16(v.x));
  u.y = __bfloat16_as_ushort(__float2bfloat16(v.y));
  u.z = __bfloat16_as_ushort(__float2bfloat16(v.z));
  u.w = __bfloat16_as_ushort(__float2bfloat16(v.w));
  *reinterpret_cast<ushort4*>(out + idx*4) = u;
}

// ---------------- weight transpose+convert: fp32 [K][N] -> bf16 [N][K] ----------------
__global__ __launch_bounds__(256) void transpose_w(const float* __restrict__ W,
    bf16* __restrict__ out, int K, int N)
{
  __shared__ float tile[32][33];
  const int gk = blockIdx.y*32, gn = blockIdx.x*32;
  const int tr = threadIdx.x >> 5, tc = threadIdx.x & 31;
  #pragma unroll
  for (int i = 0; i < 4; i++)
    tile[tr + i*8][tc] = W[(size_t)(gk + tr + i*8)*N + gn + tc];
  __syncthreads();
  #pragma unroll
  for (int i = 0; i < 4; i++)
    out[(size_t)(gn + tr + i*8)*K + gk + tc] = __float2bfloat16(tile[tc][tr + i*8]);
}

// ---------------- MFMA GEMM: C = act(A[MxK](bf16) @ Bt[NxK]^T(bf16) + bias) (+resid) ----------------
template<int ACT, int RESID, int BF16OUT>
__global__ __launch_bounds__(256) void mfma_gemm_k(const bf16* __restrict__ A,
    const bf16* __restrict__ Bt, const float* __restrict__ bias,
    const float* __restrict__ resid, void* __restrict__ Cout, int M, int N, int K)
{
  __shared__ uint4 Alds[512];
  __shared__ uint4 Blds[512];

  const int tid = threadIdx.x;
  const int wid = tid >> 6, lane = tid & 63;
  const int wr = wid >> 1, wc = wid & 1;
  const int bm = blockIdx.y*128, bn = blockIdx.x*128;

  const int g0 = tid >> 7;
  const int r0 = tid & 127;
  const int arow = min(bm + r0, M-1);
  const int brow = min(bn + r0, N-1);
  const int lg = lane >> 4, lr = lane & 15;

  f32x4 acc[4][4];
  #pragma unroll
  for (int i = 0; i < 4; i++)
    #pragma unroll
    for (int j = 0; j < 4; j++)
      acc[i][j] = (f32x4){0.f,0.f,0.f,0.f};

  for (int k0 = 0; k0 < K; k0 += 32){
    const uint4 av0 = *reinterpret_cast<const uint4*>(A  + (size_t)arow*K + k0 + g0*8);
    const uint4 av1 = *reinterpret_cast<const uint4*>(A  + (size_t)arow*K + k0 + (g0+2)*8);
    const uint4 bv0 = *reinterpret_cast<const uint4*>(Bt + (size_t)brow*K + k0 + g0*8);
    const uint4 bv1 = *reinterpret_cast<const uint4*>(Bt + (size_t)brow*K + k0 + (g0+2)*8);
    __syncthreads();
    Alds[g0*128 + r0] = av0;  Alds[(g0+2)*128 + r0] = av1;
    Blds[g0*128 + r0] = bv0;  Blds[(g0+2)*128 + r0] = bv1;
    __syncthreads();

    bf16x8 af[4], bfr[4];
    #pragma unroll
    for (int mf = 0; mf < 4; mf++)
      af[mf] = *reinterpret_cast<const bf16x8*>(&Alds[lg*128 + wr*64 + mf*16 + lr]);
    #pragma unroll
    for (int nf = 0; nf < 4; nf++)
      bfr[nf] = *reinterpret_cast<const bf16x8*>(&Blds[lg*128 + wc*64 + nf*16 + lr]);

    #pragma unroll
    for (int mf = 0; mf < 4; mf++)
      #pragma unroll
      for (int nf = 0; nf < 4; nf++)
        acc[mf][nf] = __builtin_amdgcn_mfma_f32_16x16x32_bf16(af[mf], bfr[nf], acc[mf][nf], 0, 0, 0);
  }

  #pragma unroll
  for (int mf = 0; mf < 4; mf++){
    #pragma unroll
    for (int rg = 0; rg < 4; rg++){
      const int row = bm + wr*64 + mf*16 + (lane>>4)*4 + rg;
      if (row >= M) continue;
      #pragma unroll
      for (int nf = 0; nf < 4; nf++){
        const int col = bn + wc*64 + nf*16 + (lane&15);
        if (col >= N) continue;
        float v = acc[mf][nf][rg] + bias[col];
        if (ACT == 1) v = geluf(v);
        if (RESID)    v += resid[(size_t)row*N + col];
        if (BF16OUT)  reinterpret_cast<bf16*>(Cout)[(size_t)row*N + col] = __float2bfloat16(v);
        else          reinterpret_cast<float*>(Cout)[(size_t)row*N + col] = v;
      }
    }
  }
}

// ---------------- LayerNorm over D=768: fp32 in -> bf16 out ----------------
__global__ __launch_bounds__(256) void layernorm_k(const float* __restrict__ x,
    const float* __restrict__ g, const float* __restrict__ bb, bf16* __restrict__ out)
{
  const int row = blockIdx.x;
  const float* xr = x + (size_t)row*D_;
  const int tid = threadIdx.x;
  const float v0 = xr[tid], v1 = xr[tid+256], v2 = xr[tid+512];

  float s = v0 + v1 + v2;
  #pragma unroll
  for (int o = 32; o > 0; o >>= 1) s += __shfl_xor(s, o);
  __shared__ float sm[4];
  const int wid = tid >> 6, lane = tid & 63;
  if (lane == 0) sm[wid] = s;
  __syncthreads();
  const float mean = (sm[0]+sm[1]+sm[2]+sm[3]) * (1.f/768.f);
  __syncthreads();

  const float d0 = v0-mean, d1 = v1-mean, d2 = v2-mean;
  float ss = d0*d0 + d1*d1 + d2*d2;
  #pragma unroll
  for (int o = 32; o > 0; o >>= 1) ss += __shfl_xor(ss, o);
  if (lane == 0) sm[wid] = ss;
  __syncthreads();
  const float var = (sm[0]+sm[1]+sm[2]+sm[3]) * (1.f/768.f);
  const float inv = rsqrtf(var + 1e-5f);

  bf16* orow = out + (size_t)row*D_;
  orow[tid]     = __float2bfloat16(d0*inv*g[tid]     + bb[tid]);
  orow[tid+256] = __float2bfloat16(d1*inv*g[tid+256] + bb[tid+256]);
  orow[tid+512] = __float2bfloat16(d2*inv*g[tid+512] + bb[tid+512]);
}

// ---------------- fused flash attention: MFMA qer precompute + LDS srel gather ----------------
// srel[q,k]: k<=q -> qer[q-q0][499-(q-k)] ; k==q+1 -> 0 ; k>q+1 -> qer[q-q0+1][k-q-2]
#define LDW 68
__global__ __launch_bounds__(256) void flash_attn_k(const bf16* __restrict__ qb,
    const bf16* __restrict__ kb, const bf16* __restrict__ vb,
    const bf16* __restrict__ erb, bf16* __restrict__ ob)
{
  const int b = blockIdx.y / NH_, h = blockIdx.y % NH_;
  const int q0 = blockIdx.x * 16;
  const int tid = threadIdx.x;
  const int qr = tid >> 4, kc = tid & 15;
  const int q  = q0 + qr;
  const bool qvalid = (q < T_);
  const int lane = tid & 63;

  __shared__ float qs[17][LDW];
  __shared__ float ks[2][16][LDW];
  __shared__ float vs[2][16][LDW];
  __shared__ float qer[17][512];

  // stage q rows q0..q0+16
  for (int i = tid; i < 17*16; i += 256){
    const int r = i >> 4, d4 = (i & 15) * 4;
    const int qq = q0 + r;
    float4 v = (qq < T_) ? ld4f(qb + ((size_t)(b*T_ + qq))*D_ + h*DH_ + d4)
                         : make_float4(0.f,0.f,0.f,0.f);
    qs[r][d4+0]=v.x; qs[r][d4+1]=v.y; qs[r][d4+2]=v.z; qs[r][d4+3]=v.w;
  }

  const int sr = tid >> 4, sd = (tid & 15) * 4;
  {  // K/V tile 0
    const float4 kv = ld4f(kb + ((size_t)(b*T_ + sr))*D_ + h*DH_ + sd);
    const float4 vv = ld4f(vb + ((size_t)(b*T_ + sr))*D_ + h*DH_ + sd);
    ks[0][sr][sd+0]=kv.x; ks[0][sr][sd+1]=kv.y; ks[0][sr][sd+2]=kv.z; ks[0][sr][sd+3]=kv.w;
    vs[0][sr][sd+0]=vv.x; vs[0][sr][sd+1]=vv.y; vs[0][sr][sd+2]=vv.z; vs[0][sr][sd+3]=vv.w;
  }

  // ---- qer[r][c] = Q[q0+r]·er[c] via MFMA (rows 0..16 used; C/D layout -> LDS) ----
  {
    const int lr = lane & 15, lg = lane >> 4;
    int qq0 = q0 + lr;      if (qq0 > 499) qq0 = 499;
    int qq1 = q0 + 16 + lr; if (qq1 > 499) qq1 = 499;
    bf16x8 a0f[2], a1f[2];
    #pragma unroll
    for (int h2 = 0; h2 < 2; h2++){
      a0f[h2] = *reinterpret_cast<const bf16x8*>(qb + ((size_t)(b*T_ + qq0))*D_ + h*DH_ + h2*32 + lg*8);
      a1f[h2] = *reinterpret_cast<const bf16x8*>(qb + ((size_t)(b*T_ + qq1))*D_ + h*DH_ + h2*32 + lg*8);
    }
    const int wv = tid >> 6;
    for (int ct = wv; ct < 32; ct += 4){
      const int c0 = ct*16;
      int cc = c0 + lr; if (cc > 499) cc = 499;
      bf16x8 bw[2];
      #pragma unroll
      for (int h2 = 0; h2 < 2; h2++)
        bw[h2] = *reinterpret_cast<const bf16x8*>(erb + (size_t)cc*DH_ + h2*32 + lg*8);
      f32x4 c0a = (f32x4){0,0,0,0}, c1a = (f32x4){0,0,0,0};
      c0a = __builtin_amdgcn_mfma_f32_16x16x32_bf16(a0f[0], bw[0], c0a, 0, 0, 0);
      c0a = __builtin_amdgcn_mfma_f32_16x16x32_bf16(a0f[1], bw[1], c0a, 0, 0, 0);
      c1a = __builtin_amdgcn_mfma_f32_16x16x32_bf16(a1f[0], bw[0], c1a, 0, 0, 0);
      c1a = __builtin_amdgcn_mfma_f32_16x16x32_bf16(a1f[1], bw[1], c1a, 0, 0, 0);
      #pragma unroll
      for (int rg = 0; rg < 4; rg++)
        qer[lg*4 + rg][c0 + lr] = c0a[rg];
      if (lg == 0) qer[16][c0 + lr] = c1a[0];   // row 16 = (lg=0,rg=0) of second row-tile
    }
  }
  __syncthreads();

  float m = -3.0e38f, l = 0.f;
  float oacc[4] = {0.f,0.f,0.f,0.f};
  int cur = 0;

  for (int k0 = 0; k0 < T_; k0 += 16){
    // prefetch next K/V tile to registers (T14 issue-early/write-late)
    const bool pf = (k0 + 16 < T_);
    float4 nk = make_float4(0.f,0.f,0.f,0.f), nv = make_float4(0.f,0.f,0.f,0.f);
    if (pf){
      const int kk = k0 + 16 + sr;
      if (kk < T_){
        nk = ld4f(kb + ((size_t)(b*T_ + kk))*D_ + h*DH_ + sd);
        nv = ld4f(vb + ((size_t)(b*T_ + kk))*D_ + h*DH_ + sd);
      }
    }

    const int k = k0 + kc;
    const bool kvalid = (k < T_);
    float s = -3.0e38f;
    if (qvalid && kvalid){
      const float4* q4 = reinterpret_cast<const float4*>(&qs[qr][0]);
      const float4* k4 = reinterpret_cast<const float4*>(&ks[cur][kc][0]);
      float d1a = 0.f, d1b = 0.f, d1c = 0.f, d1d = 0.f;
      #pragma unroll
      for (int i = 0; i < 16; i += 4){
        float4 a, c;
        a = q4[i];   c = k4[i];
        d1a = fmaf(a.x,c.x, fmaf(a.y,c.y, fmaf(a.z,c.z, fmaf(a.w,c.w, d1a))));
        a = q4[i+1]; c = k4[i+1];
        d1b = fmaf(a.x,c.x, fmaf(a.y,c.y, fmaf(a.z,c.z, fmaf(a.w,c.w, d1b))));
        a = q4[i+2]; c = k4[i+2];
        d1c = fmaf(a.x,c.x, fmaf(a.y,c.y, fmaf(a.z,c.z, fmaf(a.w,c.w, d1c))));
        a = q4[i+3]; c = k4[i+3];
        d1d = fmaf(a.x,c.x, fmaf(a.y,c.y, fmaf(a.z,c.z, fmaf(a.w,c.w, d1d))));
      }
      float d2 = 0.f;
      if (k != q + 1){
        const int eidx = (k <= q) ? (499 - q + k) : (k - q - 2);
        d2 = qer[qr + ((k <= q) ? 0 : 1)][eidx];
      }
      s = ((d1a + d1b) + (d1c + d1d) + d2) * 0.125f;
    }

    // online softmax across this row's 16 lanes
    float mx = s;
    #pragma unroll
    for (int o = 8; o > 0; o >>= 1) mx = fmaxf(mx, __shfl_xor(mx, o, 16));
    const float mn = fmaxf(m, mx);
    const float p = kvalid ? __expf(s - mn) : 0.f;
    const float corr = __expf(m - mn);
    float ps = p;
    #pragma unroll
    for (int o = 8; o > 0; o >>= 1) ps += __shfl_xor(ps, o, 16);
    l = l*corr + ps;
    m = mn;
    #pragma unroll
    for (int j = 0; j < 4; j++) oacc[j] *= corr;

    #pragma unroll
    for (int kc2 = 0; kc2 < 16; kc2++){
      const float pk = __shfl(p, kc2, 16);
      const float4 vv = *reinterpret_cast<const float4*>(&vs[cur][kc2][kc*4]);
      oacc[0] = fmaf(pk, vv.x, oacc[0]);
      oacc[1] = fmaf(pk, vv.y, oacc[1]);
      oacc[2] = fmaf(pk, vv.z, oacc[2]);
      oacc[3] = fmaf(pk, vv.w, oacc[3]);
    }

    if (pf){
      ks[cur^1][sr][sd+0]=nk.x; ks[cur^1][sr][sd+1]=nk.y; ks[cur^1][sr][sd+2]=nk.z; ks[cur^1][sr][sd+3]=nk.w;
      vs[cur^1][sr][sd+0]=nv.x; vs[cur^1][sr][sd+1]=nv.y; vs[cur^1][sr][sd+2]=nv.z; vs[cur^1][sr][sd+3]=nv.w;
    }
    __syncthreads();
    cur ^= 1;
  }

  if (qvalid){
    const float inv = 1.f / l;
    bf16* op = ob + ((size_t)(b*T_ + q))*D_ + h*DH_ + kc*4;
    ushort4 u;
    u.x = __bfloat16_as_ushort(__float2bfloat16(oacc[0]*inv));
    u.y = __bfloat16_as_ushort(__float2bfloat16(oacc[1]*inv));
    u.z = __bfloat16_as_ushort(__float2bfloat16(oacc[2]*inv));
    u.w = __bfloat16_as_ushort(__float2bfloat16(oacc[3]*inv));
    *reinterpret_cast<ushort4*>(op) = u;
  }
}

// =====================================================================
extern "C" void kernel_launch(void* const* d_in, const int* in_sizes, int n_in,
                              void* d_out, int out_size, void* d_ws, size_t ws_size,
                              hipStream_t stream)
{
  const float* spec  = (const float*)d_in[0];
  const float* cw1 = (const float*)d_in[1];  const float* cb1 = (const float*)d_in[2];
  const float* cw2 = (const float*)d_in[3];  const float* cb2 = (const float*)d_in[4];
  const float* cw3 = (const float*)d_in[5];  const float* cb3 = (const float*)d_in[6];
  const float* cw4 = (const float*)d_in[7];  const float* cb4 = (const float*)d_in[8];
  const float* proj_w = (const float*)d_in[9];  const float* proj_b = (const float*)d_in[10];
  const float* ln1_g = (const float*)d_in[11];  const float* ln1_b = (const float*)d_in[12];
  const float* wq = (const float*)d_in[13];  const float* bq = (const float*)d_in[14];
  const float* wk = (const float*)d_in[15];  const float* bk = (const float*)d_in[16];
  const float* wv = (const float*)d_in[17];  const float* bv = (const float*)d_in[18];
  const float* wo = (const float*)d_in[19];  const float* bo = (const float*)d_in[20];
  const float* er = (const float*)d_in[21];
  const float* ln2_g = (const float*)d_in[22];  const float* ln2_b = (const float*)d_in[23];
  const float* w1 = (const float*)d_in[24];  const float* b1 = (const float*)d_in[25];
  const float* w2 = (const float*)d_in[26];  const float* b2 = (const float*)d_in[27];
  const float* dw = (const float*)d_in[28];  const float* db = (const float*)d_in[29];

  if (ws_size < 98304000ull) return;
  char* W = (char*)d_ws;
  bf16*  n1 = (bf16*) (W + 0);
  bf16*  n2 = (bf16*) (W + 49152000);
  bf16*  n3 = (bf16*) (W + 0);
  bf16*  n4 = (bf16*) (W + 24576000);
  bf16*  tk = (bf16*) (W + 49152000);
  float* xb = (float*)(W + 0);
  bf16*  xn = (bf16*) (W + 24576000);
  bf16*  qb = (bf16*) (W + 36864000);
  bf16*  kb = (bf16*) (W + 49152000);
  bf16*  vb = (bf16*) (W + 61440000);
  bf16*  ob = (bf16*) (W + 73728000);
  bf16*  hb = (bf16*) (W + 36864000);
  bf16*  wt = (bf16*) (W + 86016000);    // up to 4.72 MB (ends 90,734,592)
  bf16*  erb= (bf16*) (W + 92274688);    // 64 KB bf16 er (per layer)
  bf16* cwt2 = (bf16*)d_out;
  bf16* cwt3 = (bf16*)((char*)d_out + 262144);
  bf16* cwt4 = (bf16*)((char*)d_out + 786432);

  // ---- CNN stack (NHWC, MFMA for conv2-4) ----
  conv_wt_k<32><<<(25*32*64 + 255)/256, 256, 0, stream>>>(cw2, cwt2);
  conv_wt_k<64><<<(25*64*64 + 255)/256, 256, 0, stream>>>(cw3, cwt3);
  conv_wt_k<64><<<(25*64*64 + 255)/256, 256, 0, stream>>>(cw4, cwt4);

  conv1_k<<<(B_*96*500 + 255)/256, 256, 0, stream>>>(spec, cw1, cb1, n1);
  conv_mfma_k<32><<<dim3(8, B_*48), 256, 0, stream>>>(n1, cwt2, cb2, n2, 96);
  conv_mfma_k<64><<<dim3(8, B_*24), 256, 0, stream>>>(n2, cwt3, cb3, n3, 48);
  conv_mfma_k<64><<<dim3(8, B_*12), 256, 0, stream>>>(n3, cwt4, cb4, n4, 24);

  tokens_k<<<(B_*12*500*64 + 255)/256, 256, 0, stream>>>(n4, tk);

  transpose_w<<<dim3(D_/32, D_/32), 256, 0, stream>>>(proj_w, wt, D_, D_);
  mfma_gemm_k<0,0,0><<<dim3(6,63), 256, 0, stream>>>(tk, wt, proj_b, nullptr, xb, 8000, D_, D_);

  // ---- transformer layers ----
  for (int l = 0; l < 3; l++){
    const size_t wOff = (size_t)l*D_*D_;
    layernorm_k<<<8000, 256, 0, stream>>>(xb, ln1_g + l*D_, ln1_b + l*D_, xn);

    transpose_w<<<dim3(D_/32, D_/32), 256, 0, stream>>>(wq + wOff, wt, D_, D_);
    mfma_gemm_k<0,0,1><<<dim3(6,63), 256, 0, stream>>>(xn, wt, bq + l*D_, nullptr, qb, 8000, D_, D_);
    transpose_w<<<dim3(D_/32, D_/32), 256, 0, stream>>>(wk + wOff, wt, D_, D_);
    mfma_gemm_k<0,0,1><<<dim3(6,63), 256, 0, stream>>>(xn, wt, bk + l*D_, nullptr, kb, 8000, D_, D_);
    transpose_w<<<dim3(D_/32, D_/32), 256, 0, stream>>>(wv + wOff, wt, D_, D_);
    mfma_gemm_k<0,0,1><<<dim3(6,63), 256, 0, stream>>>(xn, wt, bv + l*D_, nullptr, vb, 8000, D_, D_);

    er2bf_k<<<(T_*DH_ + 255)/256, 256, 0, stream>>>(er + (size_t)l*T_*DH_, erb);
    flash_attn_k<<<dim3(32, B_*NH_), 256, 0, stream>>>(qb, kb, vb, erb, ob);

    transpose_w<<<dim3(D_/32, D_/32), 256, 0, stream>>>(wo + wOff, wt, D_, D_);
    mfma_gemm_k<0,1,0><<<dim3(6,63), 256, 0, stream>>>(ob, wt, bo + l*D_, xb, xb, 8000, D_, D_);

    layernorm_k<<<8000, 256, 0, stream>>>(xb, ln2_g + l*D_, ln2_b + l*D_, xn);

    transpose_w<<<dim3(FFN_/32, D_/32), 256, 0, stream>>>(w1 + (size_t)l*D_*FFN_, wt, D_, FFN_);
    mfma_gemm_k<1,0,1><<<dim3(24,63), 256, 0, stream>>>(xn, wt, b1 + l*FFN_, nullptr, hb, 8000, FFN_, D_);
    transpose_w<<<dim3(D_/32, FFN_/32), 256, 0, stream>>>(w2 + (size_t)l*FFN_*D_, wt, FFN_, D_);
    mfma_gemm_k<0,1,0><<<dim3(6,63), 256, 0, stream>>>(hb, wt, b2 + l*D_, xb, xb, 8000, D_, FFN_);
  }

  // ---- deproj via MFMA -> fp32 output [8000, 192] ----
  f2bf_k<<<(8000*D_/4 + 255)/256, 256, 0, stream>>>(xb, xn, 8000*D_/4);
  transpose_w<<<dim3(192/32, D_/32), 256, 0, stream>>>(dw, wt, D_, 192);
  mfma_gemm_k<0,0,0><<<dim3(2,63), 256, 0, stream>>>(xn, wt, db, nullptr, d_out, 8000, 192, D_);
}

// Round 13
// 2702.246 us; speedup vs baseline: 12.0523x; 1.5535x over previous
//
#include <hip/hip_runtime.h>
#include <hip/hip_bf16.h>

typedef __hip_bfloat16 bf16;
typedef __attribute__((ext_vector_type(8))) short bf16x8;
typedef __attribute__((ext_vector_type(4))) float f32x4;

#define B_   16
#define T_   500
#define D_   768
#define NH_  12
#define DH_  64
#define FFN_ 3072

__device__ __forceinline__ float bfu2f(unsigned short u){ return __uint_as_float(((unsigned)u)<<16); }
__device__ __forceinline__ float geluf(float x){ return 0.5f*x*(1.0f + erff(x*0.70710678118654752f)); }

__device__ __forceinline__ float4 ld4f(const float* p){ return *reinterpret_cast<const float4*>(p); }
__device__ __forceinline__ float4 ld4f(const bf16* p){
  ushort4 u = *reinterpret_cast<const ushort4*>(p);
  return make_float4(bfu2f(u.x), bfu2f(u.y), bfu2f(u.z), bfu2f(u.w));
}

// ---------------- conv1: Cin=1, 32 oc per thread, writes NHWC [b][96][500][32] ----------------
__global__ __launch_bounds__(256) void conv1_k(const float* __restrict__ spec,
    const float* __restrict__ w, const float* __restrict__ bias, bf16* __restrict__ out)
{
  const int pos = blockIdx.x*256 + threadIdx.x;
  if (pos >= B_*96*500) return;
  const int x  = pos % 500;
  const int yo = (pos/500) % 96;
  const int b  = pos/(500*96);
  const float* ip = spec + (size_t)b*192*500;

  float v[6][5];
  #pragma unroll
  for (int r = 0; r < 6; r++){
    const int yy = 2*yo - 2 + r;
    const bool vy = (yy >= 0) && (yy < 192);
    const float* rp = ip + (size_t)(vy ? yy : 0)*500;
    #pragma unroll
    for (int c = 0; c < 5; c++){
      const int xx = x - 2 + c;
      v[r][c] = (vy && xx >= 0 && xx < 500) ? rp[xx] : 0.f;
    }
  }

  const size_t obase = (((size_t)(b*96 + yo))*500 + x)*32;
  #pragma unroll
  for (int oc = 0; oc < 32; oc++){
    float a0 = bias[oc], a1 = bias[oc];
    #pragma unroll
    for (int r = 0; r < 5; r++)
      #pragma unroll
      for (int c = 0; c < 5; c++){
        const float wv = w[oc*25 + r*5 + c];
        a0 = fmaf(v[r][c],   wv, a0);
        a1 = fmaf(v[r+1][c], wv, a1);
      }
    out[obase + oc] = __float2bfloat16(fmaxf(geluf(a0), geluf(a1)));
  }
}

// ---------------- conv weight repack: OIHW fp32 -> bf16 [tap][cg][nf][lane][8] ----------------
template<int CIN>
__global__ __launch_bounds__(256) void conv_wt_k(const float* __restrict__ w, bf16* __restrict__ wt)
{
  const int e = blockIdx.x*256 + threadIdx.x;
  if (e >= 25*CIN*64) return;
  const int j    = e & 7;
  const int lane = (e >> 3) & 63;
  const int nf   = (e >> 9) & 3;
  const int t3   = e >> 11;
  const int cg   = t3 % (CIN/32);
  const int tap  = t3 / (CIN/32);
  const int oc = nf*16 + (lane & 15);
  const int ci = cg*32 + (lane >> 4)*8 + j;
  wt[e] = __float2bfloat16(w[(size_t)(oc*CIN + ci)*25 + tap]);
}

// ---------------- MFMA conv + GELU + pool, NHWC, LDS-staged branch-free inner loop ----------------
template<int CIN>
__global__ __launch_bounds__(256) void conv_mfma_k(const bf16* __restrict__ in,
    const bf16* __restrict__ wt, const float* __restrict__ bias,
    bf16* __restrict__ out, int Hin)
{
  constexpr int KB   = CIN/8;
  constexpr int ROWB = 68*CIN*2;
  __shared__ uint4 ldsu[6*68*CIN/8];
  char* lds = (char*)ldsu;

  const int Hout = Hin >> 1;
  const int x0 = blockIdx.x * 64;
  const int yo = blockIdx.y % Hout;
  const int b  = blockIdx.y / Hout;
  const int tid = threadIdx.x, w = tid >> 6, lane = tid & 63;
  const int lr = lane & 15, kb = lane >> 4;

  for (int idx = tid; idx < 6*68*KB; idx += 256){
    const int kbb = idx % KB;
    const int xx  = (idx/KB) % 68;
    const int r   = idx/(KB*68);
    const int yy = 2*yo + r - 2;
    const int xg = x0 + xx - 2;
    uint4 v = make_uint4(0,0,0,0);
    if (yy >= 0 && yy < Hin && xg >= 0 && xg < 500)
      v = *reinterpret_cast<const uint4*>(in + (((size_t)(b*Hin + yy))*500 + xg)*CIN + kbb*8);
    int off = r*ROWB + xx*(CIN*2) + kbb*16;
    off ^= (xx & 7) << 4;
    *reinterpret_cast<uint4*>(lds + off) = v;
  }
  __syncthreads();

  f32x4 acc0[4], acc1[4];
  #pragma unroll
  for (int nf = 0; nf < 4; nf++){ acc0[nf] = (f32x4){0,0,0,0}; acc1[nf] = (f32x4){0,0,0,0}; }

  const int xl = w*16 + lr;
  #pragma unroll
  for (int ky = 0; ky < 5; ky++){
    #pragma unroll
    for (int kx = 0; kx < 5; kx++){
      const int xx = xl + kx;
      const int tap = ky*5 + kx;
      #pragma unroll
      for (int cg = 0; cg < CIN/32; cg++){
        int aoff = ky*ROWB + xx*(CIN*2) + (cg*32 + kb*8)*2;
        aoff ^= (xx & 7) << 4;
        const bf16x8 a0 = *reinterpret_cast<const bf16x8*>(lds + aoff);
        const bf16x8 a1 = *reinterpret_cast<const bf16x8*>(lds + aoff + ROWB);
        const bf16* bp = wt + ((size_t)((tap*(CIN/32) + cg)*4)*64 + lane)*8;
        #pragma unroll
        for (int nf = 0; nf < 4; nf++){
          const bf16x8 bf_ = *reinterpret_cast<const bf16x8*>(bp + nf*512);
          acc0[nf] = __builtin_amdgcn_mfma_f32_16x16x32_bf16(a0, bf_, acc0[nf], 0, 0, 0);
          acc1[nf] = __builtin_amdgcn_mfma_f32_16x16x32_bf16(a1, bf_, acc1[nf], 0, 0, 0);
        }
      }
    }
  }

  #pragma unroll
  for (int rg = 0; rg < 4; rg++){
    const int xs = x0 + w*16 + kb*4 + rg;
    if (xs < 500){
      const size_t obase = (((size_t)(b*Hout + yo))*500 + xs)*64;
      #pragma unroll
      for (int nf = 0; nf < 4; nf++){
        const int oc = nf*16 + lr;
        const float bv = bias[oc];
        const float p0 = geluf(acc0[nf][rg] + bv);
        const float p1 = geluf(acc1[nf][rg] + bv);
        out[obase + oc] = __float2bfloat16(fmaxf(p0, p1));
      }
    }
  }
}

// ---------------- tokens: NHWC conv4 out -> tk[b*T+t][ci*12+yo] ----------------
__global__ __launch_bounds__(256) void tokens_k(const bf16* __restrict__ n4, bf16* __restrict__ tk)
{
  const int idx = blockIdx.x*256 + threadIdx.x;
  if (idx >= B_*12*500*64) return;
  const int ci = idx & 63;
  const int t  = (idx >> 6) % 500;
  const int yo = (idx >> 6) / 500 % 12;
  const int b  = idx / (64*500*12);
  tk[((size_t)(b*500 + t))*768 + ci*12 + yo] = n4[idx];
}

// ---------------- er fp32 -> bf16 ----------------
__global__ __launch_bounds__(256) void er2bf_k(const float* __restrict__ er, bf16* __restrict__ out)
{
  const int idx = blockIdx.x*256 + threadIdx.x;
  if (idx < T_*DH_) out[idx] = __float2bfloat16(er[idx]);
}

// ---------------- fp32 -> bf16 bulk cast (vectorized) ----------------
__global__ __launch_bounds__(256) void f2bf_k(const float* __restrict__ x, bf16* __restrict__ out, int n4)
{
  const int idx = blockIdx.x*256 + threadIdx.x;
  if (idx >= n4) return;
  const float4 v = *reinterpret_cast<const float4*>(x + idx*4);
  ushort4 u;
  u.x = __bfloat16_as_ushort(__float2bfloat16(v.x));
  u.y = __bfloat16_as_ushort(__float2bfloat16(v.y));
  u.z = __bfloat16_as_ushort(__float2bfloat16(v.z));
  u.w = __bfloat16_as_ushort(__float2bfloat16(v.w));
  *reinterpret_cast<ushort4*>(out + idx*4) = u;
}

// ---------------- weight transpose+convert: fp32 [K][N] -> bf16 [N][K] ----------------
__global__ __launch_bounds__(256) void transpose_w(const float* __restrict__ W,
    bf16* __restrict__ out, int K, int N)
{
  __shared__ float tile[32][33];
  const int gk = blockIdx.y*32, gn = blockIdx.x*32;
  const int tr = threadIdx.x >> 5, tc = threadIdx.x & 31;
  #pragma unroll
  for (int i = 0; i < 4; i++)
    tile[tr + i*8][tc] = W[(size_t)(gk + tr + i*8)*N + gn + tc];
  __syncthreads();
  #pragma unroll
  for (int i = 0; i < 4; i++)
    out[(size_t)(gn + tr + i*8)*K + gk + tc] = __float2bfloat16(tile[tc][tr + i*8]);
}

// ---------------- MFMA GEMM: C = act(A[MxK](bf16) @ Bt[NxK]^T(bf16) + bias) (+resid) ----------------
template<int ACT, int RESID, int BF16OUT>
__global__ __launch_bounds__(256) void mfma_gemm_k(const bf16* __restrict__ A,
    const bf16* __restrict__ Bt, const float* __restrict__ bias,
    const float* __restrict__ resid, void* __restrict__ Cout, int M, int N, int K)
{
  __shared__ uint4 Alds[512];
  __shared__ uint4 Blds[512];

  const int tid = threadIdx.x;
  const int wid = tid >> 6, lane = tid & 63;
  const int wr = wid >> 1, wc = wid & 1;
  const int bm = blockIdx.y*128, bn = blockIdx.x*128;

  const int g0 = tid >> 7;
  const int r0 = tid & 127;
  const int arow = min(bm + r0, M-1);
  const int brow = min(bn + r0, N-1);
  const int lg = lane >> 4, lr = lane & 15;

  f32x4 acc[4][4];
  #pragma unroll
  for (int i = 0; i < 4; i++)
    #pragma unroll
    for (int j = 0; j < 4; j++)
      acc[i][j] = (f32x4){0.f,0.f,0.f,0.f};

  for (int k0 = 0; k0 < K; k0 += 32){
    const uint4 av0 = *reinterpret_cast<const uint4*>(A  + (size_t)arow*K + k0 + g0*8);
    const uint4 av1 = *reinterpret_cast<const uint4*>(A  + (size_t)arow*K + k0 + (g0+2)*8);
    const uint4 bv0 = *reinterpret_cast<const uint4*>(Bt + (size_t)brow*K + k0 + g0*8);
    const uint4 bv1 = *reinterpret_cast<const uint4*>(Bt + (size_t)brow*K + k0 + (g0+2)*8);
    __syncthreads();
    Alds[g0*128 + r0] = av0;  Alds[(g0+2)*128 + r0] = av1;
    Blds[g0*128 + r0] = bv0;  Blds[(g0+2)*128 + r0] = bv1;
    __syncthreads();

    bf16x8 af[4], bfr[4];
    #pragma unroll
    for (int mf = 0; mf < 4; mf++)
      af[mf] = *reinterpret_cast<const bf16x8*>(&Alds[lg*128 + wr*64 + mf*16 + lr]);
    #pragma unroll
    for (int nf = 0; nf < 4; nf++)
      bfr[nf] = *reinterpret_cast<const bf16x8*>(&Blds[lg*128 + wc*64 + nf*16 + lr]);

    #pragma unroll
    for (int mf = 0; mf < 4; mf++)
      #pragma unroll
      for (int nf = 0; nf < 4; nf++)
        acc[mf][nf] = __builtin_amdgcn_mfma_f32_16x16x32_bf16(af[mf], bfr[nf], acc[mf][nf], 0, 0, 0);
  }

  #pragma unroll
  for (int mf = 0; mf < 4; mf++){
    #pragma unroll
    for (int rg = 0; rg < 4; rg++){
      const int row = bm + wr*64 + mf*16 + (lane>>4)*4 + rg;
      if (row >= M) continue;
      #pragma unroll
      for (int nf = 0; nf < 4; nf++){
        const int col = bn + wc*64 + nf*16 + (lane&15);
        if (col >= N) continue;
        float v = acc[mf][nf][rg] + bias[col];
        if (ACT == 1) v = geluf(v);
        if (RESID)    v += resid[(size_t)row*N + col];
        if (BF16OUT)  reinterpret_cast<bf16*>(Cout)[(size_t)row*N + col] = __float2bfloat16(v);
        else          reinterpret_cast<float*>(Cout)[(size_t)row*N + col] = v;
      }
    }
  }
}

// ---------------- LayerNorm over D=768: fp32 in -> bf16 out ----------------
__global__ __launch_bounds__(256) void layernorm_k(const float* __restrict__ x,
    const float* __restrict__ g, const float* __restrict__ bb, bf16* __restrict__ out)
{
  const int row = blockIdx.x;
  const float* xr = x + (size_t)row*D_;
  const int tid = threadIdx.x;
  const float v0 = xr[tid], v1 = xr[tid+256], v2 = xr[tid+512];

  float s = v0 + v1 + v2;
  #pragma unroll
  for (int o = 32; o > 0; o >>= 1) s += __shfl_xor(s, o);
  __shared__ float sm[4];
  const int wid = tid >> 6, lane = tid & 63;
  if (lane == 0) sm[wid] = s;
  __syncthreads();
  const float mean = (sm[0]+sm[1]+sm[2]+sm[3]) * (1.f/768.f);
  __syncthreads();

  const float d0 = v0-mean, d1 = v1-mean, d2 = v2-mean;
  float ss = d0*d0 + d1*d1 + d2*d2;
  #pragma unroll
  for (int o = 32; o > 0; o >>= 1) ss += __shfl_xor(ss, o);
  if (lane == 0) sm[wid] = ss;
  __syncthreads();
  const float var = (sm[0]+sm[1]+sm[2]+sm[3]) * (1.f/768.f);
  const float inv = rsqrtf(var + 1e-5f);

  bf16* orow = out + (size_t)row*D_;
  orow[tid]     = __float2bfloat16(d0*inv*g[tid]     + bb[tid]);
  orow[tid+256] = __float2bfloat16(d1*inv*g[tid+256] + bb[tid+256]);
  orow[tid+512] = __float2bfloat16(d2*inv*g[tid+512] + bb[tid+512]);
}

// ---------------- flash attention: MFMA QK^T (reg frags) + split-K waves + qer LDS ----------------
// srel[q,k]: k<=q -> qer[q-q0][499-(q-k)] ; k==q+1 -> 0 ; k>q+1 -> qer[q-q0+1][k-q-2]
__global__ __launch_bounds__(256) void flash_attn_k(const bf16* __restrict__ qb,
    const bf16* __restrict__ kb, const bf16* __restrict__ vb,
    const bf16* __restrict__ erb, bf16* __restrict__ ob)
{
  const int b = blockIdx.y / NH_, h = blockIdx.y % NH_;
  const int q0 = blockIdx.x * 16;
  const int tid = threadIdx.x;
  const int w = tid >> 6, lane = tid & 63;
  const int lr = lane & 15, lg = lane >> 4;

  __shared__ float qer[17][518];        // 35.2 KB (pad 518: <=2-way banks)
  __shared__ float vs[64][68];          // 17.4 KB V superblock (single buffer)
  __shared__ float S_lds[4][16][19];    // per-wave S tiles
  __shared__ float tmax_lds[4][16];
  __shared__ float mfin[4][16], lfin[4][16];
  float* mrg = &vs[0][0];               // merge overlay (4096 of 4352 floats)

  // ---- Q fragment (rows q0..q0+15), reused for qer and QK^T ----
  int qq0 = q0 + lr;      if (qq0 > 499) qq0 = 499;
  bf16x8 qf[2];
  #pragma unroll
  for (int h2 = 0; h2 < 2; h2++)
    qf[h2] = *reinterpret_cast<const bf16x8*>(qb + ((size_t)(b*T_ + qq0))*D_ + h*DH_ + h2*32 + lg*8);

  // ---- qer[r][c] = Q[q0+r]·er[c], rows 0..16, via MFMA ----
  {
    int qq1 = q0 + 16 + lr; if (qq1 > 499) qq1 = 499;
    bf16x8 a1f[2];
    #pragma unroll
    for (int h2 = 0; h2 < 2; h2++)
      a1f[h2] = *reinterpret_cast<const bf16x8*>(qb + ((size_t)(b*T_ + qq1))*D_ + h*DH_ + h2*32 + lg*8);
    for (int ct = w; ct < 32; ct += 4){
      const int c0 = ct*16;
      int cc = c0 + lr; if (cc > 499) cc = 499;
      bf16x8 bw[2];
      #pragma unroll
      for (int h2 = 0; h2 < 2; h2++)
        bw[h2] = *reinterpret_cast<const bf16x8*>(erb + (size_t)cc*DH_ + h2*32 + lg*8);
      f32x4 c0a = (f32x4){0,0,0,0}, c1a = (f32x4){0,0,0,0};
      c0a = __builtin_amdgcn_mfma_f32_16x16x32_bf16(qf[0],  bw[0], c0a, 0, 0, 0);
      c0a = __builtin_amdgcn_mfma_f32_16x16x32_bf16(qf[1],  bw[1], c0a, 0, 0, 0);
      c1a = __builtin_amdgcn_mfma_f32_16x16x32_bf16(a1f[0], bw[0], c1a, 0, 0, 0);
      c1a = __builtin_amdgcn_mfma_f32_16x16x32_bf16(a1f[1], bw[1], c1a, 0, 0, 0);
      #pragma unroll
      for (int rg = 0; rg < 4; rg++)
        qer[lg*4 + rg][c0 + lr] = c0a[rg];
      if (lg == 0) qer[16][c0 + lr] = c1a[0];
    }
  }

  // ---- initial V stage: superblock 0 (rows 0..63) ----
  const int skr = tid >> 2;            // 0..63
  const int sc  = (tid & 3) * 16;      // 0,16,32,48
  {
    const int krow = min(skr, 499);
    const bf16* vp = vb + ((size_t)(b*T_ + krow))*D_ + h*DH_ + sc;
    const ushort4 u0 = *reinterpret_cast<const ushort4*>(vp);
    const ushort4 u1 = *reinterpret_cast<const ushort4*>(vp + 4);
    const ushort4 u2 = *reinterpret_cast<const ushort4*>(vp + 8);
    const ushort4 u3 = *reinterpret_cast<const ushort4*>(vp + 12);
    float* d = &vs[skr][sc];
    d[0]=bfu2f(u0.x); d[1]=bfu2f(u0.y); d[2]=bfu2f(u0.z); d[3]=bfu2f(u0.w);
    d[4]=bfu2f(u1.x); d[5]=bfu2f(u1.y); d[6]=bfu2f(u1.z); d[7]=bfu2f(u1.w);
    d[8]=bfu2f(u2.x); d[9]=bfu2f(u2.y); d[10]=bfu2f(u2.z); d[11]=bfu2f(u2.w);
    d[12]=bfu2f(u3.x); d[13]=bfu2f(u3.y); d[14]=bfu2f(u3.z); d[15]=bfu2f(u3.w);
  }
  __syncthreads();

  float m = -3.0e38f, l = 0.f;
  float oacc[16];
  #pragma unroll
  for (int j = 0; j < 16; j++) oacc[j] = 0.f;

  for (int sb = 0; sb < 8; sb++){
    const int K0 = sb*64;
    // prefetch next superblock's V slice into registers (issue-early / write-late)
    const bool pf = (sb < 7);
    ushort4 p0, p1, p2, p3;
    if (pf){
      const int krow = min(K0 + 64 + skr, 499);
      const bf16* vp = vb + ((size_t)(b*T_ + krow))*D_ + h*DH_ + sc;
      p0 = *reinterpret_cast<const ushort4*>(vp);
      p1 = *reinterpret_cast<const ushort4*>(vp + 4);
      p2 = *reinterpret_cast<const ushort4*>(vp + 8);
      p3 = *reinterpret_cast<const ushort4*>(vp + 12);
    }

    // ---- S-tile via MFMA: wave w handles k-tile k0 = K0 + w*16 ----
    const int k0 = K0 + w*16;
    int kk = k0 + lr; if (kk > 499) kk = 499;
    bf16x8 kf[2];
    #pragma unroll
    for (int h2 = 0; h2 < 2; h2++)
      kf[h2] = *reinterpret_cast<const bf16x8*>(kb + ((size_t)(b*T_ + kk))*D_ + h*DH_ + h2*32 + lg*8);
    f32x4 sacc = (f32x4){0,0,0,0};
    sacc = __builtin_amdgcn_mfma_f32_16x16x32_bf16(qf[0], kf[0], sacc, 0, 0, 0);
    sacc = __builtin_amdgcn_mfma_f32_16x16x32_bf16(qf[1], kf[1], sacc, 0, 0, 0);

    // srel + scale + mask; C/D: row = lg*4+rg, col = lr
    const int kcol = k0 + lr;
    float sv[4];
    #pragma unroll
    for (int rg = 0; rg < 4; rg++){
      const int r = lg*4 + rg;
      const int q = q0 + r;
      float d2 = 0.f;
      if (kcol != q + 1){
        const int eidx = (kcol <= q) ? (499 - q + kcol) : (kcol - q - 2);
        d2 = qer[(kcol <= q) ? r : r + 1][eidx];
      }
      float s = (sacc[rg] + d2) * 0.125f;
      if (kcol >= 500) s = -3.0e38f;
      sv[rg] = s;
    }
    // per-row tile max (width-16 shuffles within lane group)
    float tm[4];
    #pragma unroll
    for (int rg = 0; rg < 4; rg++){
      tm[rg] = sv[rg];
      #pragma unroll
      for (int o = 8; o > 0; o >>= 1) tm[rg] = fmaxf(tm[rg], __shfl_xor(tm[rg], o, 16));
    }
    #pragma unroll
    for (int rg = 0; rg < 4; rg++) S_lds[w][lg*4 + rg][lr] = sv[rg];
    if (lr == 0){
      #pragma unroll
      for (int rg = 0; rg < 4; rg++) tmax_lds[w][lg*4 + rg] = tm[rg];
    }

    // ---- PV: lane owns row q'=lr, d-range lg*16..lg*16+15 ----
    const float tmv = tmax_lds[w][lr];
    const float mn = fmaxf(m, tmv);
    const float corr = __expf(m - mn);
    m = mn;
    l *= corr;
    #pragma unroll
    for (int j = 0; j < 16; j++) oacc[j] *= corr;

    #pragma unroll
    for (int k2 = 0; k2 < 16; k2++){
      const float p = __expf(S_lds[w][lr][k2] - mn);
      l += p;
      const float* vrow = &vs[w*16 + k2][lg*16];
      const float4 va = *reinterpret_cast<const float4*>(vrow);
      const float4 vbv = *reinterpret_cast<const float4*>(vrow + 4);
      const float4 vc = *reinterpret_cast<const float4*>(vrow + 8);
      const float4 vd = *reinterpret_cast<const float4*>(vrow + 12);
      oacc[0]  = fmaf(p, va.x,  oacc[0]);  oacc[1]  = fmaf(p, va.y,  oacc[1]);
      oacc[2]  = fmaf(p, va.z,  oacc[2]);  oacc[3]  = fmaf(p, va.w,  oacc[3]);
      oacc[4]  = fmaf(p, vbv.x, oacc[4]);  oacc[5]  = fmaf(p, vbv.y, oacc[5]);
      oacc[6]  = fmaf(p, vbv.z, oacc[6]);  oacc[7]  = fmaf(p, vbv.w, oacc[7]);
      oacc[8]  = fmaf(p, vc.x,  oacc[8]);  oacc[9]  = fmaf(p, vc.y,  oacc[9]);
      oacc[10] = fmaf(p, vc.z,  oacc[10]); oacc[11] = fmaf(p, vc.w,  oacc[11]);
      oacc[12] = fmaf(p, vd.x,  oacc[12]); oacc[13] = fmaf(p, vd.y,  oacc[13]);
      oacc[14] = fmaf(p, vd.z,  oacc[14]); oacc[15] = fmaf(p, vd.w,  oacc[15]);
    }

    if (pf){
      __syncthreads();                 // all waves done reading vs for this superblock
      float* d = &vs[skr][sc];
      d[0]=bfu2f(p0.x); d[1]=bfu2f(p0.y); d[2]=bfu2f(p0.z); d[3]=bfu2f(p0.w);
      d[4]=bfu2f(p1.x); d[5]=bfu2f(p1.y); d[6]=bfu2f(p1.z); d[7]=bfu2f(p1.w);
      d[8]=bfu2f(p2.x); d[9]=bfu2f(p2.y); d[10]=bfu2f(p2.z); d[11]=bfu2f(p2.w);
      d[12]=bfu2f(p3.x); d[13]=bfu2f(p3.y); d[14]=bfu2f(p3.z); d[15]=bfu2f(p3.w);
      __syncthreads();                 // new V visible
    }
  }

  // ---- split-K merge across the 4 waves ----
  __syncthreads();                     // all PV reads of vs done before mrg overlay
  #pragma unroll
  for (int j4 = 0; j4 < 4; j4++)
    *reinterpret_cast<float4*>(&mrg[(w*16 + lr)*64 + lg*16 + j4*4]) =
      make_float4(oacc[j4*4+0], oacc[j4*4+1], oacc[j4*4+2], oacc[j4*4+3]);
  if (lg == 0){ mfin[w][lr] = m; lfin[w][lr] = l; }
  __syncthreads();

  const int qp = tid & 15, dgj = tid >> 4;   // q-row, d-group(4)
  float M = fmaxf(fmaxf(mfin[0][qp], mfin[1][qp]), fmaxf(mfin[2][qp], mfin[3][qp]));
  float L = 0.f, o0 = 0.f, o1 = 0.f, o2 = 0.f, o3 = 0.f;
  #pragma unroll
  for (int w2 = 0; w2 < 4; w2++){
    const float e = __expf(mfin[w2][qp] - M);
    L += lfin[w2][qp] * e;
    const float* src = &mrg[(w2*16 + qp)*64 + dgj*4];
    o0 = fmaf(e, src[0], o0); o1 = fmaf(e, src[1], o1);
    o2 = fmaf(e, src[2], o2); o3 = fmaf(e, src[3], o3);
  }
  const int q = q0 + qp;
  if (q < T_){
    const float inv = 1.f / L;
    bf16* op = ob + ((size_t)(b*T_ + q))*D_ + h*DH_ + dgj*4;
    ushort4 u;
    u.x = __bfloat16_as_ushort(__float2bfloat16(o0*inv));
    u.y = __bfloat16_as_ushort(__float2bfloat16(o1*inv));
    u.z = __bfloat16_as_ushort(__float2bfloat16(o2*inv));
    u.w = __bfloat16_as_ushort(__float2bfloat16(o3*inv));
    *reinterpret_cast<ushort4*>(op) = u;
  }
}

// =====================================================================
extern "C" void kernel_launch(void* const* d_in, const int* in_sizes, int n_in,
                              void* d_out, int out_size, void* d_ws, size_t ws_size,
                              hipStream_t stream)
{
  const float* spec  = (const float*)d_in[0];
  const float* cw1 = (const float*)d_in[1];  const float* cb1 = (const float*)d_in[2];
  const float* cw2 = (const float*)d_in[3];  const float* cb2 = (const float*)d_in[4];
  const float* cw3 = (const float*)d_in[5];  const float* cb3 = (const float*)d_in[6];
  const float* cw4 = (const float*)d_in[7];  const float* cb4 = (const float*)d_in[8];
  const float* proj_w = (const float*)d_in[9];  const float* proj_b = (const float*)d_in[10];
  const float* ln1_g = (const float*)d_in[11];  const float* ln1_b = (const float*)d_in[12];
  const float* wq = (const float*)d_in[13];  const float* bq = (const float*)d_in[14];
  const float* wk = (const float*)d_in[15];  const float* bk = (const float*)d_in[16];
  const float* wv = (const float*)d_in[17];  const float* bv = (const float*)d_in[18];
  const float* wo = (const float*)d_in[19];  const float* bo = (const float*)d_in[20];
  const float* er = (const float*)d_in[21];
  const float* ln2_g = (const float*)d_in[22];  const float* ln2_b = (const float*)d_in[23];
  const float* w1 = (const float*)d_in[24];  const float* b1 = (const float*)d_in[25];
  const float* w2 = (const float*)d_in[26];  const float* b2 = (const float*)d_in[27];
  const float* dw = (const float*)d_in[28];  const float* db = (const float*)d_in[29];

  if (ws_size < 98304000ull) return;
  char* W = (char*)d_ws;
  bf16*  n1 = (bf16*) (W + 0);
  bf16*  n2 = (bf16*) (W + 49152000);
  bf16*  n3 = (bf16*) (W + 0);
  bf16*  n4 = (bf16*) (W + 24576000);
  bf16*  tk = (bf16*) (W + 49152000);
  float* xb = (float*)(W + 0);
  bf16*  xn = (bf16*) (W + 24576000);
  bf16*  qb = (bf16*) (W + 36864000);
  bf16*  kb = (bf16*) (W + 49152000);
  bf16*  vb = (bf16*) (W + 61440000);
  bf16*  ob = (bf16*) (W + 73728000);
  bf16*  hb = (bf16*) (W + 36864000);
  bf16*  wt = (bf16*) (W + 86016000);
  bf16*  erb= (bf16*) (W + 92274688);
  bf16* cwt2 = (bf16*)d_out;
  bf16* cwt3 = (bf16*)((char*)d_out + 262144);
  bf16* cwt4 = (bf16*)((char*)d_out + 786432);

  // ---- CNN stack (NHWC, MFMA for conv2-4) ----
  conv_wt_k<32><<<(25*32*64 + 255)/256, 256, 0, stream>>>(cw2, cwt2);
  conv_wt_k<64><<<(25*64*64 + 255)/256, 256, 0, stream>>>(cw3, cwt3);
  conv_wt_k<64><<<(25*64*64 + 255)/256, 256, 0, stream>>>(cw4, cwt4);

  conv1_k<<<(B_*96*500 + 255)/256, 256, 0, stream>>>(spec, cw1, cb1, n1);
  conv_mfma_k<32><<<dim3(8, B_*48), 256, 0, stream>>>(n1, cwt2, cb2, n2, 96);
  conv_mfma_k<64><<<dim3(8, B_*24), 256, 0, stream>>>(n2, cwt3, cb3, n3, 48);
  conv_mfma_k<64><<<dim3(8, B_*12), 256, 0, stream>>>(n3, cwt4, cb4, n4, 24);

  tokens_k<<<(B_*12*500*64 + 255)/256, 256, 0, stream>>>(n4, tk);

  transpose_w<<<dim3(D_/32, D_/32), 256, 0, stream>>>(proj_w, wt, D_, D_);
  mfma_gemm_k<0,0,0><<<dim3(6,63), 256, 0, stream>>>(tk, wt, proj_b, nullptr, xb, 8000, D_, D_);

  // ---- transformer layers ----
  for (int l = 0; l < 3; l++){
    const size_t wOff = (size_t)l*D_*D_;
    layernorm_k<<<8000, 256, 0, stream>>>(xb, ln1_g + l*D_, ln1_b + l*D_, xn);

    transpose_w<<<dim3(D_/32, D_/32), 256, 0, stream>>>(wq + wOff, wt, D_, D_);
    mfma_gemm_k<0,0,1><<<dim3(6,63), 256, 0, stream>>>(xn, wt, bq + l*D_, nullptr, qb, 8000, D_, D_);
    transpose_w<<<dim3(D_/32, D_/32), 256, 0, stream>>>(wk + wOff, wt, D_, D_);
    mfma_gemm_k<0,0,1><<<dim3(6,63), 256, 0, stream>>>(xn, wt, bk + l*D_, nullptr, kb, 8000, D_, D_);
    transpose_w<<<dim3(D_/32, D_/32), 256, 0, stream>>>(wv + wOff, wt, D_, D_);
    mfma_gemm_k<0,0,1><<<dim3(6,63), 256, 0, stream>>>(xn, wt, bv + l*D_, nullptr, vb, 8000, D_, D_);

    er2bf_k<<<(T_*DH_ + 255)/256, 256, 0, stream>>>(er + (size_t)l*T_*DH_, erb);
    flash_attn_k<<<dim3(32, B_*NH_), 256, 0, stream>>>(qb, kb, vb, erb, ob);

    transpose_w<<<dim3(D_/32, D_/32), 256, 0, stream>>>(wo + wOff, wt, D_, D_);
    mfma_gemm_k<0,1,0><<<dim3(6,63), 256, 0, stream>>>(ob, wt, bo + l*D_, xb, xb, 8000, D_, D_);

    layernorm_k<<<8000, 256, 0, stream>>>(xb, ln2_g + l*D_, ln2_b + l*D_, xn);

    transpose_w<<<dim3(FFN_/32, D_/32), 256, 0, stream>>>(w1 + (size_t)l*D_*FFN_, wt, D_, FFN_);
    mfma_gemm_k<1,0,1><<<dim3(24,63), 256, 0, stream>>>(xn, wt, b1 + l*FFN_, nullptr, hb, 8000, FFN_, D_);
    transpose_w<<<dim3(D_/32, FFN_/32), 256, 0, stream>>>(w2 + (size_t)l*FFN_*D_, wt, FFN_, D_);
    mfma_gemm_k<0,1,0><<<dim3(6,63), 256, 0, stream>>>(hb, wt, b2 + l*D_, xb, xb, 8000, D_, FFN_);
  }

  // ---- deproj via MFMA -> fp32 output [8000, 192] ----
  f2bf_k<<<(8000*D_/4 + 255)/256, 256, 0, stream>>>(xb, xn, 8000*D_/4);
  transpose_w<<<dim3(192/32, D_/32), 256, 0, stream>>>(dw, wt, D_, 192);
  mfma_gemm_k<0,0,0><<<dim3(2,63), 256, 0, stream>>>(xn, wt, db, nullptr, d_out, 8000, 192, D_);
}

// Round 14
// 2438.726 us; speedup vs baseline: 13.3546x; 1.1081x over previous
//
#include <hip/hip_runtime.h>
#include <hip/hip_bf16.h>

typedef __hip_bfloat16 bf16;
typedef __attribute__((ext_vector_type(8))) short bf16x8;
typedef __attribute__((ext_vector_type(4))) float f32x4;

#define B_   16
#define T_   500
#define D_   768
#define NH_  12
#define DH_  64
#define FFN_ 3072
#define QKVS 2304

__device__ __forceinline__ float bfu2f(unsigned short u){ return __uint_as_float(((unsigned)u)<<16); }
__device__ __forceinline__ float geluf(float x){ return 0.5f*x*(1.0f + erff(x*0.70710678118654752f)); }

__device__ __forceinline__ float4 ld4f(const float* p){ return *reinterpret_cast<const float4*>(p); }
__device__ __forceinline__ float4 ld4f(const bf16* p){
  ushort4 u = *reinterpret_cast<const ushort4*>(p);
  return make_float4(bfu2f(u.x), bfu2f(u.y), bfu2f(u.z), bfu2f(u.w));
}

// ---------------- conv1: Cin=1, 32 oc per thread, writes NHWC [b][96][500][32] ----------------
__global__ __launch_bounds__(256) void conv1_k(const float* __restrict__ spec,
    const float* __restrict__ w, const float* __restrict__ bias, bf16* __restrict__ out)
{
  const int pos = blockIdx.x*256 + threadIdx.x;
  if (pos >= B_*96*500) return;
  const int x  = pos % 500;
  const int yo = (pos/500) % 96;
  const int b  = pos/(500*96);
  const float* ip = spec + (size_t)b*192*500;

  float v[6][5];
  #pragma unroll
  for (int r = 0; r < 6; r++){
    const int yy = 2*yo - 2 + r;
    const bool vy = (yy >= 0) && (yy < 192);
    const float* rp = ip + (size_t)(vy ? yy : 0)*500;
    #pragma unroll
    for (int c = 0; c < 5; c++){
      const int xx = x - 2 + c;
      v[r][c] = (vy && xx >= 0 && xx < 500) ? rp[xx] : 0.f;
    }
  }

  const size_t obase = (((size_t)(b*96 + yo))*500 + x)*32;
  #pragma unroll
  for (int oc = 0; oc < 32; oc++){
    float a0 = bias[oc], a1 = bias[oc];
    #pragma unroll
    for (int r = 0; r < 5; r++)
      #pragma unroll
      for (int c = 0; c < 5; c++){
        const float wv = w[oc*25 + r*5 + c];
        a0 = fmaf(v[r][c],   wv, a0);
        a1 = fmaf(v[r+1][c], wv, a1);
      }
    out[obase + oc] = __float2bfloat16(fmaxf(geluf(a0), geluf(a1)));
  }
}

// ---------------- conv weight repack: OIHW fp32 -> bf16 [tap][cg][nf][lane][8] ----------------
template<int CIN>
__global__ __launch_bounds__(256) void conv_wt_k(const float* __restrict__ w, bf16* __restrict__ wt)
{
  const int e = blockIdx.x*256 + threadIdx.x;
  if (e >= 25*CIN*64) return;
  const int j    = e & 7;
  const int lane = (e >> 3) & 63;
  const int nf   = (e >> 9) & 3;
  const int t3   = e >> 11;
  const int cg   = t3 % (CIN/32);
  const int tap  = t3 / (CIN/32);
  const int oc = nf*16 + (lane & 15);
  const int ci = cg*32 + (lane >> 4)*8 + j;
  wt[e] = __float2bfloat16(w[(size_t)(oc*CIN + ci)*25 + tap]);
}

// ---------------- MFMA conv + GELU + pool, NHWC, LDS-staged branch-free inner loop ----------------
template<int CIN>
__global__ __launch_bounds__(256) void conv_mfma_k(const bf16* __restrict__ in,
    const bf16* __restrict__ wt, const float* __restrict__ bias,
    bf16* __restrict__ out, int Hin)
{
  constexpr int KB   = CIN/8;
  constexpr int ROWB = 68*CIN*2;
  __shared__ uint4 ldsu[6*68*CIN/8];
  char* lds = (char*)ldsu;

  const int Hout = Hin >> 1;
  const int x0 = blockIdx.x * 64;
  const int yo = blockIdx.y % Hout;
  const int b  = blockIdx.y / Hout;
  const int tid = threadIdx.x, w = tid >> 6, lane = tid & 63;
  const int lr = lane & 15, kb = lane >> 4;

  for (int idx = tid; idx < 6*68*KB; idx += 256){
    const int kbb = idx % KB;
    const int xx  = (idx/KB) % 68;
    const int r   = idx/(KB*68);
    const int yy = 2*yo + r - 2;
    const int xg = x0 + xx - 2;
    uint4 v = make_uint4(0,0,0,0);
    if (yy >= 0 && yy < Hin && xg >= 0 && xg < 500)
      v = *reinterpret_cast<const uint4*>(in + (((size_t)(b*Hin + yy))*500 + xg)*CIN + kbb*8);
    int off = r*ROWB + xx*(CIN*2) + kbb*16;
    off ^= (xx & 7) << 4;
    *reinterpret_cast<uint4*>(lds + off) = v;
  }
  __syncthreads();

  f32x4 acc0[4], acc1[4];
  #pragma unroll
  for (int nf = 0; nf < 4; nf++){ acc0[nf] = (f32x4){0,0,0,0}; acc1[nf] = (f32x4){0,0,0,0}; }

  const int xl = w*16 + lr;
  #pragma unroll
  for (int ky = 0; ky < 5; ky++){
    #pragma unroll
    for (int kx = 0; kx < 5; kx++){
      const int xx = xl + kx;
      const int tap = ky*5 + kx;
      #pragma unroll
      for (int cg = 0; cg < CIN/32; cg++){
        int aoff = ky*ROWB + xx*(CIN*2) + (cg*32 + kb*8)*2;
        aoff ^= (xx & 7) << 4;
        const bf16x8 a0 = *reinterpret_cast<const bf16x8*>(lds + aoff);
        const bf16x8 a1 = *reinterpret_cast<const bf16x8*>(lds + aoff + ROWB);
        const bf16* bp = wt + ((size_t)((tap*(CIN/32) + cg)*4)*64 + lane)*8;
        #pragma unroll
        for (int nf = 0; nf < 4; nf++){
          const bf16x8 bf_ = *reinterpret_cast<const bf16x8*>(bp + nf*512);
          acc0[nf] = __builtin_amdgcn_mfma_f32_16x16x32_bf16(a0, bf_, acc0[nf], 0, 0, 0);
          acc1[nf] = __builtin_amdgcn_mfma_f32_16x16x32_bf16(a1, bf_, acc1[nf], 0, 0, 0);
        }
      }
    }
  }

  #pragma unroll
  for (int rg = 0; rg < 4; rg++){
    const int xs = x0 + w*16 + kb*4 + rg;
    if (xs < 500){
      const size_t obase = (((size_t)(b*Hout + yo))*500 + xs)*64;
      #pragma unroll
      for (int nf = 0; nf < 4; nf++){
        const int oc = nf*16 + lr;
        const float bv = bias[oc];
        const float p0 = geluf(acc0[nf][rg] + bv);
        const float p1 = geluf(acc1[nf][rg] + bv);
        out[obase + oc] = __float2bfloat16(fmaxf(p0, p1));
      }
    }
  }
}

// ---------------- tokens: NHWC conv4 out -> tk[b*T+t][ci*12+yo] ----------------
__global__ __launch_bounds__(256) void tokens_k(const bf16* __restrict__ n4, bf16* __restrict__ tk)
{
  const int idx = blockIdx.x*256 + threadIdx.x;
  if (idx >= B_*12*500*64) return;
  const int ci = idx & 63;
  const int t  = (idx >> 6) % 500;
  const int yo = (idx >> 6) / 500 % 12;
  const int b  = idx / (64*500*12);
  tk[((size_t)(b*500 + t))*768 + ci*12 + yo] = n4[idx];
}

// ---------------- er fp32 -> bf16 ----------------
__global__ __launch_bounds__(256) void er2bf_k(const float* __restrict__ er, bf16* __restrict__ out)
{
  const int idx = blockIdx.x*256 + threadIdx.x;
  if (idx < T_*DH_) out[idx] = __float2bfloat16(er[idx]);
}

// ---------------- fp32 -> bf16 bulk cast (vectorized) ----------------
__global__ __launch_bounds__(256) void f2bf_k(const float* __restrict__ x, bf16* __restrict__ out, int n4)
{
  const int idx = blockIdx.x*256 + threadIdx.x;
  if (idx >= n4) return;
  const float4 v = *reinterpret_cast<const float4*>(x + idx*4);
  ushort4 u;
  u.x = __bfloat16_as_ushort(__float2bfloat16(v.x));
  u.y = __bfloat16_as_ushort(__float2bfloat16(v.y));
  u.z = __bfloat16_as_ushort(__float2bfloat16(v.z));
  u.w = __bfloat16_as_ushort(__float2bfloat16(v.w));
  *reinterpret_cast<ushort4*>(out + idx*4) = u;
}

// ---------------- bias pack: [bq|bk|bv] -> out[2304] fp32 ----------------
__global__ __launch_bounds__(256) void pack3_k(const float* __restrict__ a,
    const float* __restrict__ b, const float* __restrict__ c, float* __restrict__ out)
{
  const int i = blockIdx.x*256 + threadIdx.x;
  if (i >= QKVS) return;
  out[i] = (i < 768) ? a[i] : ((i < 1536) ? b[i - 768] : c[i - 1536]);
}

// ---------------- weight transpose+convert: fp32 [K][N] -> bf16 [N][K] ----------------
__global__ __launch_bounds__(256) void transpose_w(const float* __restrict__ W,
    bf16* __restrict__ out, int K, int N)
{
  __shared__ float tile[32][33];
  const int gk = blockIdx.y*32, gn = blockIdx.x*32;
  const int tr = threadIdx.x >> 5, tc = threadIdx.x & 31;
  #pragma unroll
  for (int i = 0; i < 4; i++)
    tile[tr + i*8][tc] = W[(size_t)(gk + tr + i*8)*N + gn + tc];
  __syncthreads();
  #pragma unroll
  for (int i = 0; i < 4; i++)
    out[(size_t)(gn + tr + i*8)*K + gk + tc] = __float2bfloat16(tile[tc][tr + i*8]);
}

// ---------------- MFMA GEMM: C = act(A[MxK](bf16) @ Bt[NxK]^T(bf16) + bias) (+resid) ----------------
template<int ACT, int RESID, int BF16OUT>
__global__ __launch_bounds__(256) void mfma_gemm_k(const bf16* __restrict__ A,
    const bf16* __restrict__ Bt, const float* __restrict__ bias,
    const float* __restrict__ resid, void* __restrict__ Cout, int M, int N, int K)
{
  __shared__ uint4 Alds[512];
  __shared__ uint4 Blds[512];

  const int tid = threadIdx.x;
  const int wid = tid >> 6, lane = tid & 63;
  const int wr = wid >> 1, wc = wid & 1;
  const int bm = blockIdx.y*128, bn = blockIdx.x*128;

  const int g0 = tid >> 7;
  const int r0 = tid & 127;
  const int arow = min(bm + r0, M-1);
  const int brow = min(bn + r0, N-1);
  const int lg = lane >> 4, lr = lane & 15;

  f32x4 acc[4][4];
  #pragma unroll
  for (int i = 0; i < 4; i++)
    #pragma unroll
    for (int j = 0; j < 4; j++)
      acc[i][j] = (f32x4){0.f,0.f,0.f,0.f};

  for (int k0 = 0; k0 < K; k0 += 32){
    const uint4 av0 = *reinterpret_cast<const uint4*>(A  + (size_t)arow*K + k0 + g0*8);
    const uint4 av1 = *reinterpret_cast<const uint4*>(A  + (size_t)arow*K + k0 + (g0+2)*8);
    const uint4 bv0 = *reinterpret_cast<const uint4*>(Bt + (size_t)brow*K + k0 + g0*8);
    const uint4 bv1 = *reinterpret_cast<const uint4*>(Bt + (size_t)brow*K + k0 + (g0+2)*8);
    __syncthreads();
    Alds[g0*128 + r0] = av0;  Alds[(g0+2)*128 + r0] = av1;
    Blds[g0*128 + r0] = bv0;  Blds[(g0+2)*128 + r0] = bv1;
    __syncthreads();

    bf16x8 af[4], bfr[4];
    #pragma unroll
    for (int mf = 0; mf < 4; mf++)
      af[mf] = *reinterpret_cast<const bf16x8*>(&Alds[lg*128 + wr*64 + mf*16 + lr]);
    #pragma unroll
    for (int nf = 0; nf < 4; nf++)
      bfr[nf] = *reinterpret_cast<const bf16x8*>(&Blds[lg*128 + wc*64 + nf*16 + lr]);

    #pragma unroll
    for (int mf = 0; mf < 4; mf++)
      #pragma unroll
      for (int nf = 0; nf < 4; nf++)
        acc[mf][nf] = __builtin_amdgcn_mfma_f32_16x16x32_bf16(af[mf], bfr[nf], acc[mf][nf], 0, 0, 0);
  }

  #pragma unroll
  for (int mf = 0; mf < 4; mf++){
    #pragma unroll
    for (int rg = 0; rg < 4; rg++){
      const int row = bm + wr*64 + mf*16 + (lane>>4)*4 + rg;
      if (row >= M) continue;
      #pragma unroll
      for (int nf = 0; nf < 4; nf++){
        const int col = bn + wc*64 + nf*16 + (lane&15);
        if (col >= N) continue;
        float v = acc[mf][nf][rg] + bias[col];
        if (ACT == 1) v = geluf(v);
        if (RESID)    v += resid[(size_t)row*N + col];
        if (BF16OUT)  reinterpret_cast<bf16*>(Cout)[(size_t)row*N + col] = __float2bfloat16(v);
        else          reinterpret_cast<float*>(Cout)[(size_t)row*N + col] = v;
      }
    }
  }
}

// ---------------- LayerNorm over D=768: fp32 in -> bf16 out ----------------
__global__ __launch_bounds__(256) void layernorm_k(const float* __restrict__ x,
    const float* __restrict__ g, const float* __restrict__ bb, bf16* __restrict__ out)
{
  const int row = blockIdx.x;
  const float* xr = x + (size_t)row*D_;
  const int tid = threadIdx.x;
  const float v0 = xr[tid], v1 = xr[tid+256], v2 = xr[tid+512];

  float s = v0 + v1 + v2;
  #pragma unroll
  for (int o = 32; o > 0; o >>= 1) s += __shfl_xor(s, o);
  __shared__ float sm[4];
  const int wid = tid >> 6, lane = tid & 63;
  if (lane == 0) sm[wid] = s;
  __syncthreads();
  const float mean = (sm[0]+sm[1]+sm[2]+sm[3]) * (1.f/768.f);
  __syncthreads();

  const float d0 = v0-mean, d1 = v1-mean, d2 = v2-mean;
  float ss = d0*d0 + d1*d1 + d2*d2;
  #pragma unroll
  for (int o = 32; o > 0; o >>= 1) ss += __shfl_xor(ss, o);
  if (lane == 0) sm[wid] = ss;
  __syncthreads();
  const float var = (sm[0]+sm[1]+sm[2]+sm[3]) * (1.f/768.f);
  const float inv = rsqrtf(var + 1e-5f);

  bf16* orow = out + (size_t)row*D_;
  orow[tid]     = __float2bfloat16(d0*inv*g[tid]     + bb[tid]);
  orow[tid+256] = __float2bfloat16(d1*inv*g[tid+256] + bb[tid+256]);
  orow[tid+512] = __float2bfloat16(d2*inv*g[tid+512] + bb[tid+512]);
}

// ---------------- flash attention on packed QKV [8000][2304]: MFMA QK^T + split-K + bf16 qer ----------------
// srel[q,k]: k<=q -> qer[q-q0][499-(q-k)] ; k==q+1 -> 0 ; k>q+1 -> qer[q-q0+1][k-q-2]
__global__ __launch_bounds__(256) void flash_attn_k(const bf16* __restrict__ qkv,
    const bf16* __restrict__ erb, bf16* __restrict__ ob)
{
  const int b = blockIdx.y / NH_, h = blockIdx.y % NH_;
  const int q0 = blockIdx.x * 16;
  const int tid = threadIdx.x;
  const int w = tid >> 6, lane = tid & 63;
  const int lr = lane & 15, lg = lane >> 4;

  __shared__ unsigned short qer_l[17][520];   // 17.7 KB bf16 qer
  __shared__ float vs[64][68];                // 17.4 KB V superblock
  __shared__ float S_lds[4][16][19];
  __shared__ float tmax_lds[4][16];
  __shared__ float mfin[4][16], lfin[4][16];
  float* mrg = &vs[0][0];                     // merge overlay, stride 68 (bank-safe)

  const bf16* qbase = qkv + h*DH_;            // + row*QKVS
  const bf16* kbase = qkv + 768 + h*DH_;
  const bf16* vbase = qkv + 1536 + h*DH_;

  // ---- Q fragment (rows q0..q0+15), reused for qer and QK^T ----
  int qq0 = q0 + lr;      if (qq0 > 499) qq0 = 499;
  bf16x8 qf[2];
  #pragma unroll
  for (int h2 = 0; h2 < 2; h2++)
    qf[h2] = *reinterpret_cast<const bf16x8*>(qbase + (size_t)(b*T_ + qq0)*QKVS + h2*32 + lg*8);

  // ---- qer[r][c] = Q[q0+r]·er[c], rows 0..16, via MFMA ----
  {
    int qq1 = q0 + 16 + lr; if (qq1 > 499) qq1 = 499;
    bf16x8 a1f[2];
    #pragma unroll
    for (int h2 = 0; h2 < 2; h2++)
      a1f[h2] = *reinterpret_cast<const bf16x8*>(qbase + (size_t)(b*T_ + qq1)*QKVS + h2*32 + lg*8);
    for (int ct = w; ct < 32; ct += 4){
      const int c0 = ct*16;
      int cc = c0 + lr; if (cc > 499) cc = 499;
      bf16x8 bw[2];
      #pragma unroll
      for (int h2 = 0; h2 < 2; h2++)
        bw[h2] = *reinterpret_cast<const bf16x8*>(erb + (size_t)cc*DH_ + h2*32 + lg*8);
      f32x4 c0a = (f32x4){0,0,0,0}, c1a = (f32x4){0,0,0,0};
      c0a = __builtin_amdgcn_mfma_f32_16x16x32_bf16(qf[0],  bw[0], c0a, 0, 0, 0);
      c0a = __builtin_amdgcn_mfma_f32_16x16x32_bf16(qf[1],  bw[1], c0a, 0, 0, 0);
      c1a = __builtin_amdgcn_mfma_f32_16x16x32_bf16(a1f[0], bw[0], c1a, 0, 0, 0);
      c1a = __builtin_amdgcn_mfma_f32_16x16x32_bf16(a1f[1], bw[1], c1a, 0, 0, 0);
      #pragma unroll
      for (int rg = 0; rg < 4; rg++)
        qer_l[lg*4 + rg][c0 + lr] = __bfloat16_as_ushort(__float2bfloat16(c0a[rg]));
      if (lg == 0) qer_l[16][c0 + lr] = __bfloat16_as_ushort(__float2bfloat16(c1a[0]));
    }
  }

  // ---- initial V stage: superblock 0 ----
  const int skr = tid >> 2;
  const int sc  = (tid & 3) * 16;
  {
    const int krow = min(skr, 499);
    const bf16* vp = vbase + (size_t)(b*T_ + krow)*QKVS + sc;
    const ushort4 u0 = *reinterpret_cast<const ushort4*>(vp);
    const ushort4 u1 = *reinterpret_cast<const ushort4*>(vp + 4);
    const ushort4 u2 = *reinterpret_cast<const ushort4*>(vp + 8);
    const ushort4 u3 = *reinterpret_cast<const ushort4*>(vp + 12);
    float* d = &vs[skr][sc];
    d[0]=bfu2f(u0.x); d[1]=bfu2f(u0.y); d[2]=bfu2f(u0.z); d[3]=bfu2f(u0.w);
    d[4]=bfu2f(u1.x); d[5]=bfu2f(u1.y); d[6]=bfu2f(u1.z); d[7]=bfu2f(u1.w);
    d[8]=bfu2f(u2.x); d[9]=bfu2f(u2.y); d[10]=bfu2f(u2.z); d[11]=bfu2f(u2.w);
    d[12]=bfu2f(u3.x); d[13]=bfu2f(u3.y); d[14]=bfu2f(u3.z); d[15]=bfu2f(u3.w);
  }
  __syncthreads();

  float m = -3.0e38f, l = 0.f;
  float oacc[16];
  #pragma unroll
  for (int j = 0; j < 16; j++) oacc[j] = 0.f;

  for (int sb = 0; sb < 8; sb++){
    const int K0 = sb*64;
    const bool pf = (sb < 7);
    ushort4 p0, p1, p2, p3;
    if (pf){
      const int krow = min(K0 + 64 + skr, 499);
      const bf16* vp = vbase + (size_t)(b*T_ + krow)*QKVS + sc;
      p0 = *reinterpret_cast<const ushort4*>(vp);
      p1 = *reinterpret_cast<const ushort4*>(vp + 4);
      p2 = *reinterpret_cast<const ushort4*>(vp + 8);
      p3 = *reinterpret_cast<const ushort4*>(vp + 12);
    }

    // ---- S-tile via MFMA: wave w handles k-tile k0 = K0 + w*16 ----
    const int k0 = K0 + w*16;
    int kk = k0 + lr; if (kk > 499) kk = 499;
    bf16x8 kf[2];
    #pragma unroll
    for (int h2 = 0; h2 < 2; h2++)
      kf[h2] = *reinterpret_cast<const bf16x8*>(kbase + (size_t)(b*T_ + kk)*QKVS + h2*32 + lg*8);
    f32x4 sacc = (f32x4){0,0,0,0};
    sacc = __builtin_amdgcn_mfma_f32_16x16x32_bf16(qf[0], kf[0], sacc, 0, 0, 0);
    sacc = __builtin_amdgcn_mfma_f32_16x16x32_bf16(qf[1], kf[1], sacc, 0, 0, 0);

    const int kcol = k0 + lr;
    float sv[4];
    #pragma unroll
    for (int rg = 0; rg < 4; rg++){
      const int r = lg*4 + rg;
      const int q = q0 + r;
      float d2 = 0.f;
      if (kcol != q + 1){
        const int eidx = (kcol <= q) ? (499 - q + kcol) : (kcol - q - 2);
        d2 = bfu2f(qer_l[(kcol <= q) ? r : r + 1][eidx]);
      }
      float s = (sacc[rg] + d2) * 0.125f;
      if (kcol >= 500) s = -3.0e38f;
      sv[rg] = s;
    }
    float tm[4];
    #pragma unroll
    for (int rg = 0; rg < 4; rg++){
      tm[rg] = sv[rg];
      #pragma unroll
      for (int o = 8; o > 0; o >>= 1) tm[rg] = fmaxf(tm[rg], __shfl_xor(tm[rg], o, 16));
    }
    #pragma unroll
    for (int rg = 0; rg < 4; rg++) S_lds[w][lg*4 + rg][lr] = sv[rg];
    if (lr == 0){
      #pragma unroll
      for (int rg = 0; rg < 4; rg++) tmax_lds[w][lg*4 + rg] = tm[rg];
    }

    // ---- PV: lane owns row q'=lr, d-range lg*16..+15 ----
    const float tmv = tmax_lds[w][lr];
    const float mn = fmaxf(m, tmv);
    const float corr = __expf(m - mn);
    m = mn;
    l *= corr;
    #pragma unroll
    for (int j = 0; j < 16; j++) oacc[j] *= corr;

    #pragma unroll
    for (int k2 = 0; k2 < 16; k2++){
      const float p = __expf(S_lds[w][lr][k2] - mn);
      l += p;
      const float* vrow = &vs[w*16 + k2][lg*16];
      const float4 va = *reinterpret_cast<const float4*>(vrow);
      const float4 vbv = *reinterpret_cast<const float4*>(vrow + 4);
      const float4 vc = *reinterpret_cast<const float4*>(vrow + 8);
      const float4 vd = *reinterpret_cast<const float4*>(vrow + 12);
      oacc[0]  = fmaf(p, va.x,  oacc[0]);  oacc[1]  = fmaf(p, va.y,  oacc[1]);
      oacc[2]  = fmaf(p, va.z,  oacc[2]);  oacc[3]  = fmaf(p, va.w,  oacc[3]);
      oacc[4]  = fmaf(p, vbv.x, oacc[4]);  oacc[5]  = fmaf(p, vbv.y, oacc[5]);
      oacc[6]  = fmaf(p, vbv.z, oacc[6]);  oacc[7]  = fmaf(p, vbv.w, oacc[7]);
      oacc[8]  = fmaf(p, vc.x,  oacc[8]);  oacc[9]  = fmaf(p, vc.y,  oacc[9]);
      oacc[10] = fmaf(p, vc.z,  oacc[10]); oacc[11] = fmaf(p, vc.w,  oacc[11]);
      oacc[12] = fmaf(p, vd.x,  oacc[12]); oacc[13] = fmaf(p, vd.y,  oacc[13]);
      oacc[14] = fmaf(p, vd.z,  oacc[14]); oacc[15] = fmaf(p, vd.w,  oacc[15]);
    }

    if (pf){
      __syncthreads();
      float* d = &vs[skr][sc];
      d[0]=bfu2f(p0.x); d[1]=bfu2f(p0.y); d[2]=bfu2f(p0.z); d[3]=bfu2f(p0.w);
      d[4]=bfu2f(p1.x); d[5]=bfu2f(p1.y); d[6]=bfu2f(p1.z); d[7]=bfu2f(p1.w);
      d[8]=bfu2f(p2.x); d[9]=bfu2f(p2.y); d[10]=bfu2f(p2.z); d[11]=bfu2f(p2.w);
      d[12]=bfu2f(p3.x); d[13]=bfu2f(p3.y); d[14]=bfu2f(p3.z); d[15]=bfu2f(p3.w);
      __syncthreads();
    }
  }

  // ---- split-K merge (stride 68 overlay: bank-safe) ----
  __syncthreads();
  #pragma unroll
  for (int j4 = 0; j4 < 4; j4++)
    *reinterpret_cast<float4*>(&mrg[(w*16 + lr)*68 + lg*16 + j4*4]) =
      make_float4(oacc[j4*4+0], oacc[j4*4+1], oacc[j4*4+2], oacc[j4*4+3]);
  if (lg == 0){ mfin[w][lr] = m; lfin[w][lr] = l; }
  __syncthreads();

  const int qp = tid & 15, dgj = tid >> 4;
  float M = fmaxf(fmaxf(mfin[0][qp], mfin[1][qp]), fmaxf(mfin[2][qp], mfin[3][qp]));
  float L = 0.f, o0 = 0.f, o1 = 0.f, o2 = 0.f, o3 = 0.f;
  #pragma unroll
  for (int w2 = 0; w2 < 4; w2++){
    const float e = __expf(mfin[w2][qp] - M);
    L += lfin[w2][qp] * e;
    const float* src = &mrg[(w2*16 + qp)*68 + dgj*4];
    o0 = fmaf(e, src[0], o0); o1 = fmaf(e, src[1], o1);
    o2 = fmaf(e, src[2], o2); o3 = fmaf(e, src[3], o3);
  }
  const int q = q0 + qp;
  if (q < T_){
    const float inv = 1.f / L;
    bf16* op = ob + ((size_t)(b*T_ + q))*D_ + h*DH_ + dgj*4;
    ushort4 u;
    u.x = __bfloat16_as_ushort(__float2bfloat16(o0*inv));
    u.y = __bfloat16_as_ushort(__float2bfloat16(o1*inv));
    u.z = __bfloat16_as_ushort(__float2bfloat16(o2*inv));
    u.w = __bfloat16_as_ushort(__float2bfloat16(o3*inv));
    *reinterpret_cast<ushort4*>(op) = u;
  }
}

// =====================================================================
extern "C" void kernel_launch(void* const* d_in, const int* in_sizes, int n_in,
                              void* d_out, int out_size, void* d_ws, size_t ws_size,
                              hipStream_t stream)
{
  const float* spec  = (const float*)d_in[0];
  const float* cw1 = (const float*)d_in[1];  const float* cb1 = (const float*)d_in[2];
  const float* cw2 = (const float*)d_in[3];  const float* cb2 = (const float*)d_in[4];
  const float* cw3 = (const float*)d_in[5];  const float* cb3 = (const float*)d_in[6];
  const float* cw4 = (const float*)d_in[7];  const float* cb4 = (const float*)d_in[8];
  const float* proj_w = (const float*)d_in[9];  const float* proj_b = (const float*)d_in[10];
  const float* ln1_g = (const float*)d_in[11];  const float* ln1_b = (const float*)d_in[12];
  const float* wq = (const float*)d_in[13];  const float* bq = (const float*)d_in[14];
  const float* wk = (const float*)d_in[15];  const float* bk = (const float*)d_in[16];
  const float* wv = (const float*)d_in[17];  const float* bv = (const float*)d_in[18];
  const float* wo = (const float*)d_in[19];  const float* bo = (const float*)d_in[20];
  const float* er = (const float*)d_in[21];
  const float* ln2_g = (const float*)d_in[22];  const float* ln2_b = (const float*)d_in[23];
  const float* w1 = (const float*)d_in[24];  const float* b1 = (const float*)d_in[25];
  const float* w2 = (const float*)d_in[26];  const float* b2 = (const float*)d_in[27];
  const float* dw = (const float*)d_in[28];  const float* db = (const float*)d_in[29];

  if (ws_size < 98304000ull) return;
  char* W = (char*)d_ws;
  bf16*  n1 = (bf16*) (W + 0);
  bf16*  n2 = (bf16*) (W + 49152000);
  bf16*  n3 = (bf16*) (W + 0);
  bf16*  n4 = (bf16*) (W + 24576000);
  bf16*  tk = (bf16*) (W + 49152000);
  float* xb = (float*)(W + 0);
  bf16*  xn = (bf16*) (W + 24576000);
  bf16*  qkv= (bf16*) (W + 36864000);    // packed [8000][2304], ends 73,728,000
  bf16*  ob = (bf16*) (W + 73728000);
  bf16*  hb = (bf16*) (W + 36864000);    // FFN hidden (qkv dead by then)
  bf16*  wt = (bf16*) (W + 86016000);    // up to 3.54 MB (QKV^T) / 4.72 MB (FFN)
  bf16*  erb= (bf16*) (W + 92274688);    // 64 KB
  float* qkvb=(float*)(W + 92340224);    // 9.2 KB packed bias
  bf16* cwt2 = (bf16*)d_out;
  bf16* cwt3 = (bf16*)((char*)d_out + 262144);
  bf16* cwt4 = (bf16*)((char*)d_out + 786432);

  // ---- CNN stack (NHWC, MFMA for conv2-4) ----
  conv_wt_k<32><<<(25*32*64 + 255)/256, 256, 0, stream>>>(cw2, cwt2);
  conv_wt_k<64><<<(25*64*64 + 255)/256, 256, 0, stream>>>(cw3, cwt3);
  conv_wt_k<64><<<(25*64*64 + 255)/256, 256, 0, stream>>>(cw4, cwt4);

  conv1_k<<<(B_*96*500 + 255)/256, 256, 0, stream>>>(spec, cw1, cb1, n1);
  conv_mfma_k<32><<<dim3(8, B_*48), 256, 0, stream>>>(n1, cwt2, cb2, n2, 96);
  conv_mfma_k<64><<<dim3(8, B_*24), 256, 0, stream>>>(n2, cwt3, cb3, n3, 48);
  conv_mfma_k<64><<<dim3(8, B_*12), 256, 0, stream>>>(n3, cwt4, cb4, n4, 24);

  tokens_k<<<(B_*12*500*64 + 255)/256, 256, 0, stream>>>(n4, tk);

  transpose_w<<<dim3(D_/32, D_/32), 256, 0, stream>>>(proj_w, wt, D_, D_);
  mfma_gemm_k<0,0,0><<<dim3(6,63), 256, 0, stream>>>(tk, wt, proj_b, nullptr, xb, 8000, D_, D_);

  // ---- transformer layers ----
  for (int l = 0; l < 3; l++){
    const size_t wOff = (size_t)l*D_*D_;
    layernorm_k<<<8000, 256, 0, stream>>>(xb, ln1_g + l*D_, ln1_b + l*D_, xn);

    // fused QKV: wt = [q^T | k^T | v^T] (2304 x 768), one GEMM into packed qkv
    transpose_w<<<dim3(D_/32, D_/32), 256, 0, stream>>>(wq + wOff, wt,            D_, D_);
    transpose_w<<<dim3(D_/32, D_/32), 256, 0, stream>>>(wk + wOff, wt + 589824,   D_, D_);
    transpose_w<<<dim3(D_/32, D_/32), 256, 0, stream>>>(wv + wOff, wt + 1179648,  D_, D_);
    pack3_k<<<(QKVS + 255)/256, 256, 0, stream>>>(bq + l*D_, bk + l*D_, bv + l*D_, qkvb);
    mfma_gemm_k<0,0,1><<<dim3(18,63), 256, 0, stream>>>(xn, wt, qkvb, nullptr, qkv, 8000, QKVS, D_);

    er2bf_k<<<(T_*DH_ + 255)/256, 256, 0, stream>>>(er + (size_t)l*T_*DH_, erb);
    flash_attn_k<<<dim3(32, B_*NH_), 256, 0, stream>>>(qkv, erb, ob);

    transpose_w<<<dim3(D_/32, D_/32), 256, 0, stream>>>(wo + wOff, wt, D_, D_);
    mfma_gemm_k<0,1,0><<<dim3(6,63), 256, 0, stream>>>(ob, wt, bo + l*D_, xb, xb, 8000, D_, D_);

    layernorm_k<<<8000, 256, 0, stream>>>(xb, ln2_g + l*D_, ln2_b + l*D_, xn);

    transpose_w<<<dim3(FFN_/32, D_/32), 256, 0, stream>>>(w1 + (size_t)l*D_*FFN_, wt, D_, FFN_);
    mfma_gemm_k<1,0,1><<<dim3(24,63), 256, 0, stream>>>(xn, wt, b1 + l*FFN_, nullptr, hb, 8000, FFN_, D_);
    transpose_w<<<dim3(D_/32, FFN_/32), 256, 0, stream>>>(w2 + (size_t)l*FFN_*D_, wt, FFN_, D_);
    mfma_gemm_k<0,1,0><<<dim3(6,63), 256, 0, stream>>>(hb, wt, b2 + l*D_, xb, xb, 8000, D_, FFN_);
  }

  // ---- deproj via MFMA -> fp32 output [8000, 192] ----
  f2bf_k<<<(8000*D_/4 + 255)/256, 256, 0, stream>>>(xb, xn, 8000*D_/4);
  transpose_w<<<dim3(192/32, D_/32), 256, 0, stream>>>(dw, wt, D_, 192);
  mfma_gemm_k<0,0,0><<<dim3(2,63), 256, 0, stream>>>(xn, wt, db, nullptr, d_out, 8000, 192, D_);
}